// Round 1
// baseline (2677.064 us; speedup 1.0000x reference)
//
#include <hip/hip_runtime.h>
#include <hip/hip_bf16.h>
#include <math.h>

typedef __bf16 bf16;
typedef __attribute__((ext_vector_type(8))) __bf16 bf16x8;
typedef __attribute__((ext_vector_type(4))) float f32x4;
typedef __attribute__((ext_vector_type(4))) unsigned int u32x4;

// ---------------- problem constants ----------------
constexpr int NN  = 10000;   // nodes
constexpr int DEG = 20;      // neighbors
constexpr int DM  = 516;     // d_model
// GEMM tiling
constexpr int BM = 128, BN = 176, BK = 64;
constexpr int LDA_ = 72;     // BK + 8 pad (bf16 elems)

// ---------------- workspace layout (bytes) ----------------
constexpr size_t WKVT_OFF = 0;                                    // bf16 [1056][576]
constexpr size_t FCWT_OFF = WKVT_OFF + (size_t)1056*576*2;        // bf16 [528][576]
constexpr size_t WQT_OFF  = FCWT_OFF + (size_t)528*576*2;         // bf16 [528][192]
constexpr size_t M1WT_OFF = WQT_OFF  + (size_t)528*192*2;         // bf16 [176][704]
constexpr size_t M2WT_OFF = M1WT_OFF + (size_t)176*704*2;         // bf16 [176][192]
constexpr size_t QB_OFF   = M2WT_OFF + (size_t)176*192*2;         // f32 [516]
constexpr size_t CPH_OFF  = QB_OFF   + 516*4;                     // f32 [172]
constexpr size_t NH16_OFF = CPH_OFF  + 172*4;                     // bf16 [10000][192]
constexpr size_t Q_OFF    = NH16_OFF + (size_t)NN*192*2;          // f32 [10000][516]
constexpr size_t ATT_OFF  = Q_OFF    + (size_t)NN*516*4;          // f32 [10000][516]
constexpr size_t OVL_OFF  = ATT_OFF  + (size_t)NN*516*4;          // overlay start
constexpr size_t FCR_OFF  = OVL_OFF;                              // f32 [10000][516]
constexpr size_t X_OFF    = FCR_OFF  + (size_t)NN*516*4;          // bf16 [10000][704]
constexpr size_t R_OFF    = X_OFF    + (size_t)NN*704*2;          // bf16 [10000][192]
constexpr size_t OVERLAY_MIN = (size_t)NN*516*4 + (size_t)NN*704*2 + (size_t)NN*192*2;

// ---------------- prep kernels ----------------
// dst[(c+dstColOff)*dstK + kk] = bf16(src[kk*srcLD + c])  (transpose-pack, n-major)
__global__ void pack_t_kernel(const float* __restrict__ src, int srcLD, int Krows, int Ncols,
                              bf16* __restrict__ dst, int dstK, int dstColOff) {
    int total = Krows * Ncols;
    for (int idx = blockIdx.x * blockDim.x + threadIdx.x; idx < total;
         idx += gridDim.x * blockDim.x) {
        int kk = idx / Ncols, c = idx % Ncols;
        dst[(size_t)(c + dstColOff) * dstK + kk] = (bf16)src[(size_t)kk * srcLD + c];
    }
}

__global__ void nh_pack_kernel(const float* __restrict__ node_h, bf16* __restrict__ nh16) {
    int total = NN * 192;
    for (int idx = blockIdx.x * blockDim.x + threadIdx.x; idx < total;
         idx += gridDim.x * blockDim.x) {
        int i = idx / 192, c = idx % 192;
        nh16[idx] = (c < 172) ? (bf16)node_h[(size_t)i*172 + c] : (bf16)0.f;
    }
}

// q_bias[c] = sum_j cos(phase[j]) * w_q[(344+j)*516 + c];  cph[j] = cos(phase[j])
__global__ void qbias_kernel(const float* __restrict__ w_q, const float* __restrict__ phase,
                             float* __restrict__ q_bias, float* __restrict__ cph) {
    int t = blockIdx.x * blockDim.x + threadIdx.x;
    if (t < 172) cph[t] = cosf(phase[t]);
    if (t < 516) {
        float s = 0.f;
        for (int j = 0; j < 172; ++j)
            s += cosf(phase[j]) * w_q[(size_t)(344 + j) * 516 + t];
        q_bias[t] = s;
    }
}

// ---------------- generic MFMA GEMM ----------------
// MODE 0: KV   A = z built on the fly (gather+edge_feat+cos), out = KV bf16 [M][1056]
// MODE 1: Q    A = NH16 bf16 [192],  out = q f32 [516] + q_bias
// MODE 2: FC   A = ATT f32 [516],    out = fcr f32 [516] (+fc_b +self_z)
// MODE 3: M1   A = X bf16 [704],     out = R bf16 [192] (relu(+m1_b))
// MODE 4: M2   A = R bf16 [192],     out = d_out f32 [172] (+m2_b)
template<int MODE>
__global__ __launch_bounds__(256, 2)
void gemm_kernel(const float* __restrict__ Af, const bf16* __restrict__ Ab,
                 const bf16* __restrict__ Bt,
                 float* __restrict__ outF, bf16* __restrict__ outB,
                 const float* __restrict__ bias,
                 const float* __restrict__ aux0,   // mode2: node_h
                 const float* __restrict__ aux1,   // mode2: cph
                 const bf16* __restrict__ nh16, const float* __restrict__ edge_feat,
                 const float* __restrict__ edge_t, const int* __restrict__ nbr_idx,
                 const float* __restrict__ basis_freq, const float* __restrict__ phase,
                 const float* __restrict__ t_now_p,
                 int Mreal, int edge_base) {
    constexpr int KP = (MODE==0 || MODE==2) ? 576 : (MODE==3 ? 704 : 192);

    __shared__ __align__(16) bf16 As[BM][LDA_];
    __shared__ __align__(16) bf16 Bs[BN][LDA_];
    __shared__ float sdt[BM];
    __shared__ int   ssrc[BM];
    __shared__ float sfreq[172];
    __shared__ float sphase[172];

    const int tid = threadIdx.x;

    if constexpr (MODE == 0) {
        const float tn = t_now_p[0];
        if (tid < 172) { sfreq[tid] = basis_freq[tid]; sphase[tid] = phase[tid]; }
        if (tid < BM) {
            int row_g = blockIdx.x * BM + tid;
            if (row_g < Mreal) {
                int eg = edge_base + row_g;
                sdt[tid]  = tn - edge_t[eg];
                ssrc[tid] = nbr_idx[eg];
            } else { sdt[tid] = 0.f; ssrc[tid] = 0; }
        }
    }

    const int w    = tid >> 6;
    const int lane = tid & 63;
    const int lr   = lane & 15;
    const int ls   = lane >> 4;

    f32x4 acc[2][11];
    #pragma unroll
    for (int a = 0; a < 2; ++a)
        #pragma unroll
        for (int b2 = 0; b2 < 11; ++b2) acc[a][b2] = (f32x4)(0.0f);

    for (int k0 = 0; k0 < KP; k0 += BK) {
        __syncthreads();
        // ---- stage A [128][64] ----
        {
            const int r  = tid >> 1;
            const int kb = (tid & 1) * 32;
            const int row_g = blockIdx.x * BM + r;
            const bool rv = row_g < Mreal;
            #pragma unroll
            for (int g2 = 0; g2 < 4; ++g2) {
                bf16x8 v8;
                #pragma unroll
                for (int e2 = 0; e2 < 8; ++e2) {
                    const int k = k0 + kb + g2*8 + e2;
                    bf16 val = (bf16)0.f;
                    if (rv) {
                        if constexpr (MODE == 0) {
                            if (k < 172)       val = nh16[ssrc[r]*192 + k];
                            else if (k < 344)  val = (bf16)edge_feat[(size_t)(edge_base + row_g)*172 + (k - 172)];
                            else if (k < 516)  val = (bf16)cosf(sdt[r]*sfreq[k-344] + sphase[k-344]);
                        } else if constexpr (MODE == 1) {
                            val = Ab[(size_t)row_g*192 + k];
                        } else if constexpr (MODE == 2) {
                            if (k < 516) val = (bf16)Af[(size_t)row_g*516 + k];
                        } else if constexpr (MODE == 3) {
                            val = Ab[(size_t)row_g*704 + k];
                        } else {
                            if (k < 172) val = Ab[(size_t)row_g*192 + k];
                        }
                    }
                    v8[e2] = val;
                }
                *(bf16x8*)&As[r][kb + g2*8] = v8;
            }
        }
        // ---- stage B [176][64] ----
        {
            #pragma unroll
            for (int p = 0; p < 6; ++p) {
                int idx = p*256 + tid;
                if (idx < BN*8) {
                    int c  = idx >> 3;
                    int ko = (idx & 7) * 8;
                    u32x4 w4 = *(const u32x4*)(Bt + (size_t)(blockIdx.y*BN + c)*KP + k0 + ko);
                    *(u32x4*)&Bs[c][ko] = w4;
                }
            }
        }
        __syncthreads();
        // ---- MFMA ----
        #pragma unroll
        for (int kk = 0; kk < 2; ++kk) {
            bf16x8 a0 = *(const bf16x8*)&As[w*32 +      lr][kk*32 + ls*8];
            bf16x8 a1 = *(const bf16x8*)&As[w*32 + 16 + lr][kk*32 + ls*8];
            #pragma unroll
            for (int nt = 0; nt < 11; ++nt) {
                bf16x8 bf = *(const bf16x8*)&Bs[nt*16 + lr][kk*32 + ls*8];
                acc[0][nt] = __builtin_amdgcn_mfma_f32_16x16x32_bf16(a0, bf, acc[0][nt], 0, 0, 0);
                acc[1][nt] = __builtin_amdgcn_mfma_f32_16x16x32_bf16(a1, bf, acc[1][nt], 0, 0, 0);
            }
        }
    }

    // ---- epilogue ----
    const int colb = blockIdx.y*BN + lr;
    const int rowb = blockIdx.x*BM + w*32 + ls*4;
    #pragma unroll
    for (int mt = 0; mt < 2; ++mt)
    #pragma unroll
    for (int nt = 0; nt < 11; ++nt)
    #pragma unroll
    for (int q2 = 0; q2 < 4; ++q2) {
        int row = rowb + mt*16 + q2;
        int col = colb + nt*16;
        if (row >= Mreal) continue;
        float v = acc[mt][nt][q2];
        if constexpr (MODE == 0) {
            outB[(size_t)row*1056 + col] = (bf16)v;
        } else if constexpr (MODE == 1) {
            if (col < 516) outF[(size_t)row*516 + col] = v + bias[col];
        } else if constexpr (MODE == 2) {
            if (col < 516) {
                float sz = (col < 172) ? aux0[(size_t)row*172 + col]
                                       : ((col < 344) ? 0.f : aux1[col - 344]);
                outF[(size_t)row*516 + col] = v + bias[col] + sz;
            }
        } else if constexpr (MODE == 3) {
            if (col < 172) outB[(size_t)row*192 + col] = (bf16)fmaxf(v + bias[col], 0.f);
        } else {
            if (col < 172) outF[(size_t)row*172 + col] = v + bias[col];
        }
    }
}

// ---------------- attention (reproduces the torch permute/view pair-mixing) ----------------
// pair r (global 0..9999, here both heads per node-pair): B0=2r,B1=2r+1, b=h*N+i
// logit[knbr] = (q(B0)·k(Bsrc,2e) + q(B1)·k(Bsrc,2e+1)) / sqrt(258), src=knbr/10, e=knbr%10
// out(B0)[j] = sum p[knbr]*v(Bsrc,2e)[j] ; out(B1)[j] = sum p[knbr]*v(Bsrc,2e+1)[j]
__global__ __launch_bounds__(256)
void attn_kernel(const float* __restrict__ q, const bf16* __restrict__ KV,
                 float* __restrict__ att, int node_base) {
    __shared__ float qs[2][516];
    __shared__ float lg[2][20];
    __shared__ float pp[2][20];
    const int r2 = blockIdx.x;                 // chunk-local node pair
    const int iA = node_base + 2*r2;
    const int t  = threadIdx.x;

    for (int idx = t; idx < 1032; idx += 256) {
        int nn2 = idx / 516, c = idx % 516;
        qs[nn2][c] = q[(size_t)(iA + nn2)*516 + c];
    }
    __syncthreads();

    const int w = t >> 6, lane = t & 63;
    const int h = w >> 1;
    for (int kq = 0; kq < 10; ++kq) {
        int knbr = (w & 1)*10 + kq;
        int src = knbr / 10, e = knbr % 10;
        size_t rbase = ((size_t)(2*r2 + src))*20 + 2*e;       // chunk-local edge row
        const bf16* k0p = KV + rbase*1056 + h*258;
        const bf16* k1p = KV + (rbase + 1)*1056 + h*258;
        float acc = 0.f;
        for (int j = lane; j < 258; j += 64)
            acc += qs[0][h*258 + j]*(float)k0p[j] + qs[1][h*258 + j]*(float)k1p[j];
        #pragma unroll
        for (int o = 32; o; o >>= 1) acc += __shfl_down(acc, o);
        if (lane == 0) lg[h][knbr] = acc * 0.0622573006f;     // 1/sqrt(258)
    }
    __syncthreads();
    if (t < 2) {
        int hh = t;
        float m = -1e30f;
        for (int k2 = 0; k2 < 20; ++k2) m = fmaxf(m, lg[hh][k2]);
        float ssum = 0.f;
        float ex[20];
        #pragma unroll
        for (int k2 = 0; k2 < 20; ++k2) { ex[k2] = expf(lg[hh][k2] - m); ssum += ex[k2]; }
        float inv = 1.f / ssum;
        #pragma unroll
        for (int k2 = 0; k2 < 20; ++k2) pp[hh][k2] = ex[k2] * inv;
    }
    __syncthreads();
    for (int o = t; o < 1032; o += 256) {
        int hh = o / 516, rem = o % 516;
        int nsel = rem / 258, j = rem % 258;
        float acc = 0.f;
        #pragma unroll
        for (int knbr = 0; knbr < 20; ++knbr) {
            int src = knbr / 10, e = knbr % 10;
            size_t erow = ((size_t)(2*r2 + src))*20 + 2*e + nsel;
            acc += pp[hh][knbr] * (float)KV[erow*1056 + 520 + hh*258 + j];
        }
        att[(size_t)(iA + nsel)*516 + hh*258 + j] = acc;
    }
}

// ---------------- LayerNorm + build X = [h_ln, node_h, 0pad] ----------------
__global__ __launch_bounds__(256)
void ln_x_kernel(const float* __restrict__ fcr, const float* __restrict__ g,
                 const float* __restrict__ b, const bf16* __restrict__ nh16,
                 bf16* __restrict__ X) {
    __shared__ float red[2][4];
    __shared__ float mb[2];
    const size_t i = blockIdx.x;
    const int t = threadIdx.x;
    int c0 = t, c1 = t + 256, c2 = t + 512;
    float v0 = fcr[i*516 + c0];
    float v1 = (c1 < 516) ? fcr[i*516 + c1] : 0.f;
    float v2 = (c2 < 516) ? fcr[i*516 + c2] : 0.f;
    float s = v0 + v1 + v2, ss = v0*v0 + v1*v1 + v2*v2;
    #pragma unroll
    for (int o = 32; o; o >>= 1) { s += __shfl_down(s, o); ss += __shfl_down(ss, o); }
    if ((t & 63) == 0) { red[0][t >> 6] = s; red[1][t >> 6] = ss; }
    __syncthreads();
    if (t == 0) {
        float S  = red[0][0] + red[0][1] + red[0][2] + red[0][3];
        float SS = red[1][0] + red[1][1] + red[1][2] + red[1][3];
        float mean = S / 516.f;
        float var  = SS / 516.f - mean*mean;
        mb[0] = mean; mb[1] = rsqrtf(var + 1e-5f);
    }
    __syncthreads();
    float mean = mb[0], rstd = mb[1];
    X[i*704 + c0] = (bf16)((v0 - mean)*rstd*g[c0] + b[c0]);
    if (c1 < 516) X[i*704 + c1] = (bf16)((v1 - mean)*rstd*g[c1] + b[c1]);
    if (c2 < 516) X[i*704 + c2] = (bf16)((v2 - mean)*rstd*g[c2] + b[c2]);
    for (int c = 516 + t; c < 704; c += 256)
        X[i*704 + c] = (c < 688) ? nh16[i*192 + (c - 516)] : (bf16)0.f;
}

// ---------------- launch ----------------
extern "C" void kernel_launch(void* const* d_in, const int* in_sizes, int n_in,
                              void* d_out, int out_size, void* d_ws, size_t ws_size,
                              hipStream_t stream) {
    const float* node_h     = (const float*)d_in[0];
    const float* edge_t     = (const float*)d_in[1];
    const float* edge_feat  = (const float*)d_in[2];
    const int*   nbr_idx    = (const int*)d_in[3];
    const float* t_now      = (const float*)d_in[4];
    const float* w_q        = (const float*)d_in[6];
    const float* w_k        = (const float*)d_in[7];
    const float* w_v        = (const float*)d_in[8];
    const float* basis_freq = (const float*)d_in[9];
    const float* phase      = (const float*)d_in[10];
    const float* ln_g       = (const float*)d_in[11];
    const float* ln_b       = (const float*)d_in[12];
    const float* fc_w       = (const float*)d_in[13];
    const float* fc_b       = (const float*)d_in[14];
    const float* m1_w       = (const float*)d_in[15];
    const float* m1_b       = (const float*)d_in[16];
    const float* m2_w       = (const float*)d_in[17];
    const float* m2_b       = (const float*)d_in[18];

    char* ws = (char*)d_ws;
    bf16*  WKVT = (bf16*)(ws + WKVT_OFF);
    bf16*  FCWT = (bf16*)(ws + FCWT_OFF);
    bf16*  WQT  = (bf16*)(ws + WQT_OFF);
    bf16*  M1WT = (bf16*)(ws + M1WT_OFF);
    bf16*  M2WT = (bf16*)(ws + M2WT_OFF);
    float* QB   = (float*)(ws + QB_OFF);
    float* CPH  = (float*)(ws + CPH_OFF);
    bf16*  NH16 = (bf16*)(ws + NH16_OFF);
    float* Qb   = (float*)(ws + Q_OFF);
    float* ATT  = (float*)(ws + ATT_OFF);
    float* FCR  = (float*)(ws + FCR_OFF);
    bf16*  Xb   = (bf16*)(ws + X_OFF);
    bf16*  Rb   = (bf16*)(ws + R_OFF);
    bf16*  KV   = (bf16*)(ws + OVL_OFF);

    // adaptive chunk (nodes per chunk): KV chunk = CN*20*1056*2 bytes, overlays FCR/X/R region
    int CN = 2;
    const int cands[12] = {2500, 2000, 1250, 1000, 500, 250, 200, 100, 50, 20, 10, 2};
    for (int ci = 0; ci < 12; ++ci) {
        size_t kvb = (size_t)cands[ci] * DEG * 1056 * 2;
        size_t ovl = kvb > OVERLAY_MIN ? kvb : OVERLAY_MIN;
        if (OVL_OFF + ovl <= ws_size) { CN = cands[ci]; break; }
    }

    hipMemsetAsync(ws, 0, NH16_OFF, stream);

    pack_t_kernel<<<256, 256, 0, stream>>>(w_k, 516, 516, 516, WKVT, 576, 0);
    pack_t_kernel<<<256, 256, 0, stream>>>(w_v, 516, 516, 516, WKVT, 576, 520);
    pack_t_kernel<<<64,  256, 0, stream>>>(w_q, 516, 172, 516, WQT, 192, 0);
    pack_t_kernel<<<256, 256, 0, stream>>>(fc_w, 516, 516, 516, FCWT, 576, 0);
    pack_t_kernel<<<128, 256, 0, stream>>>(m1_w, 172, 688, 172, M1WT, 704, 0);
    pack_t_kernel<<<32,  256, 0, stream>>>(m2_w, 172, 172, 172, M2WT, 192, 0);
    nh_pack_kernel<<<256, 256, 0, stream>>>(node_h, NH16);
    qbias_kernel<<<3, 256, 0, stream>>>(w_q, phase, QB, CPH);

    // q = node_h @ w_q[0:172] + q_bias
    gemm_kernel<1><<<dim3(79, 3), 256, 0, stream>>>(
        nullptr, NH16, WQT, Qb, nullptr, QB, nullptr, nullptr,
        nullptr, nullptr, nullptr, nullptr, nullptr, nullptr, nullptr, NN, 0);

    // chunked: KV projection GEMM (z built on the fly) + attention
    for (int cb = 0; cb < NN; cb += CN) {
        int ce = CN * DEG;
        gemm_kernel<0><<<dim3((ce + BM - 1) / BM, 6), 256, 0, stream>>>(
            nullptr, nullptr, WKVT, nullptr, KV, nullptr, nullptr, nullptr,
            NH16, edge_feat, edge_t, nbr_idx, basis_freq, phase, t_now, ce, cb * DEG);
        attn_kernel<<<CN / 2, 256, 0, stream>>>(Qb, KV, ATT, cb);
    }

    // fc + bias + self_z residual
    gemm_kernel<2><<<dim3(79, 3), 256, 0, stream>>>(
        ATT, nullptr, FCWT, FCR, nullptr, fc_b, node_h, CPH,
        nullptr, nullptr, nullptr, nullptr, nullptr, nullptr, nullptr, NN, 0);

    ln_x_kernel<<<NN, 256, 0, stream>>>(FCR, ln_g, ln_b, NH16, Xb);

    // m1 + relu
    gemm_kernel<3><<<dim3(79, 1), 256, 0, stream>>>(
        nullptr, Xb, M1WT, nullptr, Rb, m1_b, nullptr, nullptr,
        nullptr, nullptr, nullptr, nullptr, nullptr, nullptr, nullptr, NN, 0);

    // m2 -> out
    gemm_kernel<4><<<dim3(79, 1), 256, 0, stream>>>(
        nullptr, Rb, M2WT, (float*)d_out, nullptr, m2_b, nullptr, nullptr,
        nullptr, nullptr, nullptr, nullptr, nullptr, nullptr, nullptr, NN, 0);
}

// Round 2
// 1416.709 us; speedup vs baseline: 1.8896x; 1.8896x over previous
//
#include <hip/hip_runtime.h>
#include <hip/hip_bf16.h>
#include <math.h>

typedef __bf16 bf16;
typedef __attribute__((ext_vector_type(8))) __bf16 bf16x8;
typedef __attribute__((ext_vector_type(4))) float f32x4;
typedef __attribute__((ext_vector_type(4))) unsigned int u32x4;

// ---------------- problem constants ----------------
constexpr int NN  = 10000;   // nodes
constexpr int DEG = 20;      // neighbors
// GEMM tiling
constexpr int BM = 128, BN = 176, BK = 64;
constexpr int LDA_ = 72;     // BK + 8 pad (bf16 elems)

// ---------------- workspace layout (bytes) ----------------
constexpr size_t WKVT_OFF = 0;                                    // bf16 [1056][576]
constexpr size_t FCWT_OFF = WKVT_OFF + (size_t)1056*576*2;        // bf16 [528][576]
constexpr size_t WQT_OFF  = FCWT_OFF + (size_t)528*576*2;         // bf16 [528][192]
constexpr size_t M1WT_OFF = WQT_OFF  + (size_t)528*192*2;         // bf16 [176][704]
constexpr size_t M2WT_OFF = M1WT_OFF + (size_t)176*704*2;         // bf16 [176][192]
constexpr size_t QB_OFF   = M2WT_OFF + (size_t)176*192*2;         // f32 [516]
constexpr size_t CPH_OFF  = QB_OFF   + 516*4;                     // f32 [172]
constexpr size_t NH16_OFF = CPH_OFF  + 172*4;                     // bf16 [10000][192]
constexpr size_t Q_OFF    = NH16_OFF + (size_t)NN*192*2;          // f32 [10000][516]
constexpr size_t ATT_OFF  = Q_OFF    + (size_t)NN*516*4;          // f32 [10000][576] (zero-padded)
constexpr size_t OVL_OFF  = ATT_OFF  + (size_t)NN*576*4;          // overlay start
constexpr size_t FCR_OFF  = OVL_OFF;                              // f32 [10000][516]
constexpr size_t X_OFF    = FCR_OFF  + (size_t)NN*516*4;          // bf16 [10000][704]
constexpr size_t R_OFF    = X_OFF    + (size_t)NN*704*2;          // bf16 [10000][192]
constexpr size_t OVERLAY_MIN = (size_t)NN*516*4 + (size_t)NN*704*2 + (size_t)NN*192*2;

// ---------------- prep kernels ----------------
__global__ void pack_t_kernel(const float* __restrict__ src, int srcLD, int Krows, int Ncols,
                              bf16* __restrict__ dst, int dstK, int dstColOff) {
    int total = Krows * Ncols;
    for (int idx = blockIdx.x * blockDim.x + threadIdx.x; idx < total;
         idx += gridDim.x * blockDim.x) {
        int kk = idx / Ncols, c = idx % Ncols;
        dst[(size_t)(c + dstColOff) * dstK + kk] = (bf16)src[(size_t)kk * srcLD + c];
    }
}

__global__ void nh_pack_kernel(const float* __restrict__ node_h, bf16* __restrict__ nh16) {
    int total = NN * 192;
    for (int idx = blockIdx.x * blockDim.x + threadIdx.x; idx < total;
         idx += gridDim.x * blockDim.x) {
        int i = idx / 192, c = idx % 192;
        nh16[idx] = (c < 172) ? (bf16)node_h[(size_t)i*172 + c] : (bf16)0.f;
    }
}

__global__ void qbias_kernel(const float* __restrict__ w_q, const float* __restrict__ phase,
                             float* __restrict__ q_bias, float* __restrict__ cph) {
    int t = blockIdx.x * blockDim.x + threadIdx.x;
    if (t < 172) cph[t] = cosf(phase[t]);
    if (t < 516) {
        float s = 0.f;
        for (int j = 0; j < 172; ++j)
            s += cosf(phase[j]) * w_q[(size_t)(344 + j) * 516 + t];
        q_bias[t] = s;
    }
}

// ---------------- per-chunk Z build: Z[ce][576] bf16 ----------------
// cols: [0,172) nh16[src], [172,344) edge_feat, [344,516) cos(dt*f+ph), [516,576) zero
__global__ __launch_bounds__(256)
void build_z_kernel(const bf16* __restrict__ nh16, const float* __restrict__ edge_feat,
                    const float* __restrict__ edge_t, const int* __restrict__ nbr_idx,
                    const float* __restrict__ freq, const float* __restrict__ ph,
                    const float* __restrict__ t_now_p,
                    bf16* __restrict__ Z, int ce, int edge_base) {
    int idx = blockIdx.x * blockDim.x + threadIdx.x;
    int total = ce * 72;
    if (idx >= total) return;
    int row = idx / 72, c = idx % 72;
    int k0 = c * 8;
    int eg = edge_base + row;
    bf16x8 v;
    if (c < 21) {
        v = *(const bf16x8*)(nh16 + (size_t)nbr_idx[eg] * 192 + k0);
    } else if (c == 21) {                       // k 168..175 mixed nh/ef
        int src = nbr_idx[eg];
        #pragma unroll
        for (int e = 0; e < 8; ++e) {
            int k = 168 + e;
            v[e] = (k < 172) ? nh16[(size_t)src * 192 + k]
                             : (bf16)edge_feat[(size_t)eg * 172 + (k - 172)];
        }
    } else if (c < 43) {                        // pure edge_feat
        const float* ep = edge_feat + (size_t)eg * 172 + (k0 - 172);
        f32x4 a = *(const f32x4*)ep;
        f32x4 b = *(const f32x4*)(ep + 4);
        #pragma unroll
        for (int e = 0; e < 4; ++e) { v[e] = (bf16)a[e]; v[e+4] = (bf16)b[e]; }
    } else if (c < 64) {                        // pure time-enc
        float dt = t_now_p[0] - edge_t[eg];
        #pragma unroll
        for (int e = 0; e < 8; ++e) {
            int j = k0 - 344 + e;
            v[e] = (bf16)cosf(dt * freq[j] + ph[j]);
        }
    } else if (c == 64) {                       // k 512..519 mixed tenc/zero
        float dt = t_now_p[0] - edge_t[eg];
        #pragma unroll
        for (int e = 0; e < 8; ++e) {
            int k = 512 + e;
            v[e] = (k < 516) ? (bf16)cosf(dt * freq[k - 344] + ph[k - 344]) : (bf16)0.f;
        }
    } else {
        #pragma unroll
        for (int e = 0; e < 8; ++e) v[e] = (bf16)0.f;
    }
    *(bf16x8*)(Z + (size_t)row * 576 + k0) = v;
}

// ---------------- generic MFMA GEMM ----------------
// MODE 0: KV  A = Z bf16 [576],   out = KV bf16 [1056]
// MODE 1: Q   A = NH16 bf16 [192],out = q f32 [516] + q_bias
// MODE 2: FC  A = ATT f32 [576],  out = fcr f32 [516] (+fc_b +self_z)
// MODE 3: M1  A = X bf16 [704],   out = R bf16 [192] (relu(+m1_b), cols 172..175 zeroed)
// MODE 4: M2  A = R bf16 [192],   out = d_out f32 [172] (+m2_b)
template<int MODE>
__global__ __launch_bounds__(256, 2)
void gemm_kernel(const float* __restrict__ Af, const bf16* __restrict__ Ab,
                 const bf16* __restrict__ Bt,
                 float* __restrict__ outF, bf16* __restrict__ outB,
                 const float* __restrict__ bias,
                 const float* __restrict__ aux0,   // mode2: node_h
                 const float* __restrict__ aux1,   // mode2: cph
                 int Mreal) {
    constexpr int KP = (MODE==0 || MODE==2) ? 576 : (MODE==3 ? 704 : 192);
    constexpr int AS = (MODE==0) ? 576 : (MODE==3 ? 704 : 192);  // bf16 A row stride

    __shared__ __align__(16) bf16 As[BM][LDA_];
    __shared__ __align__(16) bf16 Bs[BN][LDA_];

    const int tid  = threadIdx.x;
    const int w    = tid >> 6;
    const int lane = tid & 63;
    const int lr   = lane & 15;
    const int ls   = lane >> 4;

    f32x4 acc[2][11];
    #pragma unroll
    for (int a = 0; a < 2; ++a)
        #pragma unroll
        for (int b2 = 0; b2 < 11; ++b2) acc[a][b2] = (f32x4)(0.0f);

    for (int k0 = 0; k0 < KP; k0 += BK) {
        __syncthreads();
        // ---- stage A [128][64]: vector loads only ----
        {
            const int r  = tid >> 1;
            const int kb = (tid & 1) * 32;
            const int row_g = blockIdx.x * BM + r;
            const bool rv = row_g < Mreal;
            #pragma unroll
            for (int g2 = 0; g2 < 4; ++g2) {
                const int k = k0 + kb + g2 * 8;
                bf16x8 v8;
                if (rv) {
                    if constexpr (MODE == 2) {
                        const float* ap = Af + (size_t)row_g * 576 + k;
                        f32x4 lo = *(const f32x4*)ap;
                        f32x4 hi = *(const f32x4*)(ap + 4);
                        #pragma unroll
                        for (int e = 0; e < 4; ++e) { v8[e] = (bf16)lo[e]; v8[e+4] = (bf16)hi[e]; }
                    } else {
                        v8 = *(const bf16x8*)(Ab + (size_t)row_g * AS + k);
                    }
                } else {
                    #pragma unroll
                    for (int e = 0; e < 8; ++e) v8[e] = (bf16)0.f;
                }
                *(bf16x8*)&As[r][kb + g2 * 8] = v8;
            }
        }
        // ---- stage B [176][64] ----
        {
            #pragma unroll
            for (int p = 0; p < 6; ++p) {
                int idx = p * 256 + tid;
                if (idx < BN * 8) {
                    int c  = idx >> 3;
                    int ko = (idx & 7) * 8;
                    u32x4 w4 = *(const u32x4*)(Bt + (size_t)(blockIdx.y * BN + c) * KP + k0 + ko);
                    *(u32x4*)&Bs[c][ko] = w4;
                }
            }
        }
        __syncthreads();
        // ---- MFMA ----
        #pragma unroll
        for (int kk = 0; kk < 2; ++kk) {
            bf16x8 a0 = *(const bf16x8*)&As[w*32 +      lr][kk*32 + ls*8];
            bf16x8 a1 = *(const bf16x8*)&As[w*32 + 16 + lr][kk*32 + ls*8];
            #pragma unroll
            for (int nt = 0; nt < 11; ++nt) {
                bf16x8 bf = *(const bf16x8*)&Bs[nt*16 + lr][kk*32 + ls*8];
                acc[0][nt] = __builtin_amdgcn_mfma_f32_16x16x32_bf16(a0, bf, acc[0][nt], 0, 0, 0);
                acc[1][nt] = __builtin_amdgcn_mfma_f32_16x16x32_bf16(a1, bf, acc[1][nt], 0, 0, 0);
            }
        }
    }

    // ---- epilogue ----
    const int colb = blockIdx.y * BN + lr;
    const int rowb = blockIdx.x * BM + w*32 + ls*4;
    #pragma unroll
    for (int mt = 0; mt < 2; ++mt)
    #pragma unroll
    for (int nt = 0; nt < 11; ++nt)
    #pragma unroll
    for (int q2 = 0; q2 < 4; ++q2) {
        int row = rowb + mt*16 + q2;
        int col = colb + nt*16;
        if (row >= Mreal) continue;
        float v = acc[mt][nt][q2];
        if constexpr (MODE == 0) {
            outB[(size_t)row*1056 + col] = (bf16)v;
        } else if constexpr (MODE == 1) {
            if (col < 516) outF[(size_t)row*516 + col] = v + bias[col];
        } else if constexpr (MODE == 2) {
            if (col < 516) {
                float sz = (col < 172) ? aux0[(size_t)row*172 + col]
                                       : ((col < 344) ? 0.f : aux1[col - 344]);
                outF[(size_t)row*516 + col] = v + bias[col] + sz;
            }
        } else if constexpr (MODE == 3) {
            // cols 0..175 all stored; 172..175 forced zero so MODE 4 A-loads are clean
            float vv = 0.f;
            if (col < 172) vv = fmaxf(v + bias[col], 0.f);
            outB[(size_t)row*192 + col] = (bf16)vv;
        } else {
            if (col < 172) outF[(size_t)row*172 + col] = v + bias[col];
        }
    }
}

// ---------------- attention (reproduces the torch permute/view pair-mixing) ----------------
__global__ __launch_bounds__(256)
void attn_kernel(const float* __restrict__ q, const bf16* __restrict__ KV,
                 float* __restrict__ att, int node_base) {
    __shared__ float qs[2][516];
    __shared__ float lg[2][20];
    __shared__ float pp[2][20];
    const int r2 = blockIdx.x;                 // chunk-local node pair
    const int iA = node_base + 2*r2;
    const int t  = threadIdx.x;

    for (int idx = t; idx < 1032; idx += 256) {
        int nn2 = idx / 516, c = idx % 516;
        qs[nn2][c] = q[(size_t)(iA + nn2)*516 + c];
    }
    __syncthreads();

    const int w = t >> 6, lane = t & 63;
    const int h = w >> 1;
    for (int kq = 0; kq < 10; ++kq) {
        int knbr = (w & 1)*10 + kq;
        int src = knbr / 10, e = knbr % 10;
        size_t rbase = ((size_t)(2*r2 + src))*20 + 2*e;       // chunk-local edge row
        const bf16* k0p = KV + rbase*1056 + h*258;
        const bf16* k1p = KV + (rbase + 1)*1056 + h*258;
        float acc = 0.f;
        for (int j = lane; j < 258; j += 64)
            acc += qs[0][h*258 + j]*(float)k0p[j] + qs[1][h*258 + j]*(float)k1p[j];
        #pragma unroll
        for (int o = 32; o; o >>= 1) acc += __shfl_down(acc, o);
        if (lane == 0) lg[h][knbr] = acc * 0.0622573006f;     // 1/sqrt(258)
    }
    __syncthreads();
    if (t < 2) {
        int hh = t;
        float m = -1e30f;
        for (int k2 = 0; k2 < 20; ++k2) m = fmaxf(m, lg[hh][k2]);
        float ssum = 0.f;
        float ex[20];
        #pragma unroll
        for (int k2 = 0; k2 < 20; ++k2) { ex[k2] = expf(lg[hh][k2] - m); ssum += ex[k2]; }
        float inv = 1.f / ssum;
        #pragma unroll
        for (int k2 = 0; k2 < 20; ++k2) pp[hh][k2] = ex[k2] * inv;
    }
    __syncthreads();
    for (int o = t; o < 1032; o += 256) {
        int hh = o / 516, rem = o % 516;
        int nsel = rem / 258, j = rem % 258;
        float acc = 0.f;
        #pragma unroll
        for (int knbr = 0; knbr < 20; ++knbr) {
            int src = knbr / 10, e = knbr % 10;
            size_t erow = ((size_t)(2*r2 + src))*20 + 2*e + nsel;
            acc += pp[hh][knbr] * (float)KV[erow*1056 + 520 + hh*258 + j];
        }
        att[(size_t)(iA + nsel)*576 + hh*258 + j] = acc;
    }
    // zero the K-pad columns 516..575 so the FC GEMM can vector-load unguarded
    for (int o = t; o < 120; o += 256) {
        int nsel = o / 60, c = 516 + (o % 60);
        att[(size_t)(iA + nsel)*576 + c] = 0.f;
    }
}

// ---------------- LayerNorm + build X = [h_ln, node_h, 0pad] ----------------
__global__ __launch_bounds__(256)
void ln_x_kernel(const float* __restrict__ fcr, const float* __restrict__ g,
                 const float* __restrict__ b, const bf16* __restrict__ nh16,
                 bf16* __restrict__ X) {
    __shared__ float red[2][4];
    __shared__ float mb[2];
    const size_t i = blockIdx.x;
    const int t = threadIdx.x;
    int c0 = t, c1 = t + 256, c2 = t + 512;
    float v0 = fcr[i*516 + c0];
    float v1 = (c1 < 516) ? fcr[i*516 + c1] : 0.f;
    float v2 = (c2 < 516) ? fcr[i*516 + c2] : 0.f;
    float s = v0 + v1 + v2, ss = v0*v0 + v1*v1 + v2*v2;
    #pragma unroll
    for (int o = 32; o; o >>= 1) { s += __shfl_down(s, o); ss += __shfl_down(ss, o); }
    if ((t & 63) == 0) { red[0][t >> 6] = s; red[1][t >> 6] = ss; }
    __syncthreads();
    if (t == 0) {
        float S  = red[0][0] + red[0][1] + red[0][2] + red[0][3];
        float SS = red[1][0] + red[1][1] + red[1][2] + red[1][3];
        float mean = S / 516.f;
        float var  = SS / 516.f - mean*mean;
        mb[0] = mean; mb[1] = rsqrtf(var + 1e-5f);
    }
    __syncthreads();
    float mean = mb[0], rstd = mb[1];
    X[i*704 + c0] = (bf16)((v0 - mean)*rstd*g[c0] + b[c0]);
    if (c1 < 516) X[i*704 + c1] = (bf16)((v1 - mean)*rstd*g[c1] + b[c1]);
    if (c2 < 516) X[i*704 + c2] = (bf16)((v2 - mean)*rstd*g[c2] + b[c2]);
    for (int c = 516 + t; c < 704; c += 256)
        X[i*704 + c] = (c < 688) ? nh16[i*192 + (c - 516)] : (bf16)0.f;
}

// ---------------- launch ----------------
extern "C" void kernel_launch(void* const* d_in, const int* in_sizes, int n_in,
                              void* d_out, int out_size, void* d_ws, size_t ws_size,
                              hipStream_t stream) {
    const float* node_h     = (const float*)d_in[0];
    const float* edge_t     = (const float*)d_in[1];
    const float* edge_feat  = (const float*)d_in[2];
    const int*   nbr_idx    = (const int*)d_in[3];
    const float* t_now      = (const float*)d_in[4];
    const float* w_q        = (const float*)d_in[6];
    const float* w_k        = (const float*)d_in[7];
    const float* w_v        = (const float*)d_in[8];
    const float* basis_freq = (const float*)d_in[9];
    const float* phase      = (const float*)d_in[10];
    const float* ln_g       = (const float*)d_in[11];
    const float* ln_b       = (const float*)d_in[12];
    const float* fc_w       = (const float*)d_in[13];
    const float* fc_b       = (const float*)d_in[14];
    const float* m1_w       = (const float*)d_in[15];
    const float* m1_b       = (const float*)d_in[16];
    const float* m2_w       = (const float*)d_in[17];
    const float* m2_b       = (const float*)d_in[18];

    char* ws = (char*)d_ws;
    bf16*  WKVT = (bf16*)(ws + WKVT_OFF);
    bf16*  FCWT = (bf16*)(ws + FCWT_OFF);
    bf16*  WQT  = (bf16*)(ws + WQT_OFF);
    bf16*  M1WT = (bf16*)(ws + M1WT_OFF);
    bf16*  M2WT = (bf16*)(ws + M2WT_OFF);
    float* QB   = (float*)(ws + QB_OFF);
    float* CPH  = (float*)(ws + CPH_OFF);
    bf16*  NH16 = (bf16*)(ws + NH16_OFF);
    float* Qb   = (float*)(ws + Q_OFF);
    float* ATT  = (float*)(ws + ATT_OFF);
    float* FCR  = (float*)(ws + FCR_OFF);
    bf16*  Xb   = (bf16*)(ws + X_OFF);
    bf16*  Rb   = (bf16*)(ws + R_OFF);

    // adaptive chunk: overlay holds Z (rounded to 128 rows) + KV for CN nodes
    int CN = 2;
    const int cands[12] = {1250, 1000, 625, 500, 250, 200, 125, 100, 50, 20, 10, 2};
    for (int ci = 0; ci < 12; ++ci) {
        size_t ce = (size_t)cands[ci] * DEG;
        size_t zrows = (ce + 127) & ~(size_t)127;
        size_t need = zrows * 576 * 2 + ce * 1056 * 2;
        size_t ovl = need > OVERLAY_MIN ? need : OVERLAY_MIN;
        if (OVL_OFF + ovl <= ws_size) { CN = cands[ci]; break; }
    }
    const size_t ce_sz   = (size_t)CN * DEG;
    const size_t zrows   = (ce_sz + 127) & ~(size_t)127;
    bf16* Zb = (bf16*)(ws + OVL_OFF);
    bf16* KV = (bf16*)(ws + OVL_OFF + zrows * 576 * 2);

    hipMemsetAsync(ws, 0, NH16_OFF, stream);

    pack_t_kernel<<<256, 256, 0, stream>>>(w_k, 516, 516, 516, WKVT, 576, 0);
    pack_t_kernel<<<256, 256, 0, stream>>>(w_v, 516, 516, 516, WKVT, 576, 520);
    pack_t_kernel<<<64,  256, 0, stream>>>(w_q, 516, 172, 516, WQT, 192, 0);
    pack_t_kernel<<<256, 256, 0, stream>>>(fc_w, 516, 516, 516, FCWT, 576, 0);
    pack_t_kernel<<<128, 256, 0, stream>>>(m1_w, 172, 688, 172, M1WT, 704, 0);
    pack_t_kernel<<<32,  256, 0, stream>>>(m2_w, 172, 172, 172, M2WT, 192, 0);
    nh_pack_kernel<<<256, 256, 0, stream>>>(node_h, NH16);
    qbias_kernel<<<3, 256, 0, stream>>>(w_q, phase, QB, CPH);

    // q = node_h @ w_q[0:172] + q_bias
    gemm_kernel<1><<<dim3(79, 3), 256, 0, stream>>>(
        nullptr, NH16, WQT, Qb, nullptr, QB, nullptr, nullptr, NN);

    // chunked: build Z -> KV GEMM -> attention
    const int ce = CN * DEG;
    for (int cb = 0; cb < NN; cb += CN) {
        build_z_kernel<<<(ce * 72 + 255) / 256, 256, 0, stream>>>(
            NH16, edge_feat, edge_t, nbr_idx, basis_freq, phase, t_now,
            Zb, ce, cb * DEG);
        gemm_kernel<0><<<dim3((ce + BM - 1) / BM, 6), 256, 0, stream>>>(
            nullptr, Zb, WKVT, nullptr, KV, nullptr, nullptr, nullptr, ce);
        attn_kernel<<<CN / 2, 256, 0, stream>>>(Qb, KV, ATT, cb);
    }

    // fc + bias + self_z residual
    gemm_kernel<2><<<dim3(79, 3), 256, 0, stream>>>(
        ATT, nullptr, FCWT, FCR, nullptr, fc_b, node_h, CPH, NN);

    ln_x_kernel<<<NN, 256, 0, stream>>>(FCR, ln_g, ln_b, NH16, Xb);

    // m1 + relu
    gemm_kernel<3><<<dim3(79, 1), 256, 0, stream>>>(
        nullptr, Xb, M1WT, nullptr, Rb, m1_b, nullptr, nullptr, NN);

    // m2 -> out
    gemm_kernel<4><<<dim3(79, 1), 256, 0, stream>>>(
        nullptr, Rb, M2WT, (float*)d_out, nullptr, m2_b, nullptr, nullptr, NN);
}

// Round 3
// 1185.044 us; speedup vs baseline: 2.2590x; 1.1955x over previous
//
#include <hip/hip_runtime.h>
#include <hip/hip_bf16.h>
#include <math.h>

typedef __bf16 bf16;
typedef __attribute__((ext_vector_type(8))) __bf16 bf16x8;
typedef __attribute__((ext_vector_type(4))) float f32x4;
typedef __attribute__((ext_vector_type(4))) unsigned int u32x4;

// ---------------- problem constants ----------------
constexpr int NN   = 10000;   // nodes
constexpr int NPAD = 10112;   // 10000 rounded up to 128 (DMA overrun pad)
constexpr int DEG  = 20;      // neighbors
// GEMM tiling
constexpr int BM = 128, BN = 176, BK = 64;

// ---------------- workspace layout (bytes) ----------------
constexpr size_t WKVT_OFF = 0;                                    // bf16 [1056][576]
constexpr size_t FCWT_OFF = WKVT_OFF + (size_t)1056*576*2;        // bf16 [528][576]
constexpr size_t WQT_OFF  = FCWT_OFF + (size_t)528*576*2;         // bf16 [528][192]
constexpr size_t M1WT_OFF = WQT_OFF  + (size_t)528*192*2;         // bf16 [176][704]
constexpr size_t M2WT_OFF = M1WT_OFF + (size_t)176*704*2;         // bf16 [176][192]
constexpr size_t QB_OFF   = M2WT_OFF + (size_t)176*192*2;         // f32 [516]
constexpr size_t CPH_OFF  = QB_OFF   + 516*4;                     // f32 [172]
constexpr size_t NH16_OFF = CPH_OFF  + 172*4;                     // bf16 [NPAD][192]
constexpr size_t Q_OFF    = NH16_OFF + (size_t)NPAD*192*2;        // f32 [10000][516]
constexpr size_t ATT_OFF  = Q_OFF    + (size_t)NN*516*4;          // bf16 [NPAD][576]
constexpr size_t OVL_OFF  = ATT_OFF  + (size_t)NPAD*576*2;        // overlay start
constexpr size_t FCR_OFF  = OVL_OFF;                              // f32 [10000][516]
constexpr size_t X_OFF    = FCR_OFF  + (size_t)NN*516*4;          // bf16 [NPAD][704]
constexpr size_t R_OFF    = X_OFF    + (size_t)NPAD*704*2;        // bf16 [NPAD][192]
constexpr size_t OVERLAY_MIN = (size_t)NN*516*4 + (size_t)NPAD*704*2 + (size_t)NPAD*192*2;

// ---------------- global_load_lds helper (width 16) ----------------
typedef __attribute__((address_space(3))) void lds_void;
typedef const __attribute__((address_space(1))) void glb_void;
__device__ __forceinline__ void gload16(const void* g, void* l) {
    // generic->AS1 is bit-identical; generic LDS pointer low 32 bits == LDS offset (gfx9 aperture)
    __builtin_amdgcn_global_load_lds((glb_void*)(uintptr_t)g,
                                     (lds_void*)(unsigned int)(uintptr_t)l, 16, 0, 0);
}

// ---------------- prep kernels ----------------
__global__ void pack_t_kernel(const float* __restrict__ src, int srcLD, int Krows, int Ncols,
                              bf16* __restrict__ dst, int dstK, int dstColOff) {
    int total = Krows * Ncols;
    for (int idx = blockIdx.x * blockDim.x + threadIdx.x; idx < total;
         idx += gridDim.x * blockDim.x) {
        int kk = idx / Ncols, c = idx % Ncols;
        dst[(size_t)(c + dstColOff) * dstK + kk] = (bf16)src[(size_t)kk * srcLD + c];
    }
}

__global__ void nh_pack_kernel(const float* __restrict__ node_h, bf16* __restrict__ nh16) {
    int total = NN * 192;
    for (int idx = blockIdx.x * blockDim.x + threadIdx.x; idx < total;
         idx += gridDim.x * blockDim.x) {
        int i = idx / 192, c = idx % 192;
        nh16[idx] = (c < 172) ? (bf16)node_h[(size_t)i*172 + c] : (bf16)0.f;
    }
}

__global__ void qbias_kernel(const float* __restrict__ w_q, const float* __restrict__ phase,
                             float* __restrict__ q_bias, float* __restrict__ cph) {
    int t = blockIdx.x * blockDim.x + threadIdx.x;
    if (t < 172) cph[t] = cosf(phase[t]);
    if (t < 516) {
        float s = 0.f;
        for (int j = 0; j < 172; ++j)
            s += cosf(phase[j]) * w_q[(size_t)(344 + j) * 516 + t];
        q_bias[t] = s;
    }
}

// ---------------- per-chunk Z build: Z[ce][576] bf16 ----------------
__global__ __launch_bounds__(256)
void build_z_kernel(const bf16* __restrict__ nh16, const float* __restrict__ edge_feat,
                    const float* __restrict__ edge_t, const int* __restrict__ nbr_idx,
                    const float* __restrict__ freq, const float* __restrict__ ph,
                    const float* __restrict__ t_now_p,
                    bf16* __restrict__ Z, int ce, int edge_base) {
    int idx = blockIdx.x * blockDim.x + threadIdx.x;
    int total = ce * 72;
    if (idx >= total) return;
    int row = idx / 72, c = idx % 72;
    int k0 = c * 8;
    int eg = edge_base + row;
    bf16x8 v;
    if (c < 21) {
        v = *(const bf16x8*)(nh16 + (size_t)nbr_idx[eg] * 192 + k0);
    } else if (c == 21) {
        int src = nbr_idx[eg];
        #pragma unroll
        for (int e = 0; e < 8; ++e) {
            int k = 168 + e;
            v[e] = (k < 172) ? nh16[(size_t)src * 192 + k]
                             : (bf16)edge_feat[(size_t)eg * 172 + (k - 172)];
        }
    } else if (c < 43) {
        const float* ep = edge_feat + (size_t)eg * 172 + (k0 - 172);
        f32x4 a = *(const f32x4*)ep;
        f32x4 b = *(const f32x4*)(ep + 4);
        #pragma unroll
        for (int e = 0; e < 4; ++e) { v[e] = (bf16)a[e]; v[e+4] = (bf16)b[e]; }
    } else if (c < 64) {
        float dt = t_now_p[0] - edge_t[eg];
        #pragma unroll
        for (int e = 0; e < 8; ++e) {
            int j = k0 - 344 + e;
            v[e] = (bf16)cosf(dt * freq[j] + ph[j]);
        }
    } else if (c == 64) {
        float dt = t_now_p[0] - edge_t[eg];
        #pragma unroll
        for (int e = 0; e < 8; ++e) {
            int k = 512 + e;
            v[e] = (k < 516) ? (bf16)cosf(dt * freq[k - 344] + ph[k - 344]) : (bf16)0.f;
        }
    } else {
        #pragma unroll
        for (int e = 0; e < 8; ++e) v[e] = (bf16)0.f;
    }
    *(bf16x8*)(Z + (size_t)row * 576 + k0) = v;
}

// ---------------- MFMA GEMM, global_load_lds staging ----------------
// A is bf16 with row stride == KP for every mode. B is n-major [Ncols][KP].
// MODE 0: KV  (K=576, out bf16 [1056])      MODE 1: Q  (K=192, out f32 +qbias)
// MODE 2: FC  (K=576, out f32 +b +self_z)   MODE 3: M1 (K=704, out bf16 relu)
// MODE 4: M2  (K=192, out f32 +b, N=172)
template<int MODE>
__global__ __launch_bounds__(256, 3)
void gemm_kernel(const bf16* __restrict__ A, const bf16* __restrict__ Bt,
                 float* __restrict__ outF, bf16* __restrict__ outB,
                 const float* __restrict__ bias,
                 const float* __restrict__ aux0,   // mode2: node_h
                 const float* __restrict__ aux1,   // mode2: cph
                 int Mreal) {
    constexpr int KP = (MODE==0 || MODE==2) ? 576 : (MODE==3 ? 704 : 192);

    __shared__ __align__(16) bf16 As[BM][BK];   // 16 KB, linear (DMA layout)
    __shared__ __align__(16) bf16 Bs[BN][BK];   // 22 KB, linear

    const int tid  = threadIdx.x;
    const int w    = tid >> 6;
    const int lane = tid & 63;
    const int lr   = lane & 15;
    const int ls   = lane >> 4;

    // DMA lane mapping: instr covers 8 rows x 64 cols; lane l -> row l/8, col (l%8)*8
    const int lrow = lane >> 3;
    const int lcol = (lane & 7) * 8;

    const bf16* aBase = A  + (size_t)(blockIdx.x * BM + w * 32 + lrow) * KP + lcol;
    const bf16* bBase = Bt + (size_t)(blockIdx.y * BN + lrow) * KP + lcol;

    f32x4 acc[2][11];
    #pragma unroll
    for (int a = 0; a < 2; ++a)
        #pragma unroll
        for (int b2 = 0; b2 < 11; ++b2) acc[a][b2] = (f32x4)(0.0f);

    for (int k0 = 0; k0 < KP; k0 += BK) {
        __syncthreads();
        // A tile: 16 instrs, wave w handles its own 32 rows (4 instrs)
        #pragma unroll
        for (int i = 0; i < 4; ++i)
            gload16(aBase + (size_t)(i * 8) * KP + k0, &As[w * 32 + i * 8][0]);
        // B tile: 22 instrs, strided over waves (uniform predicate)
        #pragma unroll
        for (int jj = 0; jj < 6; ++jj) {
            int j = jj * 4 + w;
            if (j < 22)
                gload16(bBase + (size_t)(j * 8) * KP + k0 - (size_t)lrow * KP
                              + (size_t)lrow * KP,   // keep addressing simple
                        &Bs[j * 8][0]);
        }
        __syncthreads();
        #pragma unroll
        for (int kk = 0; kk < 2; ++kk) {
            bf16x8 a0 = *(const bf16x8*)&As[w*32 +      lr][kk*32 + ls*8];
            bf16x8 a1 = *(const bf16x8*)&As[w*32 + 16 + lr][kk*32 + ls*8];
            #pragma unroll
            for (int nt = 0; nt < 11; ++nt) {
                bf16x8 bfr = *(const bf16x8*)&Bs[nt*16 + lr][kk*32 + ls*8];
                acc[0][nt] = __builtin_amdgcn_mfma_f32_16x16x32_bf16(a0, bfr, acc[0][nt], 0, 0, 0);
                acc[1][nt] = __builtin_amdgcn_mfma_f32_16x16x32_bf16(a1, bfr, acc[1][nt], 0, 0, 0);
            }
        }
    }

    // ---- epilogue ----
    const int colb = blockIdx.y * BN + lr;
    const int rowb = blockIdx.x * BM + w*32 + ls*4;
    #pragma unroll
    for (int mt = 0; mt < 2; ++mt)
    #pragma unroll
    for (int nt = 0; nt < 11; ++nt)
    #pragma unroll
    for (int q2 = 0; q2 < 4; ++q2) {
        int row = rowb + mt*16 + q2;
        int col = colb + nt*16;
        if (row >= Mreal) continue;
        float v = acc[mt][nt][q2];
        if constexpr (MODE == 0) {
            outB[(size_t)row*1056 + col] = (bf16)v;
        } else if constexpr (MODE == 1) {
            if (col < 516) outF[(size_t)row*516 + col] = v + bias[col];
        } else if constexpr (MODE == 2) {
            if (col < 516) {
                float sz = (col < 172) ? aux0[(size_t)row*172 + col]
                                       : ((col < 344) ? 0.f : aux1[col - 344]);
                outF[(size_t)row*516 + col] = v + bias[col] + sz;
            }
        } else if constexpr (MODE == 3) {
            float vv = 0.f;
            if (col < 172) vv = fmaxf(v + bias[col], 0.f);
            outB[(size_t)row*192 + col] = (bf16)vv;   // cols 172..175 zeroed
        } else {
            if (col < 172) outF[(size_t)row*172 + col] = v + bias[col];
        }
    }
}

// ---------------- attention (torch permute/view pair-mixing), bf16 out ----------------
__global__ __launch_bounds__(256)
void attn_kernel(const float* __restrict__ q, const bf16* __restrict__ KV,
                 bf16* __restrict__ att, int node_base) {
    __shared__ float qs[2][516];
    __shared__ float lg[2][20];
    __shared__ float pp[2][20];
    const int r2 = blockIdx.x;
    const int iA = node_base + 2*r2;
    const int t  = threadIdx.x;

    for (int idx = t; idx < 1032; idx += 256) {
        int nn2 = idx / 516, c = idx % 516;
        qs[nn2][c] = q[(size_t)(iA + nn2)*516 + c];
    }
    __syncthreads();

    const int w = t >> 6, lane = t & 63;
    const int h = w >> 1;
    for (int kq = 0; kq < 10; ++kq) {
        int knbr = (w & 1)*10 + kq;
        int src = knbr / 10, e = knbr % 10;
        size_t rbase = ((size_t)(2*r2 + src))*20 + 2*e;
        const bf16* k0p = KV + rbase*1056 + h*258;
        const bf16* k1p = KV + (rbase + 1)*1056 + h*258;
        float acc = 0.f;
        for (int j = lane; j < 258; j += 64)
            acc += qs[0][h*258 + j]*(float)k0p[j] + qs[1][h*258 + j]*(float)k1p[j];
        #pragma unroll
        for (int o = 32; o; o >>= 1) acc += __shfl_down(acc, o);
        if (lane == 0) lg[h][knbr] = acc * 0.0622573006f;     // 1/sqrt(258)
    }
    __syncthreads();
    if (t < 2) {
        int hh = t;
        float m = -1e30f;
        for (int k2 = 0; k2 < 20; ++k2) m = fmaxf(m, lg[hh][k2]);
        float ssum = 0.f;
        float ex[20];
        #pragma unroll
        for (int k2 = 0; k2 < 20; ++k2) { ex[k2] = expf(lg[hh][k2] - m); ssum += ex[k2]; }
        float inv = 1.f / ssum;
        #pragma unroll
        for (int k2 = 0; k2 < 20; ++k2) pp[hh][k2] = ex[k2] * inv;
    }
    __syncthreads();
    for (int o = t; o < 1032; o += 256) {
        int hh = o / 516, rem = o % 516;
        int nsel = rem / 258, j = rem % 258;
        float acc = 0.f;
        #pragma unroll
        for (int knbr = 0; knbr < 20; ++knbr) {
            int src = knbr / 10, e = knbr % 10;
            size_t erow = ((size_t)(2*r2 + src))*20 + 2*e + nsel;
            acc += pp[hh][knbr] * (float)KV[erow*1056 + 520 + hh*258 + j];
        }
        att[(size_t)(iA + nsel)*576 + hh*258 + j] = (bf16)acc;
    }
    // zero K-pad cols 516..575 so FC GEMM K-tail is exact
    for (int o = t; o < 120; o += 256) {
        int nsel = o / 60, c = 516 + (o % 60);
        att[(size_t)(iA + nsel)*576 + c] = (bf16)0.f;
    }
}

// ---------------- LayerNorm + build X = [h_ln, node_h, 0pad] ----------------
__global__ __launch_bounds__(256)
void ln_x_kernel(const float* __restrict__ fcr, const float* __restrict__ g,
                 const float* __restrict__ b, const bf16* __restrict__ nh16,
                 bf16* __restrict__ X) {
    __shared__ float red[2][4];
    __shared__ float mb[2];
    const size_t i = blockIdx.x;
    const int t = threadIdx.x;
    int c0 = t, c1 = t + 256, c2 = t + 512;
    float v0 = fcr[i*516 + c0];
    float v1 = (c1 < 516) ? fcr[i*516 + c1] : 0.f;
    float v2 = (c2 < 516) ? fcr[i*516 + c2] : 0.f;
    float s = v0 + v1 + v2, ss = v0*v0 + v1*v1 + v2*v2;
    #pragma unroll
    for (int o = 32; o; o >>= 1) { s += __shfl_down(s, o); ss += __shfl_down(ss, o); }
    if ((t & 63) == 0) { red[0][t >> 6] = s; red[1][t >> 6] = ss; }
    __syncthreads();
    if (t == 0) {
        float S  = red[0][0] + red[0][1] + red[0][2] + red[0][3];
        float SS = red[1][0] + red[1][1] + red[1][2] + red[1][3];
        float mean = S / 516.f;
        float var  = SS / 516.f - mean*mean;
        mb[0] = mean; mb[1] = rsqrtf(var + 1e-5f);
    }
    __syncthreads();
    float mean = mb[0], rstd = mb[1];
    X[i*704 + c0] = (bf16)((v0 - mean)*rstd*g[c0] + b[c0]);
    if (c1 < 516) X[i*704 + c1] = (bf16)((v1 - mean)*rstd*g[c1] + b[c1]);
    if (c2 < 516) X[i*704 + c2] = (bf16)((v2 - mean)*rstd*g[c2] + b[c2]);
    for (int c = 516 + t; c < 704; c += 256)
        X[i*704 + c] = (c < 688) ? nh16[i*192 + (c - 516)] : (bf16)0.f;
}

// ---------------- launch ----------------
extern "C" void kernel_launch(void* const* d_in, const int* in_sizes, int n_in,
                              void* d_out, int out_size, void* d_ws, size_t ws_size,
                              hipStream_t stream) {
    const float* node_h     = (const float*)d_in[0];
    const float* edge_t     = (const float*)d_in[1];
    const float* edge_feat  = (const float*)d_in[2];
    const int*   nbr_idx    = (const int*)d_in[3];
    const float* t_now      = (const float*)d_in[4];
    const float* w_q        = (const float*)d_in[6];
    const float* w_k        = (const float*)d_in[7];
    const float* w_v        = (const float*)d_in[8];
    const float* basis_freq = (const float*)d_in[9];
    const float* phase      = (const float*)d_in[10];
    const float* ln_g       = (const float*)d_in[11];
    const float* ln_b       = (const float*)d_in[12];
    const float* fc_w       = (const float*)d_in[13];
    const float* fc_b       = (const float*)d_in[14];
    const float* m1_w       = (const float*)d_in[15];
    const float* m1_b       = (const float*)d_in[16];
    const float* m2_w       = (const float*)d_in[17];
    const float* m2_b       = (const float*)d_in[18];

    char* ws = (char*)d_ws;
    bf16*  WKVT = (bf16*)(ws + WKVT_OFF);
    bf16*  FCWT = (bf16*)(ws + FCWT_OFF);
    bf16*  WQT  = (bf16*)(ws + WQT_OFF);
    bf16*  M1WT = (bf16*)(ws + M1WT_OFF);
    bf16*  M2WT = (bf16*)(ws + M2WT_OFF);
    float* QB   = (float*)(ws + QB_OFF);
    float* CPH  = (float*)(ws + CPH_OFF);
    bf16*  NH16 = (bf16*)(ws + NH16_OFF);
    float* Qb   = (float*)(ws + Q_OFF);
    bf16*  ATTb = (bf16*)(ws + ATT_OFF);
    float* FCR  = (float*)(ws + FCR_OFF);
    bf16*  Xb   = (bf16*)(ws + X_OFF);
    bf16*  Rb   = (bf16*)(ws + R_OFF);

    // adaptive chunk: overlay holds Z (rounded to 128 rows) + KV for CN nodes
    int CN = 2;
    const int cands[12] = {1250, 1000, 625, 500, 250, 200, 125, 100, 50, 20, 10, 2};
    for (int ci = 0; ci < 12; ++ci) {
        size_t ce = (size_t)cands[ci] * DEG;
        size_t zrows = (ce + 127) & ~(size_t)127;
        size_t need = zrows * 576 * 2 + ce * 1056 * 2;
        size_t ovl = need > OVERLAY_MIN ? need : OVERLAY_MIN;
        if (OVL_OFF + ovl <= ws_size) { CN = cands[ci]; break; }
    }
    const size_t ce_sz = (size_t)CN * DEG;
    const size_t zrows = (ce_sz + 127) & ~(size_t)127;
    bf16* Zb = (bf16*)(ws + OVL_OFF);
    bf16* KV = (bf16*)(ws + OVL_OFF + zrows * 576 * 2);

    hipMemsetAsync(ws, 0, NH16_OFF, stream);

    pack_t_kernel<<<256, 256, 0, stream>>>(w_k, 516, 516, 516, WKVT, 576, 0);
    pack_t_kernel<<<256, 256, 0, stream>>>(w_v, 516, 516, 516, WKVT, 576, 520);
    pack_t_kernel<<<64,  256, 0, stream>>>(w_q, 516, 172, 516, WQT, 192, 0);
    pack_t_kernel<<<256, 256, 0, stream>>>(fc_w, 516, 516, 516, FCWT, 576, 0);
    pack_t_kernel<<<128, 256, 0, stream>>>(m1_w, 172, 688, 172, M1WT, 704, 0);
    pack_t_kernel<<<32,  256, 0, stream>>>(m2_w, 172, 172, 172, M2WT, 192, 0);
    nh_pack_kernel<<<256, 256, 0, stream>>>(node_h, NH16);
    qbias_kernel<<<3, 256, 0, stream>>>(w_q, phase, QB, CPH);

    // q = node_h @ w_q[0:172] + q_bias
    gemm_kernel<1><<<dim3(79, 3), 256, 0, stream>>>(
        NH16, WQT, Qb, nullptr, QB, nullptr, nullptr, NN);

    // chunked: build Z -> KV GEMM -> attention
    const int ce = CN * DEG;
    for (int cb = 0; cb < NN; cb += CN) {
        build_z_kernel<<<(ce * 72 + 255) / 256, 256, 0, stream>>>(
            NH16, edge_feat, edge_t, nbr_idx, basis_freq, phase, t_now,
            Zb, ce, cb * DEG);
        gemm_kernel<0><<<dim3((ce + BM - 1) / BM, 6), 256, 0, stream>>>(
            Zb, WKVT, nullptr, KV, nullptr, nullptr, nullptr, ce);
        attn_kernel<<<CN / 2, 256, 0, stream>>>(Qb, KV, ATTb, cb);
    }

    // fc + bias + self_z residual
    gemm_kernel<2><<<dim3(79, 3), 256, 0, stream>>>(
        ATTb, FCWT, FCR, nullptr, fc_b, node_h, CPH, NN);

    ln_x_kernel<<<NN, 256, 0, stream>>>(FCR, ln_g, ln_b, NH16, Xb);

    // m1 + relu
    gemm_kernel<3><<<dim3(79, 1), 256, 0, stream>>>(
        Xb, M1WT, nullptr, Rb, m1_b, nullptr, nullptr, NN);

    // m2 -> out
    gemm_kernel<4><<<dim3(79, 1), 256, 0, stream>>>(
        Rb, M2WT, (float*)d_out, nullptr, m2_b, nullptr, nullptr, NN);
}

// Round 4
// 971.876 us; speedup vs baseline: 2.7545x; 1.2193x over previous
//
#include <hip/hip_runtime.h>
#include <hip/hip_bf16.h>
#include <math.h>

typedef __bf16 bf16;
typedef __attribute__((ext_vector_type(8))) __bf16 bf16x8;
typedef __attribute__((ext_vector_type(4))) float f32x4;

// ---------------- problem constants ----------------
constexpr int NN   = 10000;   // nodes
constexpr int NPAD = 10112;   // 10000 rounded up to 128 (DMA overrun pad)
constexpr int DEG  = 20;      // neighbors
// GEMM tiling
constexpr int BM = 128, BN = 176, BK = 64;

// ---------------- workspace layout (bytes) ----------------
constexpr size_t WKVT_OFF = 0;                                    // bf16 [1056][576]
constexpr size_t FCWT_OFF = WKVT_OFF + (size_t)1056*576*2;        // bf16 [528][576]
constexpr size_t WQT_OFF  = FCWT_OFF + (size_t)528*576*2;         // bf16 [528][192]
constexpr size_t M1WT_OFF = WQT_OFF  + (size_t)528*192*2;         // bf16 [176][704]
constexpr size_t M2WT_OFF = M1WT_OFF + (size_t)176*704*2;         // bf16 [176][192]
constexpr size_t QB_OFF   = M2WT_OFF + (size_t)176*192*2;         // f32 [516]
constexpr size_t CPH_OFF  = QB_OFF   + 516*4;                     // f32 [172]
constexpr size_t NH16_OFF = CPH_OFF  + 172*4;                     // bf16 [NPAD][192]
constexpr size_t Q_OFF    = NH16_OFF + (size_t)NPAD*192*2;        // f32 [10000][516]
constexpr size_t ATT_OFF  = Q_OFF    + (size_t)NN*516*4;          // bf16 [NPAD][576]
constexpr size_t OVL_OFF  = ATT_OFF  + (size_t)NPAD*576*2;        // overlay start
constexpr size_t FCR_OFF  = OVL_OFF;                              // f32 [10000][516]
constexpr size_t X_OFF    = FCR_OFF  + (size_t)NN*516*4;          // bf16 [NPAD][704]
constexpr size_t R_OFF    = X_OFF    + (size_t)NPAD*704*2;        // bf16 [NPAD][192]
constexpr size_t OVERLAY_MIN = (size_t)NN*516*4 + (size_t)NPAD*704*2 + (size_t)NPAD*192*2;

// ---------------- global_load_lds helper (width 16) ----------------
typedef __attribute__((address_space(3))) void lds_void;
typedef const __attribute__((address_space(1))) void glb_void;
__device__ __forceinline__ void gload16(const void* g, void* l) {
    __builtin_amdgcn_global_load_lds((glb_void*)(uintptr_t)g,
                                     (lds_void*)(unsigned int)(uintptr_t)l, 16, 0, 0);
}

// ---------------- fused prep: all weight transpose-packs + nh pack + cph ----------------
// seg0 wk->WKVT col0, seg1 wv->WKVT col520, seg2 wq->WQT, seg3 fcw->FCWT,
// seg4 m1w->M1WT, seg5 m2w->M2WT, seg6 node_h->NH16, seg7 cph
__global__ __launch_bounds__(256)
void prep_kernel(const float* __restrict__ wk, const float* __restrict__ wv,
                 const float* __restrict__ wq, const float* __restrict__ fcw,
                 const float* __restrict__ m1w, const float* __restrict__ m2w,
                 const float* __restrict__ node_h, const float* __restrict__ phase,
                 bf16* __restrict__ WKVT, bf16* __restrict__ WQT, bf16* __restrict__ FCWT,
                 bf16* __restrict__ M1WT, bf16* __restrict__ M2WT, bf16* __restrict__ NH16,
                 float* __restrict__ cph) {
    constexpr int S0 = 266256;            // 516*516
    constexpr int S1 = S0 + 266256;
    constexpr int S2 = S1 + 88752;        // 172*516
    constexpr int S3 = S2 + 266256;
    constexpr int S4 = S3 + 118336;       // 688*172
    constexpr int S5 = S4 + 29584;        // 172*172
    constexpr int S6 = S5 + 1920000;      // 10000*192
    constexpr int S7 = S6 + 172;
    for (int idx = blockIdx.x * blockDim.x + threadIdx.x; idx < S7;
         idx += gridDim.x * blockDim.x) {
        if (idx < S0) {
            int i = idx, kk = i / 516, c = i % 516;
            WKVT[(size_t)c * 576 + kk] = (bf16)wk[(size_t)kk * 516 + c];
        } else if (idx < S1) {
            int i = idx - S0, kk = i / 516, c = i % 516;
            WKVT[(size_t)(c + 520) * 576 + kk] = (bf16)wv[(size_t)kk * 516 + c];
        } else if (idx < S2) {
            int i = idx - S1, kk = i / 516, c = i % 516;
            WQT[(size_t)c * 192 + kk] = (bf16)wq[(size_t)kk * 516 + c];
        } else if (idx < S3) {
            int i = idx - S2, kk = i / 516, c = i % 516;
            FCWT[(size_t)c * 576 + kk] = (bf16)fcw[(size_t)kk * 516 + c];
        } else if (idx < S4) {
            int i = idx - S3, kk = i / 172, c = i % 172;
            M1WT[(size_t)c * 704 + kk] = (bf16)m1w[(size_t)kk * 172 + c];
        } else if (idx < S5) {
            int i = idx - S4, kk = i / 172, c = i % 172;
            M2WT[(size_t)c * 192 + kk] = (bf16)m2w[(size_t)kk * 172 + c];
        } else if (idx < S6) {
            int i = idx - S5, r = i / 192, c = i % 192;
            NH16[i] = (c < 172) ? (bf16)node_h[(size_t)r * 172 + c] : (bf16)0.f;
        } else {
            int j = idx - S6;
            cph[j] = cosf(phase[j]);
        }
    }
}

// q_bias[c] = sum_j cph[j] * w_q[(344+j)*516 + c] — one block per c, LDS reduce
__global__ __launch_bounds__(256)
void qbias_kernel(const float* __restrict__ w_q, const float* __restrict__ cph,
                  float* __restrict__ q_bias) {
    __shared__ float red[256];
    const int c = blockIdx.x, j = threadIdx.x;
    red[j] = (j < 172) ? cph[j] * w_q[(size_t)(344 + j) * 516 + c] : 0.f;
    __syncthreads();
    #pragma unroll
    for (int o = 128; o; o >>= 1) {
        if (j < o) red[j] += red[j + o];
        __syncthreads();
    }
    if (j == 0) q_bias[c] = red[0];
}

// ---------------- per-chunk Z build: Z[ce][576] bf16 ----------------
__global__ __launch_bounds__(256)
void build_z_kernel(const bf16* __restrict__ nh16, const float* __restrict__ edge_feat,
                    const float* __restrict__ edge_t, const int* __restrict__ nbr_idx,
                    const float* __restrict__ freq, const float* __restrict__ ph,
                    const float* __restrict__ t_now_p,
                    bf16* __restrict__ Z, int ce, int edge_base) {
    int idx = blockIdx.x * blockDim.x + threadIdx.x;
    int total = ce * 72;
    if (idx >= total) return;
    int row = idx / 72, c = idx % 72;
    int k0 = c * 8;
    int eg = edge_base + row;
    bf16x8 v;
    if (c < 21) {
        v = *(const bf16x8*)(nh16 + (size_t)nbr_idx[eg] * 192 + k0);
    } else if (c == 21) {
        int src = nbr_idx[eg];
        #pragma unroll
        for (int e = 0; e < 8; ++e) {
            int k = 168 + e;
            v[e] = (k < 172) ? nh16[(size_t)src * 192 + k]
                             : (bf16)edge_feat[(size_t)eg * 172 + (k - 172)];
        }
    } else if (c < 43) {
        const float* ep = edge_feat + (size_t)eg * 172 + (k0 - 172);
        f32x4 a = *(const f32x4*)ep;
        f32x4 b = *(const f32x4*)(ep + 4);
        #pragma unroll
        for (int e = 0; e < 4; ++e) { v[e] = (bf16)a[e]; v[e+4] = (bf16)b[e]; }
    } else if (c < 64) {
        float dt = t_now_p[0] - edge_t[eg];
        #pragma unroll
        for (int e = 0; e < 8; ++e) {
            int j = k0 - 344 + e;
            v[e] = (bf16)cosf(dt * freq[j] + ph[j]);
        }
    } else if (c == 64) {
        float dt = t_now_p[0] - edge_t[eg];
        #pragma unroll
        for (int e = 0; e < 8; ++e) {
            int k = 512 + e;
            v[e] = (k < 516) ? (bf16)cosf(dt * freq[k - 344] + ph[k - 344]) : (bf16)0.f;
        }
    } else {
        #pragma unroll
        for (int e = 0; e < 8; ++e) v[e] = (bf16)0.f;
    }
    *(bf16x8*)(Z + (size_t)row * 576 + k0) = v;
}

// ---------------- MFMA GEMM, DMA staging + 2-phase double buffer ----------------
// MODE 0: KV  (K=576, out bf16 [1056])      MODE 1: Q  (K=192, out f32 +qbias)
// MODE 2: FC  (K=576, out f32 +b +self_z)   MODE 3: M1 (K=704, out bf16 relu)
// MODE 4: M2  (K=192, out f32 +b, N=172)
template<int MODE>
__global__ __launch_bounds__(256, 2)
void gemm_kernel(const bf16* __restrict__ A, const bf16* __restrict__ Bt,
                 float* __restrict__ outF, bf16* __restrict__ outB,
                 const float* __restrict__ bias,
                 const float* __restrict__ aux0,   // mode2: node_h
                 const float* __restrict__ aux1,   // mode2: cph
                 int Mreal) {
    constexpr int KP = (MODE==0 || MODE==2) ? 576 : (MODE==3 ? 704 : 192);
    constexpr int NT = KP / BK;

    __shared__ __align__(16) bf16 As[2][BM][BK];   // 32 KB
    __shared__ __align__(16) bf16 Bs[2][BN][BK];   // 44 KB

    const int tid  = threadIdx.x;
    const int w    = tid >> 6;
    const int lane = tid & 63;
    const int lr   = lane & 15;
    const int ls   = lane >> 4;

    // DMA lane mapping: one instr covers 8 rows x 64 cols; lane l -> row l/8, col (l%8)*8
    const int lrow = lane >> 3;
    const int lcol = (lane & 7) * 8;

    const bf16* aBase = A  + (size_t)(blockIdx.x * BM + w * 32 + lrow) * KP + lcol;
    const bf16* bBase = Bt + (size_t)(blockIdx.y * BN + lrow) * KP + lcol;

    auto stage = [&](int buf, int k0) {
        #pragma unroll
        for (int i = 0; i < 4; ++i)
            gload16(aBase + (size_t)(i * 8) * KP + k0, &As[buf][w * 32 + i * 8][0]);
        #pragma unroll
        for (int jj = 0; jj < 6; ++jj) {
            int j = jj * 4 + w;                  // wave-uniform
            if (j < 22)
                gload16(bBase + (size_t)(j * 8) * KP + k0, &Bs[buf][j * 8][0]);
        }
    };

    f32x4 acc[2][11];
    #pragma unroll
    for (int a = 0; a < 2; ++a)
        #pragma unroll
        for (int b2 = 0; b2 < 11; ++b2) acc[a][b2] = (f32x4)(0.0f);

    stage(0, 0);
    __syncthreads();                              // drains vmcnt for buf0
    int cur = 0;
    for (int t = 0; t < NT; ++t) {
        if (t + 1 < NT) stage(cur ^ 1, (t + 1) * BK);   // DMA flies under MFMA
        #pragma unroll
        for (int kk = 0; kk < 2; ++kk) {
            bf16x8 a0 = *(const bf16x8*)&As[cur][w*32 +      lr][kk*32 + ls*8];
            bf16x8 a1 = *(const bf16x8*)&As[cur][w*32 + 16 + lr][kk*32 + ls*8];
            #pragma unroll
            for (int nt = 0; nt < 11; ++nt) {
                bf16x8 bfr = *(const bf16x8*)&Bs[cur][nt*16 + lr][kk*32 + ls*8];
                acc[0][nt] = __builtin_amdgcn_mfma_f32_16x16x32_bf16(a0, bfr, acc[0][nt], 0, 0, 0);
                acc[1][nt] = __builtin_amdgcn_mfma_f32_16x16x32_bf16(a1, bfr, acc[1][nt], 0, 0, 0);
            }
        }
        __syncthreads();                          // next-tile DMA landed + readers done
        cur ^= 1;
    }

    // ---- epilogue ----
    const int colb = blockIdx.y * BN + lr;
    const int rowb = blockIdx.x * BM + w*32 + ls*4;
    #pragma unroll
    for (int mt = 0; mt < 2; ++mt)
    #pragma unroll
    for (int nt = 0; nt < 11; ++nt)
    #pragma unroll
    for (int q2 = 0; q2 < 4; ++q2) {
        int row = rowb + mt*16 + q2;
        int col = colb + nt*16;
        if (row >= Mreal) continue;
        float v = acc[mt][nt][q2];
        if constexpr (MODE == 0) {
            outB[(size_t)row*1056 + col] = (bf16)v;
        } else if constexpr (MODE == 1) {
            if (col < 516) outF[(size_t)row*516 + col] = v + bias[col];
        } else if constexpr (MODE == 2) {
            if (col < 516) {
                float sz = (col < 172) ? aux0[(size_t)row*172 + col]
                                       : ((col < 344) ? 0.f : aux1[col - 344]);
                outF[(size_t)row*516 + col] = v + bias[col] + sz;
            }
        } else if constexpr (MODE == 3) {
            float vv = 0.f;
            if (col < 172) vv = fmaxf(v + bias[col], 0.f);
            outB[(size_t)row*192 + col] = (bf16)vv;   // cols 172..175 zeroed
        } else {
            if (col < 172) outF[(size_t)row*172 + col] = v + bias[col];
        }
    }
}

// ---------------- attention (torch permute/view pair-mixing), bf16 out ----------------
__global__ __launch_bounds__(256)
void attn_kernel(const float* __restrict__ q, const bf16* __restrict__ KV,
                 bf16* __restrict__ att, int node_base) {
    __shared__ float qs[2][516];
    __shared__ float lg[2][20];
    __shared__ float pp[2][20];
    const int r2 = blockIdx.x;
    const int iA = node_base + 2*r2;
    const int t  = threadIdx.x;

    for (int idx = t; idx < 1032; idx += 256) {
        int nn2 = idx / 516, c = idx % 516;
        qs[nn2][c] = q[(size_t)(iA + nn2)*516 + c];
    }
    __syncthreads();

    const int w = t >> 6, lane = t & 63;
    const int h = w >> 1;
    for (int kq = 0; kq < 10; ++kq) {
        int knbr = (w & 1)*10 + kq;
        int src = knbr / 10, e = knbr % 10;
        size_t rbase = ((size_t)(2*r2 + src))*20 + 2*e;
        const bf16* k0p = KV + rbase*1056 + h*258;
        const bf16* k1p = KV + (rbase + 1)*1056 + h*258;
        float acc = 0.f;
        for (int j = lane; j < 258; j += 64)
            acc += qs[0][h*258 + j]*(float)k0p[j] + qs[1][h*258 + j]*(float)k1p[j];
        #pragma unroll
        for (int o = 32; o; o >>= 1) acc += __shfl_down(acc, o);
        if (lane == 0) lg[h][knbr] = acc * 0.0622573006f;     // 1/sqrt(258)
    }
    __syncthreads();
    if (t < 2) {
        int hh = t;
        float m = -1e30f;
        for (int k2 = 0; k2 < 20; ++k2) m = fmaxf(m, lg[hh][k2]);
        float ssum = 0.f;
        float ex[20];
        #pragma unroll
        for (int k2 = 0; k2 < 20; ++k2) { ex[k2] = expf(lg[hh][k2] - m); ssum += ex[k2]; }
        float inv = 1.f / ssum;
        #pragma unroll
        for (int k2 = 0; k2 < 20; ++k2) pp[hh][k2] = ex[k2] * inv;
    }
    __syncthreads();
    for (int o = t; o < 1032; o += 256) {
        int hh = o / 516, rem = o % 516;
        int nsel = rem / 258, j = rem % 258;
        float acc = 0.f;
        #pragma unroll
        for (int knbr = 0; knbr < 20; ++knbr) {
            int src = knbr / 10, e = knbr % 10;
            size_t erow = ((size_t)(2*r2 + src))*20 + 2*e + nsel;
            acc += pp[hh][knbr] * (float)KV[erow*1056 + 520 + hh*258 + j];
        }
        att[(size_t)(iA + nsel)*576 + hh*258 + j] = (bf16)acc;
    }
    for (int o = t; o < 120; o += 256) {
        int nsel = o / 60, c = 516 + (o % 60);
        att[(size_t)(iA + nsel)*576 + c] = (bf16)0.f;
    }
}

// ---------------- LayerNorm + build X = [h_ln, node_h, 0pad] ----------------
__global__ __launch_bounds__(256)
void ln_x_kernel(const float* __restrict__ fcr, const float* __restrict__ g,
                 const float* __restrict__ b, const bf16* __restrict__ nh16,
                 bf16* __restrict__ X) {
    __shared__ float red[2][4];
    __shared__ float mb[2];
    const size_t i = blockIdx.x;
    const int t = threadIdx.x;
    int c0 = t, c1 = t + 256, c2 = t + 512;
    float v0 = fcr[i*516 + c0];
    float v1 = (c1 < 516) ? fcr[i*516 + c1] : 0.f;
    float v2 = (c2 < 516) ? fcr[i*516 + c2] : 0.f;
    float s = v0 + v1 + v2, ss = v0*v0 + v1*v1 + v2*v2;
    #pragma unroll
    for (int o = 32; o; o >>= 1) { s += __shfl_down(s, o); ss += __shfl_down(ss, o); }
    if ((t & 63) == 0) { red[0][t >> 6] = s; red[1][t >> 6] = ss; }
    __syncthreads();
    if (t == 0) {
        float S  = red[0][0] + red[0][1] + red[0][2] + red[0][3];
        float SS = red[1][0] + red[1][1] + red[1][2] + red[1][3];
        float mean = S / 516.f;
        float var  = SS / 516.f - mean*mean;
        mb[0] = mean; mb[1] = rsqrtf(var + 1e-5f);
    }
    __syncthreads();
    float mean = mb[0], rstd = mb[1];
    X[i*704 + c0] = (bf16)((v0 - mean)*rstd*g[c0] + b[c0]);
    if (c1 < 516) X[i*704 + c1] = (bf16)((v1 - mean)*rstd*g[c1] + b[c1]);
    if (c2 < 516) X[i*704 + c2] = (bf16)((v2 - mean)*rstd*g[c2] + b[c2]);
    for (int c = 516 + t; c < 704; c += 256)
        X[i*704 + c] = (c < 688) ? nh16[i*192 + (c - 516)] : (bf16)0.f;
}

// ---------------- launch ----------------
extern "C" void kernel_launch(void* const* d_in, const int* in_sizes, int n_in,
                              void* d_out, int out_size, void* d_ws, size_t ws_size,
                              hipStream_t stream) {
    const float* node_h     = (const float*)d_in[0];
    const float* edge_t     = (const float*)d_in[1];
    const float* edge_feat  = (const float*)d_in[2];
    const int*   nbr_idx    = (const int*)d_in[3];
    const float* t_now      = (const float*)d_in[4];
    const float* w_q        = (const float*)d_in[6];
    const float* w_k        = (const float*)d_in[7];
    const float* w_v        = (const float*)d_in[8];
    const float* basis_freq = (const float*)d_in[9];
    const float* phase      = (const float*)d_in[10];
    const float* ln_g       = (const float*)d_in[11];
    const float* ln_b       = (const float*)d_in[12];
    const float* fc_w       = (const float*)d_in[13];
    const float* fc_b       = (const float*)d_in[14];
    const float* m1_w       = (const float*)d_in[15];
    const float* m1_b       = (const float*)d_in[16];
    const float* m2_w       = (const float*)d_in[17];
    const float* m2_b       = (const float*)d_in[18];

    char* ws = (char*)d_ws;
    bf16*  WKVT = (bf16*)(ws + WKVT_OFF);
    bf16*  FCWT = (bf16*)(ws + FCWT_OFF);
    bf16*  WQT  = (bf16*)(ws + WQT_OFF);
    bf16*  M1WT = (bf16*)(ws + M1WT_OFF);
    bf16*  M2WT = (bf16*)(ws + M2WT_OFF);
    float* QB   = (float*)(ws + QB_OFF);
    float* CPH  = (float*)(ws + CPH_OFF);
    bf16*  NH16 = (bf16*)(ws + NH16_OFF);
    float* Qb   = (float*)(ws + Q_OFF);
    bf16*  ATTb = (bf16*)(ws + ATT_OFF);
    float* FCR  = (float*)(ws + FCR_OFF);
    bf16*  Xb   = (bf16*)(ws + X_OFF);
    bf16*  Rb   = (bf16*)(ws + R_OFF);

    // adaptive chunk: overlay holds Z (rounded to 128 rows) + KV for CN nodes
    int CN = 2;
    const int cands[14] = {2500, 2000, 1250, 1000, 625, 500, 250, 200, 125, 100, 50, 20, 10, 2};
    for (int ci = 0; ci < 14; ++ci) {
        size_t ce = (size_t)cands[ci] * DEG;
        size_t zrows = (ce + 127) & ~(size_t)127;
        size_t need = zrows * 576 * 2 + ce * 1056 * 2;
        size_t ovl = need > OVERLAY_MIN ? need : OVERLAY_MIN;
        if (OVL_OFF + ovl <= ws_size) { CN = cands[ci]; break; }
    }
    const size_t ce_sz = (size_t)CN * DEG;
    const size_t zrows = (ce_sz + 127) & ~(size_t)127;
    bf16* Zb = (bf16*)(ws + OVL_OFF);
    bf16* KV = (bf16*)(ws + OVL_OFF + zrows * 576 * 2);

    hipMemsetAsync(ws, 0, NH16_OFF, stream);

    prep_kernel<<<2048, 256, 0, stream>>>(w_k, w_v, w_q, fc_w, m1_w, m2_w,
                                          node_h, phase,
                                          WKVT, WQT, FCWT, M1WT, M2WT, NH16, CPH);
    qbias_kernel<<<516, 256, 0, stream>>>(w_q, CPH, QB);

    // q = node_h @ w_q[0:172] + q_bias
    gemm_kernel<1><<<dim3(79, 3), 256, 0, stream>>>(
        NH16, WQT, Qb, nullptr, QB, nullptr, nullptr, NN);

    // chunked: build Z -> KV GEMM -> attention
    const int ce = CN * DEG;
    for (int cb = 0; cb < NN; cb += CN) {
        build_z_kernel<<<(ce * 72 + 255) / 256, 256, 0, stream>>>(
            NH16, edge_feat, edge_t, nbr_idx, basis_freq, phase, t_now,
            Zb, ce, cb * DEG);
        gemm_kernel<0><<<dim3((ce + BM - 1) / BM, 6), 256, 0, stream>>>(
            Zb, WKVT, nullptr, KV, nullptr, nullptr, nullptr, ce);
        attn_kernel<<<CN / 2, 256, 0, stream>>>(Qb, KV, ATTb, cb);
    }

    // fc + bias + self_z residual
    gemm_kernel<2><<<dim3(79, 3), 256, 0, stream>>>(
        ATTb, FCWT, FCR, nullptr, fc_b, node_h, CPH, NN);

    ln_x_kernel<<<NN, 256, 0, stream>>>(FCR, ln_g, ln_b, NH16, Xb);

    // m1 + relu
    gemm_kernel<3><<<dim3(79, 1), 256, 0, stream>>>(
        Xb, M1WT, nullptr, Rb, m1_b, nullptr, nullptr, NN);

    // m2 -> out
    gemm_kernel<4><<<dim3(79, 1), 256, 0, stream>>>(
        Rb, M2WT, (float*)d_out, nullptr, m2_b, nullptr, nullptr, NN);
}

// Round 5
// 941.076 us; speedup vs baseline: 2.8447x; 1.0327x over previous
//
#include <hip/hip_runtime.h>
#include <hip/hip_bf16.h>
#include <math.h>

typedef __bf16 bf16;
typedef __attribute__((ext_vector_type(2))) __bf16 bf16x2;
typedef __attribute__((ext_vector_type(8))) __bf16 bf16x8;
typedef __attribute__((ext_vector_type(4))) float f32x4;

// ---------------- problem constants ----------------
constexpr int NN   = 10000;   // nodes
constexpr int NPAD = 10112;   // 10000 rounded up to 128 (DMA overrun pad)
constexpr int DEG  = 20;      // neighbors
// GEMM tiling
constexpr int BM = 128, BN = 176, BK = 64;

// ---------------- workspace layout (bytes) ----------------
constexpr size_t WKVT_OFF = 0;                                    // bf16 [1056][576]
constexpr size_t FCWT_OFF = WKVT_OFF + (size_t)1056*576*2;        // bf16 [528][576]
constexpr size_t WQT_OFF  = FCWT_OFF + (size_t)528*576*2;         // bf16 [528][192]
constexpr size_t M1WT_OFF = WQT_OFF  + (size_t)528*192*2;         // bf16 [176][704]
constexpr size_t M2WT_OFF = M1WT_OFF + (size_t)176*704*2;         // bf16 [176][192]
constexpr size_t QB_OFF   = M2WT_OFF + (size_t)176*192*2;         // f32 [516]
constexpr size_t CPH_OFF  = QB_OFF   + 516*4;                     // f32 [172]
constexpr size_t NH16_OFF = CPH_OFF  + 172*4;                     // bf16 [NPAD][192]
constexpr size_t Q_OFF    = NH16_OFF + (size_t)NPAD*192*2;        // f32 [10000][516]
constexpr size_t ATT_OFF  = Q_OFF    + (size_t)NN*516*4;          // bf16 [NPAD][576]
constexpr size_t OVL_OFF  = ATT_OFF  + (size_t)NPAD*576*2;        // overlay start
constexpr size_t FCR_OFF  = OVL_OFF;                              // f32 [10000][516]
constexpr size_t X_OFF    = FCR_OFF  + (size_t)NN*516*4;          // bf16 [NPAD][704]
constexpr size_t R_OFF    = X_OFF    + (size_t)NPAD*704*2;        // bf16 [NPAD][192]
constexpr size_t OVERLAY_MIN = (size_t)NN*516*4 + (size_t)NPAD*704*2 + (size_t)NPAD*192*2;

// ---------------- global_load_lds helper (width 16) ----------------
typedef __attribute__((address_space(3))) void lds_void;
typedef const __attribute__((address_space(1))) void glb_void;
__device__ __forceinline__ void gload16(const void* g, void* l) {
    __builtin_amdgcn_global_load_lds((glb_void*)(uintptr_t)g,
                                     (lds_void*)(unsigned int)(uintptr_t)l, 16, 0, 0);
}

// ---------------- tiled transpose-pack: dst[(c+off)*LD + k] = bf16(src[k*C + c]) ----------------
// blockIdx.y selects the weight; 32x32 LDS tiles, coalesced read and write.
__global__ __launch_bounds__(256)
void packT_kernel(const float* __restrict__ wk, const float* __restrict__ wv,
                  const float* __restrict__ wq, const float* __restrict__ fcw,
                  const float* __restrict__ m1w, const float* __restrict__ m2w,
                  bf16* __restrict__ WKVT, bf16* __restrict__ WQT, bf16* __restrict__ FCWT,
                  bf16* __restrict__ M1WT, bf16* __restrict__ M2WT) {
    __shared__ float tile[32][33];
    const float* src; bf16* dst; int K, C, LD, off;
    switch (blockIdx.y) {
        case 0:  src = wk;  K = 516; C = 516; dst = WKVT; LD = 576; off = 0;   break;
        case 1:  src = wv;  K = 516; C = 516; dst = WKVT; LD = 576; off = 520; break;
        case 2:  src = wq;  K = 172; C = 516; dst = WQT;  LD = 192; off = 0;   break;
        case 3:  src = fcw; K = 516; C = 516; dst = FCWT; LD = 576; off = 0;   break;
        case 4:  src = m1w; K = 688; C = 172; dst = M1WT; LD = 704; off = 0;   break;
        default: src = m2w; K = 172; C = 172; dst = M2WT; LD = 192; off = 0;   break;
    }
    const int tilesC = (C + 31) >> 5;
    const int tilesK = (K + 31) >> 5;
    const int nt = tilesC * tilesK;
    const int tx = threadIdx.x & 31, ty = threadIdx.x >> 5;
    for (int tb = blockIdx.x; tb < nt; tb += gridDim.x) {
        int tc = tb % tilesC, tk = tb / tilesC;
        #pragma unroll
        for (int i = 0; i < 4; ++i) {
            int k = tk*32 + ty + i*8, c = tc*32 + tx;
            tile[ty + i*8][tx] = (k < K && c < C) ? src[(size_t)k*C + c] : 0.f;
        }
        __syncthreads();
        #pragma unroll
        for (int i = 0; i < 4; ++i) {
            int c = tc*32 + ty + i*8, k = tk*32 + tx;
            if (c < C && k < K)
                dst[(size_t)(c + off)*LD + k] = (bf16)tile[tx][ty + i*8];
        }
        __syncthreads();
    }
}

// ---------------- nh16 pack + cph ----------------
__global__ void nh_pack_kernel(const float* __restrict__ node_h, const float* __restrict__ phase,
                               bf16* __restrict__ nh16, float* __restrict__ cph) {
    constexpr int S6 = NN * 192;
    constexpr int S7 = S6 + 172;
    for (int idx = blockIdx.x * blockDim.x + threadIdx.x; idx < S7;
         idx += gridDim.x * blockDim.x) {
        if (idx < S6) {
            int i = idx / 192, c = idx % 192;
            nh16[idx] = (c < 172) ? (bf16)node_h[(size_t)i*172 + c] : (bf16)0.f;
        } else {
            int j = idx - S6;
            cph[j] = cosf(phase[j]);
        }
    }
}

// q_bias[c] = sum_j cos(phase[j]) * w_q[(344+j)*516 + c] — one block per c, LDS reduce
__global__ __launch_bounds__(256)
void qbias_kernel(const float* __restrict__ w_q, const float* __restrict__ phase,
                  float* __restrict__ q_bias) {
    __shared__ float red[256];
    const int c = blockIdx.x, j = threadIdx.x;
    red[j] = (j < 172) ? cosf(phase[j]) * w_q[(size_t)(344 + j) * 516 + c] : 0.f;
    __syncthreads();
    #pragma unroll
    for (int o = 128; o; o >>= 1) {
        if (j < o) red[j] += red[j + o];
        __syncthreads();
    }
    if (j == 0) q_bias[c] = red[0];
}

// ---------------- per-chunk Z build: Z[ce][576] bf16 ----------------
__global__ __launch_bounds__(256)
void build_z_kernel(const bf16* __restrict__ nh16, const float* __restrict__ edge_feat,
                    const float* __restrict__ edge_t, const int* __restrict__ nbr_idx,
                    const float* __restrict__ freq, const float* __restrict__ ph,
                    const float* __restrict__ t_now_p,
                    bf16* __restrict__ Z, int ce, int edge_base) {
    int idx = blockIdx.x * blockDim.x + threadIdx.x;
    int total = ce * 72;
    if (idx >= total) return;
    int row = idx / 72, c = idx % 72;
    int k0 = c * 8;
    int eg = edge_base + row;
    bf16x8 v;
    if (c < 21) {
        v = *(const bf16x8*)(nh16 + (size_t)nbr_idx[eg] * 192 + k0);
    } else if (c == 21) {
        int src = nbr_idx[eg];
        #pragma unroll
        for (int e = 0; e < 8; ++e) {
            int k = 168 + e;
            v[e] = (k < 172) ? nh16[(size_t)src * 192 + k]
                             : (bf16)edge_feat[(size_t)eg * 172 + (k - 172)];
        }
    } else if (c < 43) {
        const float* ep = edge_feat + (size_t)eg * 172 + (k0 - 172);
        f32x4 a = *(const f32x4*)ep;
        f32x4 b = *(const f32x4*)(ep + 4);
        #pragma unroll
        for (int e = 0; e < 4; ++e) { v[e] = (bf16)a[e]; v[e+4] = (bf16)b[e]; }
    } else if (c < 64) {
        float dt = t_now_p[0] - edge_t[eg];
        #pragma unroll
        for (int e = 0; e < 8; ++e) {
            int j = k0 - 344 + e;
            v[e] = (bf16)cosf(dt * freq[j] + ph[j]);
        }
    } else if (c == 64) {
        float dt = t_now_p[0] - edge_t[eg];
        #pragma unroll
        for (int e = 0; e < 8; ++e) {
            int k = 512 + e;
            v[e] = (k < 516) ? (bf16)cosf(dt * freq[k - 344] + ph[k - 344]) : (bf16)0.f;
        }
    } else {
        #pragma unroll
        for (int e = 0; e < 8; ++e) v[e] = (bf16)0.f;
    }
    *(bf16x8*)(Z + (size_t)row * 576 + k0) = v;
}

// ---------------- MFMA GEMM, DMA staging + 2-phase dbuf; N on blockIdx.x, M on blockIdx.y ----------------
// MODE 0: KV  (K=576, out bf16 [1056])      MODE 1: Q  (K=192, out f32 +qbias)
// MODE 2: FC  (K=576, out f32 +b +self_z)   MODE 3: M1 (K=704, out bf16 relu)
// MODE 4: M2  (K=192, out f32 +b, N=172)
template<int MODE>
__global__ __launch_bounds__(256, 2)
void gemm_kernel(const bf16* __restrict__ A, const bf16* __restrict__ Bt,
                 float* __restrict__ outF, bf16* __restrict__ outB,
                 const float* __restrict__ bias,
                 const float* __restrict__ aux0,   // mode2: node_h
                 const float* __restrict__ aux1,   // mode2: cph
                 int Mreal) {
    constexpr int KP = (MODE==0 || MODE==2) ? 576 : (MODE==3 ? 704 : 192);
    constexpr int NT = KP / BK;

    __shared__ __align__(16) bf16 As[2][BM][BK];   // 32 KB
    __shared__ __align__(16) bf16 Bs[2][BN][BK];   // 44 KB

    const int tid  = threadIdx.x;
    const int w    = tid >> 6;
    const int lane = tid & 63;
    const int lr   = lane & 15;
    const int ls   = lane >> 4;

    // DMA lane mapping: one instr covers 8 rows x 64 cols; lane l -> row l/8, col (l%8)*8
    const int lrow = lane >> 3;
    const int lcol = (lane & 7) * 8;

    const bf16* aBase = A  + (size_t)(blockIdx.y * BM + w * 32 + lrow) * KP + lcol;
    const bf16* bBase = Bt + (size_t)(blockIdx.x * BN + lrow) * KP + lcol;

    auto stage = [&](int buf, int k0) {
        #pragma unroll
        for (int i = 0; i < 4; ++i)
            gload16(aBase + (size_t)(i * 8) * KP + k0, &As[buf][w * 32 + i * 8][0]);
        #pragma unroll
        for (int jj = 0; jj < 6; ++jj) {
            int j = jj * 4 + w;                  // wave-uniform
            if (j < 22)
                gload16(bBase + (size_t)(j * 8) * KP + k0, &Bs[buf][j * 8][0]);
        }
    };

    f32x4 acc[2][11];
    #pragma unroll
    for (int a = 0; a < 2; ++a)
        #pragma unroll
        for (int b2 = 0; b2 < 11; ++b2) acc[a][b2] = (f32x4)(0.0f);

    stage(0, 0);
    __syncthreads();                              // drains vmcnt for buf0
    int cur = 0;
    for (int t = 0; t < NT; ++t) {
        if (t + 1 < NT) stage(cur ^ 1, (t + 1) * BK);   // DMA flies under MFMA
        #pragma unroll
        for (int kk = 0; kk < 2; ++kk) {
            bf16x8 a0 = *(const bf16x8*)&As[cur][w*32 +      lr][kk*32 + ls*8];
            bf16x8 a1 = *(const bf16x8*)&As[cur][w*32 + 16 + lr][kk*32 + ls*8];
            #pragma unroll
            for (int nt = 0; nt < 11; ++nt) {
                bf16x8 bfr = *(const bf16x8*)&Bs[cur][nt*16 + lr][kk*32 + ls*8];
                acc[0][nt] = __builtin_amdgcn_mfma_f32_16x16x32_bf16(a0, bfr, acc[0][nt], 0, 0, 0);
                acc[1][nt] = __builtin_amdgcn_mfma_f32_16x16x32_bf16(a1, bfr, acc[1][nt], 0, 0, 0);
            }
        }
        __syncthreads();                          // next-tile DMA landed + readers done
        cur ^= 1;
    }

    // ---- epilogue ----
    const int colb = blockIdx.x * BN + lr;
    const int rowb = blockIdx.y * BM + w*32 + ls*4;
    #pragma unroll
    for (int mt = 0; mt < 2; ++mt)
    #pragma unroll
    for (int nt = 0; nt < 11; ++nt)
    #pragma unroll
    for (int q2 = 0; q2 < 4; ++q2) {
        int row = rowb + mt*16 + q2;
        int col = colb + nt*16;
        if (row >= Mreal) continue;
        float v = acc[mt][nt][q2];
        if constexpr (MODE == 0) {
            outB[(size_t)row*1056 + col] = (bf16)v;
        } else if constexpr (MODE == 1) {
            if (col < 516) outF[(size_t)row*516 + col] = v + bias[col];
        } else if constexpr (MODE == 2) {
            if (col < 516) {
                float sz = (col < 172) ? aux0[(size_t)row*172 + col]
                                       : ((col < 344) ? 0.f : aux1[col - 344]);
                outF[(size_t)row*516 + col] = v + bias[col] + sz;
            }
        } else if constexpr (MODE == 3) {
            float vv = 0.f;
            if (col < 172) vv = fmaxf(v + bias[col], 0.f);
            outB[(size_t)row*192 + col] = (bf16)vv;   // cols 172..175 zeroed
        } else {
            if (col < 172) outF[(size_t)row*172 + col] = v + bias[col];
        }
    }
}

// ---------------- attention (torch permute/view pair-mixing), bf16x2 vectorized ----------------
__global__ __launch_bounds__(256)
void attn_kernel(const float* __restrict__ q, const bf16* __restrict__ KV,
                 bf16* __restrict__ att, int node_base) {
    __shared__ float qs[2][516];
    __shared__ float lg[2][20];
    __shared__ float pp[2][20];
    const int r2 = blockIdx.x;
    const int iA = node_base + 2*r2;
    const int t  = threadIdx.x;

    for (int idx = t; idx < 1032; idx += 256) {
        int nn2 = idx / 516, c = idx % 516;
        qs[nn2][c] = q[(size_t)(iA + nn2)*516 + c];
    }
    __syncthreads();

    const int w = t >> 6, lane = t & 63;
    const int h = w >> 1;
    for (int kq = 0; kq < 10; ++kq) {
        int knbr = (w & 1)*10 + kq;
        int src = knbr / 10, e = knbr % 10;
        size_t rbase = ((size_t)(2*r2 + src))*20 + 2*e;
        const bf16* k0p = KV + rbase*1056 + h*258;
        const bf16* k1p = KV + (rbase + 1)*1056 + h*258;
        float acc = 0.f;
        for (int j2 = lane; j2 < 129; j2 += 64) {       // pairs: 129*2 = 258
            bf16x2 ka = *(const bf16x2*)(k0p + 2*j2);
            bf16x2 kb = *(const bf16x2*)(k1p + 2*j2);
            int jj = h*258 + 2*j2;
            acc += qs[0][jj]*(float)ka[0] + qs[0][jj+1]*(float)ka[1]
                 + qs[1][jj]*(float)kb[0] + qs[1][jj+1]*(float)kb[1];
        }
        #pragma unroll
        for (int o = 32; o; o >>= 1) acc += __shfl_down(acc, o);
        if (lane == 0) lg[h][knbr] = acc * 0.0622573006f;     // 1/sqrt(258)
    }
    __syncthreads();
    if (t < 2) {
        int hh = t;
        float m = -1e30f;
        for (int k2 = 0; k2 < 20; ++k2) m = fmaxf(m, lg[hh][k2]);
        float ssum = 0.f;
        float ex[20];
        #pragma unroll
        for (int k2 = 0; k2 < 20; ++k2) { ex[k2] = expf(lg[hh][k2] - m); ssum += ex[k2]; }
        float inv = 1.f / ssum;
        #pragma unroll
        for (int k2 = 0; k2 < 20; ++k2) pp[hh][k2] = ex[k2] * inv;
    }
    __syncthreads();
    // PV: 516 pair-tasks: combo = (hh,nsel) in 0..3 (129 pairs each)
    for (int idx = t; idx < 516; idx += 256) {
        int combo = idx / 129, j = (idx % 129) * 2;     // j = 0..256 (covers 258 elems)
        int hh = combo >> 1, nsel = combo & 1;
        float a0 = 0.f, a1 = 0.f;
        #pragma unroll
        for (int knbr = 0; knbr < 20; ++knbr) {
            int src = knbr / 10, e = knbr % 10;
            size_t erow = ((size_t)(2*r2 + src))*20 + 2*e + nsel;
            bf16x2 vv = *(const bf16x2*)(KV + erow*1056 + 520 + hh*258 + j);
            float p = pp[hh][knbr];
            a0 += p * (float)vv[0];
            a1 += p * (float)vv[1];
        }
        bf16x2 r; r[0] = (bf16)a0; r[1] = (bf16)a1;
        *(bf16x2*)(att + (size_t)(iA + nsel)*576 + hh*258 + j) = r;
    }
    // zero K-pad cols 516..575 so FC GEMM K-tail is exact
    for (int o = t; o < 120; o += 256) {
        int nsel = o / 60, c = 516 + (o % 60);
        att[(size_t)(iA + nsel)*576 + c] = (bf16)0.f;
    }
}

// ---------------- LayerNorm + build X = [h_ln, node_h, 0pad] ----------------
__global__ __launch_bounds__(256)
void ln_x_kernel(const float* __restrict__ fcr, const float* __restrict__ g,
                 const float* __restrict__ b, const bf16* __restrict__ nh16,
                 bf16* __restrict__ X) {
    __shared__ float red[2][4];
    __shared__ float mb[2];
    const size_t i = blockIdx.x;
    const int t = threadIdx.x;
    int c0 = t, c1 = t + 256, c2 = t + 512;
    float v0 = fcr[i*516 + c0];
    float v1 = (c1 < 516) ? fcr[i*516 + c1] : 0.f;
    float v2 = (c2 < 516) ? fcr[i*516 + c2] : 0.f;
    float s = v0 + v1 + v2, ss = v0*v0 + v1*v1 + v2*v2;
    #pragma unroll
    for (int o = 32; o; o >>= 1) { s += __shfl_down(s, o); ss += __shfl_down(ss, o); }
    if ((t & 63) == 0) { red[0][t >> 6] = s; red[1][t >> 6] = ss; }
    __syncthreads();
    if (t == 0) {
        float S  = red[0][0] + red[0][1] + red[0][2] + red[0][3];
        float SS = red[1][0] + red[1][1] + red[1][2] + red[1][3];
        float mean = S / 516.f;
        float var  = SS / 516.f - mean*mean;
        mb[0] = mean; mb[1] = rsqrtf(var + 1e-5f);
    }
    __syncthreads();
    float mean = mb[0], rstd = mb[1];
    X[i*704 + c0] = (bf16)((v0 - mean)*rstd*g[c0] + b[c0]);
    if (c1 < 516) X[i*704 + c1] = (bf16)((v1 - mean)*rstd*g[c1] + b[c1]);
    if (c2 < 516) X[i*704 + c2] = (bf16)((v2 - mean)*rstd*g[c2] + b[c2]);
    for (int c = 516 + t; c < 704; c += 256)
        X[i*704 + c] = (c < 688) ? nh16[i*192 + (c - 516)] : (bf16)0.f;
}

// ---------------- launch ----------------
extern "C" void kernel_launch(void* const* d_in, const int* in_sizes, int n_in,
                              void* d_out, int out_size, void* d_ws, size_t ws_size,
                              hipStream_t stream) {
    const float* node_h     = (const float*)d_in[0];
    const float* edge_t     = (const float*)d_in[1];
    const float* edge_feat  = (const float*)d_in[2];
    const int*   nbr_idx    = (const int*)d_in[3];
    const float* t_now      = (const float*)d_in[4];
    const float* w_q        = (const float*)d_in[6];
    const float* w_k        = (const float*)d_in[7];
    const float* w_v        = (const float*)d_in[8];
    const float* basis_freq = (const float*)d_in[9];
    const float* phase      = (const float*)d_in[10];
    const float* ln_g       = (const float*)d_in[11];
    const float* ln_b       = (const float*)d_in[12];
    const float* fc_w       = (const float*)d_in[13];
    const float* fc_b       = (const float*)d_in[14];
    const float* m1_w       = (const float*)d_in[15];
    const float* m1_b       = (const float*)d_in[16];
    const float* m2_w       = (const float*)d_in[17];
    const float* m2_b       = (const float*)d_in[18];

    char* ws = (char*)d_ws;
    bf16*  WKVT = (bf16*)(ws + WKVT_OFF);
    bf16*  FCWT = (bf16*)(ws + FCWT_OFF);
    bf16*  WQT  = (bf16*)(ws + WQT_OFF);
    bf16*  M1WT = (bf16*)(ws + M1WT_OFF);
    bf16*  M2WT = (bf16*)(ws + M2WT_OFF);
    float* QB   = (float*)(ws + QB_OFF);
    float* CPH  = (float*)(ws + CPH_OFF);
    bf16*  NH16 = (bf16*)(ws + NH16_OFF);
    float* Qb   = (float*)(ws + Q_OFF);
    bf16*  ATTb = (bf16*)(ws + ATT_OFF);
    float* FCR  = (float*)(ws + FCR_OFF);
    bf16*  Xb   = (bf16*)(ws + X_OFF);
    bf16*  Rb   = (bf16*)(ws + R_OFF);

    // adaptive chunk: overlay holds Z (rounded to 128 rows) + KV for CN nodes
    int CN = 2;
    const int cands[14] = {2500, 2000, 1250, 1000, 625, 500, 250, 200, 125, 100, 50, 20, 10, 2};
    for (int ci = 0; ci < 14; ++ci) {
        size_t ce = (size_t)cands[ci] * DEG;
        size_t zrows = (ce + 127) & ~(size_t)127;
        size_t need = zrows * 576 * 2 + ce * 1056 * 2;
        size_t ovl = need > OVERLAY_MIN ? need : OVERLAY_MIN;
        if (OVL_OFF + ovl <= ws_size) { CN = cands[ci]; break; }
    }
    const size_t ce_sz = (size_t)CN * DEG;
    const size_t zrows = (ce_sz + 127) & ~(size_t)127;
    bf16* Zb = (bf16*)(ws + OVL_OFF);
    bf16* KV = (bf16*)(ws + OVL_OFF + zrows * 576 * 2);

    hipMemsetAsync(ws, 0, NH16_OFF, stream);

    packT_kernel<<<dim3(289, 6), 256, 0, stream>>>(w_k, w_v, w_q, fc_w, m1_w, m2_w,
                                                   WKVT, WQT, FCWT, M1WT, M2WT);
    nh_pack_kernel<<<2048, 256, 0, stream>>>(node_h, phase, NH16, CPH);
    qbias_kernel<<<516, 256, 0, stream>>>(w_q, QB ? phase : phase, QB);

    // q = node_h @ w_q[0:172] + q_bias
    gemm_kernel<1><<<dim3(3, 79), 256, 0, stream>>>(
        NH16, WQT, Qb, nullptr, QB, nullptr, nullptr, NN);

    // chunked: build Z -> KV GEMM -> attention
    const int ce = CN * DEG;
    for (int cb = 0; cb < NN; cb += CN) {
        build_z_kernel<<<(ce * 72 + 255) / 256, 256, 0, stream>>>(
            NH16, edge_feat, edge_t, nbr_idx, basis_freq, phase, t_now,
            Zb, ce, cb * DEG);
        gemm_kernel<0><<<dim3(6, (ce + BM - 1) / BM), 256, 0, stream>>>(
            Zb, WKVT, nullptr, KV, nullptr, nullptr, nullptr, ce);
        attn_kernel<<<CN / 2, 256, 0, stream>>>(Qb, KV, ATTb, cb);
    }

    // fc + bias + self_z residual
    gemm_kernel<2><<<dim3(3, 79), 256, 0, stream>>>(
        ATTb, FCWT, FCR, nullptr, fc_b, node_h, CPH, NN);

    ln_x_kernel<<<NN, 256, 0, stream>>>(FCR, ln_g, ln_b, NH16, Xb);

    // m1 + relu
    gemm_kernel<3><<<dim3(1, 79), 256, 0, stream>>>(
        Xb, M1WT, nullptr, Rb, m1_b, nullptr, nullptr, NN);

    // m2 -> out
    gemm_kernel<4><<<dim3(1, 79), 256, 0, stream>>>(
        Rb, M2WT, (float*)d_out, nullptr, m2_b, nullptr, nullptr, NN);
}

// Round 6
// 472.991 us; speedup vs baseline: 5.6599x; 1.9896x over previous
//
#include <hip/hip_runtime.h>
#include <hip/hip_bf16.h>
#include <math.h>

typedef __bf16 bf16;
typedef __attribute__((ext_vector_type(8))) __bf16 bf16x8;
typedef __attribute__((ext_vector_type(4))) float f32x4;

// ---------------- problem constants ----------------
constexpr int NN   = 10000;
constexpr int NPAD = 10112;            // 128-aligned (DMA overrun pad)
constexpr int BM = 128, BN = 176, BK = 64;

// ---------------- workspace layout (bytes) ----------------
constexpr size_t FCWT_OFF = 0;                         // bf16 [528][576]   fcw^T (zero-padded)
constexpr size_t M1WT_OFF = 608256;                    // bf16 [176][704]
constexpr size_t M2WT_OFF = 856064;                    // bf16 [176][192]
constexpr size_t WKH_OFF  = 923648;                    // bf16 [2*576][320] wk head-slices
constexpr size_t WQHT_OFF = 1660928;                   // bf16 [2*352][320] wq head-slices (rows<172)
constexpr size_t WVH_OFF  = 2111488;                   // bf16 [2*704][320] wv head-slices
constexpr size_t WQKT_OFF = 3012608;                   // bf16 [1232][192]  WQK^T (qk GEMM B)
constexpr size_t WVFT_OFF = 3485696;                   // bf16 [528][1152]  WVF^T (fusedFC B)
constexpr size_t QB_OFF   = 4702208;                   // f32 [516]
constexpr size_t QKB_OFF  = 4706304;                   // f32 [1232]
constexpr size_t CPH_OFF  = 4714496;                   // f32 [172]
constexpr size_t NH16_OFF = 4715520;                   // bf16 [NPAD][192]
constexpr size_t QK_OFF   = NH16_OFF + (size_t)NPAD*192*2;    // bf16 [NPAD][1152]
constexpr size_t ZB_OFF   = QK_OFF   + (size_t)NPAD*1152*2;   // bf16 [NPAD][1152]
constexpr size_t FCR_OFF  = ZB_OFF   + (size_t)NPAD*1152*2;   // f32 [NN][516]
constexpr size_t X_OFF    = FCR_OFF  + (size_t)NN*516*4;      // bf16 [NPAD][704]
constexpr size_t R_OFF    = X_OFF    + (size_t)NPAD*704*2;    // bf16 [NPAD][192]

// ---------------- global_load_lds helper (width 16) ----------------
typedef __attribute__((address_space(3))) void lds_void;
typedef const __attribute__((address_space(1))) void glb_void;
__device__ __forceinline__ void gload16(const void* g, void* l) {
    __builtin_amdgcn_global_load_lds((glb_void*)(uintptr_t)g,
                                     (lds_void*)(unsigned int)(uintptr_t)l, 16, 0, 0);
}

// ---------------- tiled transpose-pack (fcw, m1w, m2w) ----------------
__global__ __launch_bounds__(256)
void packT_kernel(const float* __restrict__ fcw, const float* __restrict__ m1w,
                  const float* __restrict__ m2w,
                  bf16* __restrict__ FCWT, bf16* __restrict__ M1WT, bf16* __restrict__ M2WT) {
    __shared__ float tile[32][33];
    const float* src; bf16* dst; int K, C, LD;
    switch (blockIdx.y) {
        case 0:  src = fcw; K = 516; C = 516; dst = FCWT; LD = 576; break;
        case 1:  src = m1w; K = 688; C = 172; dst = M1WT; LD = 704; break;
        default: src = m2w; K = 172; C = 172; dst = M2WT; LD = 192; break;
    }
    const int tilesC = (C + 31) >> 5, tilesK = (K + 31) >> 5;
    const int nt = tilesC * tilesK;
    const int tx = threadIdx.x & 31, ty = threadIdx.x >> 5;
    for (int tb = blockIdx.x; tb < nt; tb += gridDim.x) {
        int tc = tb % tilesC, tk = tb / tilesC;
        #pragma unroll
        for (int i = 0; i < 4; ++i) {
            int k = tk*32 + ty + i*8, c = tc*32 + tx;
            tile[ty + i*8][tx] = (k < K && c < C) ? src[(size_t)k*C + c] : 0.f;
        }
        __syncthreads();
        #pragma unroll
        for (int i = 0; i < 4; ++i) {
            int c = tc*32 + ty + i*8, k = tk*32 + tx;
            if (c < C && k < K) dst[(size_t)c*LD + k] = (bf16)tile[tx][ty + i*8];
        }
        __syncthreads();
    }
}

// ---------------- head-slice packs (no transpose) ----------------
__global__ void slice_pack_kernel(const float* __restrict__ wk, const float* __restrict__ wq,
                                  const float* __restrict__ wv,
                                  bf16* __restrict__ WKH, bf16* __restrict__ WQHT,
                                  bf16* __restrict__ WVH) {
    constexpr int T0 = 2*516*258;
    constexpr int T1 = T0 + 2*172*258;
    constexpr int T2 = T1 + 2*516*258;
    for (int idx = blockIdx.x * blockDim.x + threadIdx.x; idx < T2;
         idx += gridDim.x * blockDim.x) {
        if (idx < T0) {
            int h = idx / (516*258), rem = idx % (516*258), d = rem / 258, j = rem % 258;
            WKH[((size_t)h*576 + d)*320 + j] = (bf16)wk[(size_t)d*516 + h*258 + j];
        } else if (idx < T1) {
            int i = idx - T0;
            int h = i / (172*258), rem = i % (172*258), k = rem / 258, j = rem % 258;
            WQHT[((size_t)h*352 + k)*320 + j] = (bf16)wq[(size_t)k*516 + h*258 + j];
        } else {
            int i = idx - T1;
            int h = i / (516*258), rem = i % (516*258), c = rem / 258, j = rem % 258;
            WVH[((size_t)h*704 + c)*320 + j] = (bf16)wv[(size_t)c*516 + h*258 + j];
        }
    }
}

// ---------------- nh16 pack + cph ----------------
__global__ void nh_pack_kernel(const float* __restrict__ node_h, const float* __restrict__ phase,
                               bf16* __restrict__ nh16, float* __restrict__ cph) {
    constexpr int S6 = NN * 192;
    constexpr int S7 = S6 + 172;
    for (int idx = blockIdx.x * blockDim.x + threadIdx.x; idx < S7;
         idx += gridDim.x * blockDim.x) {
        if (idx < S6) {
            int i = idx / 192, c = idx % 192;
            nh16[idx] = (c < 172) ? (bf16)node_h[(size_t)i*172 + c] : (bf16)0.f;
        } else cph[idx - S6] = cosf(phase[idx - S6]);
    }
}

// QB[c] = sum_j cos(phase[j]) * w_q[(344+j)*516 + c]
__global__ __launch_bounds__(256)
void qbias_kernel(const float* __restrict__ w_q, const float* __restrict__ phase,
                  float* __restrict__ q_bias) {
    __shared__ float red[256];
    const int c = blockIdx.x, j = threadIdx.x;
    red[j] = (j < 172) ? cosf(phase[j]) * w_q[(size_t)(344 + j) * 516 + c] : 0.f;
    __syncthreads();
    #pragma unroll
    for (int o = 128; o; o >>= 1) { if (j < o) red[j] += red[j + o]; __syncthreads(); }
    if (j == 0) q_bias[c] = red[0];
}

// qkb[h*576+d] = sum_{j<258} QB[h*258+j] * wk[d][h*258+j]   (d<516, else 0)
__global__ __launch_bounds__(256)
void qkb_kernel(const float* __restrict__ wk, const float* __restrict__ QB,
                float* __restrict__ qkb) {
    __shared__ float red[256];
    const int hd = blockIdx.x, h = hd / 576, d = hd % 576, t = threadIdx.x;
    float a = 0.f;
    if (d < 516) {
        a = QB[h*258 + t] * wk[(size_t)d*516 + h*258 + t];
        if (t < 2) a += QB[h*258 + 256 + t] * wk[(size_t)d*516 + h*258 + 256 + t];
    }
    red[t] = a; __syncthreads();
    #pragma unroll
    for (int o = 128; o; o >>= 1) { if (t < o) red[t] += red[t + o]; __syncthreads(); }
    if (t == 0) qkb[hd] = red[0];
}

// ---------------- MFMA GEMM (DMA staging + 2-phase dbuf), runtime lda/ldo ----------------
// EPI 0: bf16 out, +bias            EPI 1: bf16 out plain
// EPI 2: f32 out, +bias +selfz      EPI 3: bf16 relu(+bias), zero past Nreal
// EPI 4: f32 out, +bias
template<int KP, int EPI>
__global__ __launch_bounds__(256, 2)
void gemm_kernel(const bf16* __restrict__ A, int lda, const bf16* __restrict__ Bt,
                 float* __restrict__ outF, bf16* __restrict__ outB, int ldo,
                 const float* __restrict__ bias,
                 const float* __restrict__ aux0, const float* __restrict__ aux1,
                 int Mreal, int Nreal) {
    constexpr int NT = KP / BK;
    __shared__ __align__(16) bf16 As[2][BM][BK];
    __shared__ __align__(16) bf16 Bs[2][BN][BK];

    const int tid  = threadIdx.x;
    const int w    = tid >> 6;
    const int lane = tid & 63;
    const int lr   = lane & 15;
    const int ls   = lane >> 4;
    const int lrow = lane >> 3;
    const int lcol = (lane & 7) * 8;

    const bf16* aBase = A  + (size_t)(blockIdx.y * BM + w * 32 + lrow) * lda + lcol;
    const bf16* bBase = Bt + (size_t)(blockIdx.x * BN + lrow) * KP + lcol;

    auto stage = [&](int buf, int k0) {
        #pragma unroll
        for (int i = 0; i < 4; ++i)
            gload16(aBase + (size_t)(i * 8) * lda + k0, &As[buf][w * 32 + i * 8][0]);
        #pragma unroll
        for (int jj = 0; jj < 6; ++jj) {
            int j = jj * 4 + w;
            if (j < 22) gload16(bBase + (size_t)(j * 8) * KP + k0, &Bs[buf][j * 8][0]);
        }
    };

    f32x4 acc[2][11];
    #pragma unroll
    for (int a = 0; a < 2; ++a)
        #pragma unroll
        for (int b2 = 0; b2 < 11; ++b2) acc[a][b2] = (f32x4)(0.0f);

    stage(0, 0);
    __syncthreads();
    int cur = 0;
    for (int t = 0; t < NT; ++t) {
        if (t + 1 < NT) stage(cur ^ 1, (t + 1) * BK);
        #pragma unroll
        for (int kk = 0; kk < 2; ++kk) {
            bf16x8 a0 = *(const bf16x8*)&As[cur][w*32 +      lr][kk*32 + ls*8];
            bf16x8 a1 = *(const bf16x8*)&As[cur][w*32 + 16 + lr][kk*32 + ls*8];
            #pragma unroll
            for (int nt = 0; nt < 11; ++nt) {
                bf16x8 bfr = *(const bf16x8*)&Bs[cur][nt*16 + lr][kk*32 + ls*8];
                acc[0][nt] = __builtin_amdgcn_mfma_f32_16x16x32_bf16(a0, bfr, acc[0][nt], 0, 0, 0);
                acc[1][nt] = __builtin_amdgcn_mfma_f32_16x16x32_bf16(a1, bfr, acc[1][nt], 0, 0, 0);
            }
        }
        __syncthreads();
        cur ^= 1;
    }

    const int colb = blockIdx.x * BN + lr;
    const int rowb = blockIdx.y * BM + w*32 + ls*4;
    #pragma unroll
    for (int mt = 0; mt < 2; ++mt)
    #pragma unroll
    for (int nt = 0; nt < 11; ++nt)
    #pragma unroll
    for (int q2 = 0; q2 < 4; ++q2) {
        int row = rowb + mt*16 + q2;
        int col = colb + nt*16;
        if (row >= Mreal) continue;
        float v = acc[mt][nt][q2];
        if constexpr (EPI == 0) {
            if (col < Nreal) outB[(size_t)row*ldo + col] = (bf16)(v + bias[col]);
        } else if constexpr (EPI == 1) {
            if (col < Nreal) outB[(size_t)row*ldo + col] = (bf16)v;
        } else if constexpr (EPI == 2) {
            if (col < Nreal) {
                float sz = (col < 172) ? aux0[(size_t)row*172 + col]
                                       : ((col < 344) ? 0.f : aux1[col - 344]);
                outF[(size_t)row*ldo + col] = v + bias[col] + sz;
            }
        } else if constexpr (EPI == 3) {
            float vv = (col < Nreal) ? fmaxf(v + bias[col], 0.f) : 0.f;
            outB[(size_t)row*ldo + col] = (bf16)vv;
        } else {
            if (col < Nreal) outF[(size_t)row*ldo + col] = v + bias[col];
        }
    }
}

// ---------------- attention-lite: z in LDS, logits via qk·z, ZB = softmax-weighted z ----------------
__global__ __launch_bounds__(256)
void attn_lite_kernel(const bf16* __restrict__ QK, const bf16* __restrict__ nh16,
                      const float* __restrict__ edge_feat, const float* __restrict__ edge_t,
                      const int* __restrict__ nbr_idx, const float* __restrict__ freq,
                      const float* __restrict__ ph, const float* __restrict__ tnow,
                      bf16* __restrict__ ZB) {
    __shared__ bf16  zs[40][576];
    __shared__ bf16  qks[2][1152];
    __shared__ float sfreq[172], sph[172];
    __shared__ float sdt[40];
    __shared__ int   ssrc[40];
    __shared__ float lg[2][20], pp[2][20];

    const int r  = blockIdx.x;
    const int iA = 2 * r;
    const int t  = threadIdx.x;

    if (t < 172) { sfreq[t] = freq[t]; sph[t] = ph[t]; }
    if (t >= 192 && t < 232) {
        int e2 = t - 192;
        int ge = iA * 20 + e2;                 // 40 contiguous global edge rows
        sdt[e2]  = tnow[0] - edge_t[ge];
        ssrc[e2] = nbr_idx[ge];
    }
    __syncthreads();

    // build z rows in LDS (same bf16 rounding points as before)
    for (int idx = t; idx < 40 * 72; idx += 256) {
        int row = idx / 72, c = idx % 72;
        int k0 = c * 8;
        int ge = iA * 20 + row;
        bf16x8 v;
        if (c < 21) {
            v = *(const bf16x8*)(nh16 + (size_t)ssrc[row] * 192 + k0);
        } else if (c == 21) {
            #pragma unroll
            for (int e = 0; e < 8; ++e) {
                int k = 168 + e;
                v[e] = (k < 172) ? nh16[(size_t)ssrc[row] * 192 + k]
                                 : (bf16)edge_feat[(size_t)ge * 172 + (k - 172)];
            }
        } else if (c < 43) {
            const float* ep = edge_feat + (size_t)ge * 172 + (k0 - 172);
            f32x4 a = *(const f32x4*)ep;
            f32x4 b = *(const f32x4*)(ep + 4);
            #pragma unroll
            for (int e = 0; e < 4; ++e) { v[e] = (bf16)a[e]; v[e+4] = (bf16)b[e]; }
        } else if (c < 64) {
            float dt = sdt[row];
            #pragma unroll
            for (int e = 0; e < 8; ++e) {
                int j = k0 - 344 + e;
                v[e] = (bf16)cosf(dt * sfreq[j] + sph[j]);
            }
        } else if (c == 64) {
            float dt = sdt[row];
            #pragma unroll
            for (int e = 0; e < 8; ++e) {
                int k = 512 + e;
                v[e] = (k < 516) ? (bf16)cosf(dt * sfreq[k - 344] + sph[k - 344]) : (bf16)0.f;
            }
        } else {
            #pragma unroll
            for (int e = 0; e < 8; ++e) v[e] = (bf16)0.f;
        }
        *(bf16x8*)&zs[row][k0] = v;
    }
    // load qk rows for both nodes
    for (int idx = t; idx < 2 * 144; idx += 256) {
        int a = idx / 144, g = idx % 144;
        *(bf16x8*)&qks[a][g * 8] = *(const bf16x8*)(QK + (size_t)(iA + a) * 1152 + g * 8);
    }
    __syncthreads();

    // logits: 40 tasks (h,knbr), 10 per wave; lanes split the 2x576 dot
    const int w = t >> 6, lane = t & 63;
    for (int q = 0; q < 10; ++q) {
        int tt = w * 10 + q;
        int h = tt / 20, knbr = tt % 20;
        int src = knbr / 10, e = knbr % 10;
        int z0 = src * 20 + 2 * e;
        float acc = 0.f;
        #pragma unroll
        for (int i = 0; i < 9; ++i) {
            int d = lane + i * 64;
            acc += (float)qks[0][h*576 + d] * (float)zs[z0][d]
                 + (float)qks[1][h*576 + d] * (float)zs[z0 + 1][d];
        }
        #pragma unroll
        for (int o = 32; o; o >>= 1) acc += __shfl_down(acc, o);
        if (lane == 0) lg[h][knbr] = acc * 0.0622573006f;   // 1/sqrt(258)
    }
    __syncthreads();
    if (t < 2) {
        float m = -1e30f;
        for (int k2 = 0; k2 < 20; ++k2) m = fmaxf(m, lg[t][k2]);
        float ssum = 0.f, ex[20];
        #pragma unroll
        for (int k2 = 0; k2 < 20; ++k2) { ex[k2] = expf(lg[t][k2] - m); ssum += ex[k2]; }
        float inv = 1.f / ssum;
        #pragma unroll
        for (int k2 = 0; k2 < 20; ++k2) pp[t][k2] = ex[k2] * inv;
    }
    __syncthreads();

    // ZB[iA+nsel][hh*576+c] = sum_knbr pp[hh][knbr] * z[src*20+2e+nsel][c]
    for (int idx = t; idx < 2304; idx += 256) {
        int nsel = idx / 1152, rem = idx % 1152;
        int hh = rem / 576, c = rem % 576;
        float acc = 0.f;
        #pragma unroll
        for (int knbr = 0; knbr < 20; ++knbr) {
            int src = knbr / 10, e = knbr % 10;
            acc += pp[hh][knbr] * (float)zs[src*20 + 2*e + nsel][c];
        }
        ZB[(size_t)(iA + nsel) * 1152 + rem] = (bf16)acc;
    }
}

// ---------------- LayerNorm + build X = [h_ln, node_h, 0pad] ----------------
__global__ __launch_bounds__(256)
void ln_x_kernel(const float* __restrict__ fcr, const float* __restrict__ g,
                 const float* __restrict__ b, const bf16* __restrict__ nh16,
                 bf16* __restrict__ X) {
    __shared__ float red[2][4];
    __shared__ float mb[2];
    const size_t i = blockIdx.x;
    const int t = threadIdx.x;
    int c0 = t, c1 = t + 256, c2 = t + 512;
    float v0 = fcr[i*516 + c0];
    float v1 = (c1 < 516) ? fcr[i*516 + c1] : 0.f;
    float v2 = (c2 < 516) ? fcr[i*516 + c2] : 0.f;
    float s = v0 + v1 + v2, ss = v0*v0 + v1*v1 + v2*v2;
    #pragma unroll
    for (int o = 32; o; o >>= 1) { s += __shfl_down(s, o); ss += __shfl_down(ss, o); }
    if ((t & 63) == 0) { red[0][t >> 6] = s; red[1][t >> 6] = ss; }
    __syncthreads();
    if (t == 0) {
        float S  = red[0][0] + red[0][1] + red[0][2] + red[0][3];
        float SS = red[1][0] + red[1][1] + red[1][2] + red[1][3];
        float mean = S / 516.f;
        float var  = SS / 516.f - mean*mean;
        mb[0] = mean; mb[1] = rsqrtf(var + 1e-5f);
    }
    __syncthreads();
    float mean = mb[0], rstd = mb[1];
    X[i*704 + c0] = (bf16)((v0 - mean)*rstd*g[c0] + b[c0]);
    if (c1 < 516) X[i*704 + c1] = (bf16)((v1 - mean)*rstd*g[c1] + b[c1]);
    if (c2 < 516) X[i*704 + c2] = (bf16)((v2 - mean)*rstd*g[c2] + b[c2]);
    for (int c = 516 + t; c < 704; c += 256)
        X[i*704 + c] = (c < 688) ? nh16[i*192 + (c - 516)] : (bf16)0.f;
}

// ---------------- launch ----------------
extern "C" void kernel_launch(void* const* d_in, const int* in_sizes, int n_in,
                              void* d_out, int out_size, void* d_ws, size_t ws_size,
                              hipStream_t stream) {
    const float* node_h     = (const float*)d_in[0];
    const float* edge_t     = (const float*)d_in[1];
    const float* edge_feat  = (const float*)d_in[2];
    const int*   nbr_idx    = (const int*)d_in[3];
    const float* t_now      = (const float*)d_in[4];
    const float* w_q        = (const float*)d_in[6];
    const float* w_k        = (const float*)d_in[7];
    const float* w_v        = (const float*)d_in[8];
    const float* basis_freq = (const float*)d_in[9];
    const float* phase      = (const float*)d_in[10];
    const float* ln_g       = (const float*)d_in[11];
    const float* ln_b       = (const float*)d_in[12];
    const float* fc_w       = (const float*)d_in[13];
    const float* fc_b       = (const float*)d_in[14];
    const float* m1_w       = (const float*)d_in[15];
    const float* m1_b       = (const float*)d_in[16];
    const float* m2_w       = (const float*)d_in[17];
    const float* m2_b       = (const float*)d_in[18];

    char* ws = (char*)d_ws;
    bf16*  FCWT = (bf16*)(ws + FCWT_OFF);
    bf16*  M1WT = (bf16*)(ws + M1WT_OFF);
    bf16*  M2WT = (bf16*)(ws + M2WT_OFF);
    bf16*  WKH  = (bf16*)(ws + WKH_OFF);
    bf16*  WQHT = (bf16*)(ws + WQHT_OFF);
    bf16*  WVH  = (bf16*)(ws + WVH_OFF);
    bf16*  WQKT = (bf16*)(ws + WQKT_OFF);
    bf16*  WVFT = (bf16*)(ws + WVFT_OFF);
    float* QB   = (float*)(ws + QB_OFF);
    float* QKB  = (float*)(ws + QKB_OFF);
    float* CPH  = (float*)(ws + CPH_OFF);
    bf16*  NH16 = (bf16*)(ws + NH16_OFF);
    bf16*  QK   = (bf16*)(ws + QK_OFF);
    bf16*  ZB   = (bf16*)(ws + ZB_OFF);
    float* FCR  = (float*)(ws + FCR_OFF);
    bf16*  Xb   = (bf16*)(ws + X_OFF);
    bf16*  Rb   = (bf16*)(ws + R_OFF);

    // zero all weight-derived buffers (padding correctness)
    hipMemsetAsync(ws, 0, NH16_OFF, stream);

    packT_kernel<<<dim3(289, 3), 256, 0, stream>>>(fc_w, m1_w, m2_w, FCWT, M1WT, M2WT);
    slice_pack_kernel<<<1024, 256, 0, stream>>>(w_k, w_q, w_v, WKH, WQHT, WVH);
    nh_pack_kernel<<<2048, 256, 0, stream>>>(node_h, phase, NH16, CPH);
    qbias_kernel<<<516, 256, 0, stream>>>(w_q, phase, QB);
    qkb_kernel<<<1152, 256, 0, stream>>>(w_k, QB, QKB);

    // WQK^T[h*576+d][k] = sum_j wq[k][hs+j] wk[d][hs+j]
    for (int h = 0; h < 2; ++h)
        gemm_kernel<320, 1><<<dim3(2, 5), 256, 0, stream>>>(
            WKH + (size_t)h*576*320, 320, WQHT + (size_t)h*352*320,
            nullptr, WQKT + (size_t)h*576*192, 192,
            nullptr, nullptr, nullptr, 576, 192);

    // qk = NH16 @ WQK^T + qkb   -> QK [NPAD][1152]
    gemm_kernel<192, 0><<<dim3(7, 79), 256, 0, stream>>>(
        NH16, 192, WQKT, nullptr, QK, 1152, QKB, nullptr, nullptr, NN, 1152);

    // WVF^T[o][h*576+c] = sum_j fcw[hs+j][o] wv[c][hs+j]
    for (int h = 0; h < 2; ++h)
        gemm_kernel<320, 1><<<dim3(4, 5), 256, 0, stream>>>(
            FCWT + (size_t)h*258, 576, WVH + (size_t)h*704*320,
            nullptr, WVFT + (size_t)h*576, 1152,
            nullptr, nullptr, nullptr, 516, 576);

    // attention (z built in LDS, never materialized) -> ZB [NPAD][1152]
    attn_lite_kernel<<<NN / 2, 256, 0, stream>>>(
        QK, NH16, edge_feat, edge_t, nbr_idx, basis_freq, phase, t_now, ZB);

    // fcr = ZB @ WVF^T + fc_b + self_z
    gemm_kernel<1152, 2><<<dim3(3, 79), 256, 0, stream>>>(
        ZB, 1152, WVFT, FCR, nullptr, 516, fc_b, node_h, CPH, NN, 516);

    ln_x_kernel<<<NN, 256, 0, stream>>>(FCR, ln_g, ln_b, NH16, Xb);

    // m1 + relu
    gemm_kernel<704, 3><<<dim3(1, 79), 256, 0, stream>>>(
        Xb, 704, M1WT, nullptr, Rb, 192, m1_b, nullptr, nullptr, NN, 172);

    // m2 -> out
    gemm_kernel<192, 4><<<dim3(1, 79), 256, 0, stream>>>(
        Rb, 192, M2WT, (float*)d_out, nullptr, 172, m2_b, nullptr, nullptr, NN, 172);
}

// Round 7
// 382.560 us; speedup vs baseline: 6.9978x; 1.2364x over previous
//
#include <hip/hip_runtime.h>
#include <hip/hip_bf16.h>
#include <math.h>

typedef __bf16 bf16;
typedef __attribute__((ext_vector_type(8))) __bf16 bf16x8;
typedef __attribute__((ext_vector_type(4))) float f32x4;

// ---------------- problem constants ----------------
constexpr int NN   = 10000;
constexpr int NPAD = 10112;            // 128-aligned (DMA overrun pad)
constexpr int BM = 128, BN = 176, BK = 64;

// ---------------- workspace layout (bytes) ----------------
constexpr size_t FCWT_OFF = 0;                         // bf16 [528][576]   fcw^T (zero-padded)
constexpr size_t M1WT_OFF = 608256;                    // bf16 [176][704]
constexpr size_t M2WT_OFF = 856064;                    // bf16 [176][192]
constexpr size_t WKH_OFF  = 923648;                    // bf16 [2*576][320] wk head-slices
constexpr size_t WQHT_OFF = 1660928;                   // bf16 [2*352][320] wq head-slices (rows<172)
constexpr size_t WVH_OFF  = 2111488;                   // bf16 [2*704][320] wv head-slices
constexpr size_t WQKT_OFF = 3012608;                   // bf16 [1232][192]  WQK^T (qk GEMM B)
constexpr size_t WVFT_OFF = 3485696;                   // bf16 [528][1152]  WVF^T (fusedFC B)
constexpr size_t QB_OFF   = 4702208;                   // f32 [516]
constexpr size_t QKB_OFF  = 4706304;                   // f32 [1232]
constexpr size_t CPH_OFF  = 4714496;                   // f32 [172]
constexpr size_t NH16_OFF = 4715520;                   // bf16 [NPAD][192]
constexpr size_t QK_OFF   = NH16_OFF + (size_t)NPAD*192*2;    // bf16 [NPAD][1152]
constexpr size_t ZB_OFF   = QK_OFF   + (size_t)NPAD*1152*2;   // bf16 [NPAD][1152]
constexpr size_t FCR_OFF  = ZB_OFF   + (size_t)NPAD*1152*2;   // f32 [NN][516]
constexpr size_t X_OFF    = FCR_OFF  + (size_t)NN*516*4;      // bf16 [NPAD][704]
constexpr size_t R_OFF    = X_OFF    + (size_t)NPAD*704*2;    // bf16 [NPAD][192]

// ---------------- global_load_lds helper (width 16) ----------------
typedef __attribute__((address_space(3))) void lds_void;
typedef const __attribute__((address_space(1))) void glb_void;
__device__ __forceinline__ void gload16(const void* g, void* l) {
    __builtin_amdgcn_global_load_lds((glb_void*)(uintptr_t)g,
                                     (lds_void*)(unsigned int)(uintptr_t)l, 16, 0, 0);
}

// ---------------- tiled transpose-pack (fcw, m1w, m2w) ----------------
__global__ __launch_bounds__(256)
void packT_kernel(const float* __restrict__ fcw, const float* __restrict__ m1w,
                  const float* __restrict__ m2w,
                  bf16* __restrict__ FCWT, bf16* __restrict__ M1WT, bf16* __restrict__ M2WT) {
    __shared__ float tile[32][33];
    const float* src; bf16* dst; int K, C, LD;
    switch (blockIdx.y) {
        case 0:  src = fcw; K = 516; C = 516; dst = FCWT; LD = 576; break;
        case 1:  src = m1w; K = 688; C = 172; dst = M1WT; LD = 704; break;
        default: src = m2w; K = 172; C = 172; dst = M2WT; LD = 192; break;
    }
    const int tilesC = (C + 31) >> 5, tilesK = (K + 31) >> 5;
    const int nt = tilesC * tilesK;
    const int tx = threadIdx.x & 31, ty = threadIdx.x >> 5;
    for (int tb = blockIdx.x; tb < nt; tb += gridDim.x) {
        int tc = tb % tilesC, tk = tb / tilesC;
        #pragma unroll
        for (int i = 0; i < 4; ++i) {
            int k = tk*32 + ty + i*8, c = tc*32 + tx;
            tile[ty + i*8][tx] = (k < K && c < C) ? src[(size_t)k*C + c] : 0.f;
        }
        __syncthreads();
        #pragma unroll
        for (int i = 0; i < 4; ++i) {
            int c = tc*32 + ty + i*8, k = tk*32 + tx;
            if (c < C && k < K) dst[(size_t)c*LD + k] = (bf16)tile[tx][ty + i*8];
        }
        __syncthreads();
    }
}

// ---------------- head-slice packs (no transpose) ----------------
__global__ void slice_pack_kernel(const float* __restrict__ wk, const float* __restrict__ wq,
                                  const float* __restrict__ wv,
                                  bf16* __restrict__ WKH, bf16* __restrict__ WQHT,
                                  bf16* __restrict__ WVH) {
    constexpr int T0 = 2*516*258;
    constexpr int T1 = T0 + 2*172*258;
    constexpr int T2 = T1 + 2*516*258;
    for (int idx = blockIdx.x * blockDim.x + threadIdx.x; idx < T2;
         idx += gridDim.x * blockDim.x) {
        if (idx < T0) {
            int h = idx / (516*258), rem = idx % (516*258), d = rem / 258, j = rem % 258;
            WKH[((size_t)h*576 + d)*320 + j] = (bf16)wk[(size_t)d*516 + h*258 + j];
        } else if (idx < T1) {
            int i = idx - T0;
            int h = i / (172*258), rem = i % (172*258), k = rem / 258, j = rem % 258;
            WQHT[((size_t)h*352 + k)*320 + j] = (bf16)wq[(size_t)k*516 + h*258 + j];
        } else {
            int i = idx - T1;
            int h = i / (516*258), rem = i % (516*258), c = rem / 258, j = rem % 258;
            WVH[((size_t)h*704 + c)*320 + j] = (bf16)wv[(size_t)c*516 + h*258 + j];
        }
    }
}

// ---------------- nh16 pack + cph ----------------
__global__ void nh_pack_kernel(const float* __restrict__ node_h, const float* __restrict__ phase,
                               bf16* __restrict__ nh16, float* __restrict__ cph) {
    constexpr int S6 = NN * 192;
    constexpr int S7 = S6 + 172;
    for (int idx = blockIdx.x * blockDim.x + threadIdx.x; idx < S7;
         idx += gridDim.x * blockDim.x) {
        if (idx < S6) {
            int i = idx / 192, c = idx % 192;
            nh16[idx] = (c < 172) ? (bf16)node_h[(size_t)i*172 + c] : (bf16)0.f;
        } else cph[idx - S6] = cosf(phase[idx - S6]);
    }
}

// QB[c] = sum_j cos(phase[j]) * w_q[(344+j)*516 + c]
__global__ __launch_bounds__(256)
void qbias_kernel(const float* __restrict__ w_q, const float* __restrict__ phase,
                  float* __restrict__ q_bias) {
    __shared__ float red[256];
    const int c = blockIdx.x, j = threadIdx.x;
    red[j] = (j < 172) ? cosf(phase[j]) * w_q[(size_t)(344 + j) * 516 + c] : 0.f;
    __syncthreads();
    #pragma unroll
    for (int o = 128; o; o >>= 1) { if (j < o) red[j] += red[j + o]; __syncthreads(); }
    if (j == 0) q_bias[c] = red[0];
}

// qkb[h*576+d] = sum_{j<258} QB[h*258+j] * wk[d][h*258+j]   (d<516, else 0)
__global__ __launch_bounds__(256)
void qkb_kernel(const float* __restrict__ wk, const float* __restrict__ QB,
                float* __restrict__ qkb) {
    __shared__ float red[256];
    const int hd = blockIdx.x, h = hd / 576, d = hd % 576, t = threadIdx.x;
    float a = 0.f;
    if (d < 516) {
        a = QB[h*258 + t] * wk[(size_t)d*516 + h*258 + t];
        if (t < 2) a += QB[h*258 + 256 + t] * wk[(size_t)d*516 + h*258 + 256 + t];
    }
    red[t] = a; __syncthreads();
    #pragma unroll
    for (int o = 128; o; o >>= 1) { if (t < o) red[t] += red[t + o]; __syncthreads(); }
    if (t == 0) qkb[hd] = red[0];
}

// ---------------- MFMA GEMM (DMA staging + 2-phase dbuf), runtime lda/ldo ----------------
template<int KP, int EPI>
__global__ __launch_bounds__(256, 2)
void gemm_kernel(const bf16* __restrict__ A, int lda, const bf16* __restrict__ Bt,
                 float* __restrict__ outF, bf16* __restrict__ outB, int ldo,
                 const float* __restrict__ bias,
                 const float* __restrict__ aux0, const float* __restrict__ aux1,
                 int Mreal, int Nreal) {
    constexpr int NT = KP / BK;
    __shared__ __align__(16) bf16 As[2][BM][BK];
    __shared__ __align__(16) bf16 Bs[2][BN][BK];

    const int tid  = threadIdx.x;
    const int w    = tid >> 6;
    const int lane = tid & 63;
    const int lr   = lane & 15;
    const int ls   = lane >> 4;
    const int lrow = lane >> 3;
    const int lcol = (lane & 7) * 8;

    const bf16* aBase = A  + (size_t)(blockIdx.y * BM + w * 32 + lrow) * lda + lcol;
    const bf16* bBase = Bt + (size_t)(blockIdx.x * BN + lrow) * KP + lcol;

    auto stage = [&](int buf, int k0) {
        #pragma unroll
        for (int i = 0; i < 4; ++i)
            gload16(aBase + (size_t)(i * 8) * lda + k0, &As[buf][w * 32 + i * 8][0]);
        #pragma unroll
        for (int jj = 0; jj < 6; ++jj) {
            int j = jj * 4 + w;
            if (j < 22) gload16(bBase + (size_t)(j * 8) * KP + k0, &Bs[buf][j * 8][0]);
        }
    };

    f32x4 acc[2][11];
    #pragma unroll
    for (int a = 0; a < 2; ++a)
        #pragma unroll
        for (int b2 = 0; b2 < 11; ++b2) acc[a][b2] = (f32x4)(0.0f);

    stage(0, 0);
    __syncthreads();
    int cur = 0;
    for (int t = 0; t < NT; ++t) {
        if (t + 1 < NT) stage(cur ^ 1, (t + 1) * BK);
        #pragma unroll
        for (int kk = 0; kk < 2; ++kk) {
            bf16x8 a0 = *(const bf16x8*)&As[cur][w*32 +      lr][kk*32 + ls*8];
            bf16x8 a1 = *(const bf16x8*)&As[cur][w*32 + 16 + lr][kk*32 + ls*8];
            #pragma unroll
            for (int nt = 0; nt < 11; ++nt) {
                bf16x8 bfr = *(const bf16x8*)&Bs[cur][nt*16 + lr][kk*32 + ls*8];
                acc[0][nt] = __builtin_amdgcn_mfma_f32_16x16x32_bf16(a0, bfr, acc[0][nt], 0, 0, 0);
                acc[1][nt] = __builtin_amdgcn_mfma_f32_16x16x32_bf16(a1, bfr, acc[1][nt], 0, 0, 0);
            }
        }
        __syncthreads();
        cur ^= 1;
    }

    const int colb = blockIdx.x * BN + lr;
    const int rowb = blockIdx.y * BM + w*32 + ls*4;
    #pragma unroll
    for (int mt = 0; mt < 2; ++mt)
    #pragma unroll
    for (int nt = 0; nt < 11; ++nt)
    #pragma unroll
    for (int q2 = 0; q2 < 4; ++q2) {
        int row = rowb + mt*16 + q2;
        int col = colb + nt*16;
        if (row >= Mreal) continue;
        float v = acc[mt][nt][q2];
        if constexpr (EPI == 0) {
            if (col < Nreal) outB[(size_t)row*ldo + col] = (bf16)(v + bias[col]);
        } else if constexpr (EPI == 1) {
            if (col < Nreal) outB[(size_t)row*ldo + col] = (bf16)v;
        } else if constexpr (EPI == 2) {
            if (col < Nreal) {
                float sz = (col < 172) ? aux0[(size_t)row*172 + col]
                                       : ((col < 344) ? 0.f : aux1[col - 344]);
                outF[(size_t)row*ldo + col] = v + bias[col] + sz;
            }
        } else if constexpr (EPI == 3) {
            float vv = (col < Nreal) ? fmaxf(v + bias[col], 0.f) : 0.f;
            outB[(size_t)row*ldo + col] = (bf16)vv;
        } else {
            if (col < Nreal) outF[(size_t)row*ldo + col] = v + bias[col];
        }
    }
}

// ---------------- attention-lite v2: vectorized LDS, reg-resident qk, fast cos ----------------
__global__ __launch_bounds__(256, 3)
void attn_lite_kernel(const bf16* __restrict__ QK, const bf16* __restrict__ nh16,
                      const float* __restrict__ edge_feat, const float* __restrict__ edge_t,
                      const int* __restrict__ nbr_idx, const float* __restrict__ freq,
                      const float* __restrict__ ph, const float* __restrict__ tnow,
                      bf16* __restrict__ ZB) {
    __shared__ bf16  zs[40][576];
    __shared__ float sfreq[172], sph[172];
    __shared__ float sdt[40];
    __shared__ int   ssrc[40];
    __shared__ float lg[2][20], pp[2][20];

    const int r  = blockIdx.x;
    const int iA = 2 * r;
    const int t  = threadIdx.x;
    const int w  = t >> 6, lane = t & 63;
    const int h  = w >> 1;                       // wave-uniform head

    if (t < 172) { sfreq[t] = freq[t]; sph[t] = ph[t]; }
    if (t >= 192 && t < 232) {
        int e2 = t - 192;
        int ge = iA * 20 + e2;
        sdt[e2]  = tnow[0] - edge_t[ge];
        ssrc[e2] = nbr_idx[ge];
    }

    // per-wave qk rows (this wave's head), f32 in statically-indexed regs
    float qa0[8], qa1[8], qt0[8], qt1[8];
    {
        bf16x8 v0 = *(const bf16x8*)(QK + (size_t)iA * 1152 + h * 576 + lane * 8);
        bf16x8 v1 = *(const bf16x8*)(QK + (size_t)(iA + 1) * 1152 + h * 576 + lane * 8);
        #pragma unroll
        for (int i = 0; i < 8; ++i) { qa0[i] = (float)v0[i]; qa1[i] = (float)v1[i]; }
        if (lane >= 56) {
            int d1 = 512 + (lane - 56) * 8;
            bf16x8 u0 = *(const bf16x8*)(QK + (size_t)iA * 1152 + h * 576 + d1);
            bf16x8 u1 = *(const bf16x8*)(QK + (size_t)(iA + 1) * 1152 + h * 576 + d1);
            #pragma unroll
            for (int i = 0; i < 8; ++i) { qt0[i] = (float)u0[i]; qt1[i] = (float)u1[i]; }
        } else {
            #pragma unroll
            for (int i = 0; i < 8; ++i) { qt0[i] = 0.f; qt1[i] = 0.f; }
        }
    }
    __syncthreads();

    // build z rows in LDS (same bf16 rounding points; fast cos)
    for (int idx = t; idx < 40 * 72; idx += 256) {
        int row = idx / 72, c = idx % 72;
        int k0 = c * 8;
        int ge = iA * 20 + row;
        bf16x8 v;
        if (c < 21) {
            v = *(const bf16x8*)(nh16 + (size_t)ssrc[row] * 192 + k0);
        } else if (c == 21) {
            #pragma unroll
            for (int e = 0; e < 8; ++e) {
                int k = 168 + e;
                v[e] = (k < 172) ? nh16[(size_t)ssrc[row] * 192 + k]
                                 : (bf16)edge_feat[(size_t)ge * 172 + (k - 172)];
            }
        } else if (c < 43) {
            const float* ep = edge_feat + (size_t)ge * 172 + (k0 - 172);
            f32x4 a = *(const f32x4*)ep;
            f32x4 b = *(const f32x4*)(ep + 4);
            #pragma unroll
            for (int e = 0; e < 4; ++e) { v[e] = (bf16)a[e]; v[e+4] = (bf16)b[e]; }
        } else if (c < 64) {
            float dt = sdt[row];
            #pragma unroll
            for (int e = 0; e < 8; ++e) {
                int j = k0 - 344 + e;
                v[e] = (bf16)__cosf(dt * sfreq[j] + sph[j]);
            }
        } else if (c == 64) {
            float dt = sdt[row];
            #pragma unroll
            for (int e = 0; e < 8; ++e) {
                int k = 512 + e;
                v[e] = (k < 516) ? (bf16)__cosf(dt * sfreq[k - 344] + sph[k - 344]) : (bf16)0.f;
            }
        } else {
            #pragma unroll
            for (int e = 0; e < 8; ++e) v[e] = (bf16)0.f;
        }
        *(bf16x8*)&zs[row][k0] = v;
    }
    __syncthreads();

    // logits: per wave 10 tasks (my head h, knbr = (w&1)*10+q), vector z reads
    #pragma unroll
    for (int q = 0; q < 10; ++q) {
        const int knbr = (w & 1) * 10 + q;
        const int src = knbr / 10, e = knbr % 10;
        const int z0 = src * 20 + 2 * e;
        float acc = 0.f;
        bf16x8 za = *(const bf16x8*)&zs[z0][lane * 8];
        bf16x8 zb = *(const bf16x8*)&zs[z0 + 1][lane * 8];
        #pragma unroll
        for (int i = 0; i < 8; ++i)
            acc += qa0[i] * (float)za[i] + qa1[i] * (float)zb[i];
        if (lane >= 56) {
            int d1 = 512 + (lane - 56) * 8;
            bf16x8 zc = *(const bf16x8*)&zs[z0][d1];
            bf16x8 zd = *(const bf16x8*)&zs[z0 + 1][d1];
            #pragma unroll
            for (int i = 0; i < 8; ++i)
                acc += qt0[i] * (float)zc[i] + qt1[i] * (float)zd[i];
        }
        #pragma unroll
        for (int o = 32; o; o >>= 1) acc += __shfl_down(acc, o);
        if (lane == 0) lg[h][knbr] = acc * 0.0622573006f;   // 1/sqrt(258)
    }
    __syncthreads();
    if (t < 2) {
        float m = -1e30f;
        for (int k2 = 0; k2 < 20; ++k2) m = fmaxf(m, lg[t][k2]);
        float ssum = 0.f, ex[20];
        #pragma unroll
        for (int k2 = 0; k2 < 20; ++k2) { ex[k2] = expf(lg[t][k2] - m); ssum += ex[k2]; }
        float inv = 1.f / ssum;
        #pragma unroll
        for (int k2 = 0; k2 < 20; ++k2) pp[t][k2] = ex[k2] * inv;
    }
    __syncthreads();

    // ZB: 288 8-wide tasks; all lanes read the same z-row contiguously (conflict-free)
    for (int idx = t; idx < 288; idx += 256) {
        int nsel = idx / 144, rem = idx % 144;
        int hh = rem / 72, c8 = rem % 72;
        float a[8] = {0.f, 0.f, 0.f, 0.f, 0.f, 0.f, 0.f, 0.f};
        #pragma unroll
        for (int knbr = 0; knbr < 20; ++knbr) {
            int src = knbr / 10, e = knbr % 10;
            bf16x8 zv = *(const bf16x8*)&zs[src*20 + 2*e + nsel][c8 * 8];
            float p = pp[hh][knbr];
            #pragma unroll
            for (int i = 0; i < 8; ++i) a[i] += p * (float)zv[i];
        }
        bf16x8 o;
        #pragma unroll
        for (int i = 0; i < 8; ++i) o[i] = (bf16)a[i];
        *(bf16x8*)(ZB + (size_t)(iA + nsel) * 1152 + hh * 576 + c8 * 8) = o;
    }
}

// ---------------- LayerNorm + build X = [h_ln, node_h, 0pad] ----------------
__global__ __launch_bounds__(256)
void ln_x_kernel(const float* __restrict__ fcr, const float* __restrict__ g,
                 const float* __restrict__ b, const bf16* __restrict__ nh16,
                 bf16* __restrict__ X) {
    __shared__ float red[2][4];
    __shared__ float mb[2];
    const size_t i = blockIdx.x;
    const int t = threadIdx.x;
    int c0 = t, c1 = t + 256, c2 = t + 512;
    float v0 = fcr[i*516 + c0];
    float v1 = (c1 < 516) ? fcr[i*516 + c1] : 0.f;
    float v2 = (c2 < 516) ? fcr[i*516 + c2] : 0.f;
    float s = v0 + v1 + v2, ss = v0*v0 + v1*v1 + v2*v2;
    #pragma unroll
    for (int o = 32; o; o >>= 1) { s += __shfl_down(s, o); ss += __shfl_down(ss, o); }
    if ((t & 63) == 0) { red[0][t >> 6] = s; red[1][t >> 6] = ss; }
    __syncthreads();
    if (t == 0) {
        float S  = red[0][0] + red[0][1] + red[0][2] + red[0][3];
        float SS = red[1][0] + red[1][1] + red[1][2] + red[1][3];
        float mean = S / 516.f;
        float var  = SS / 516.f - mean*mean;
        mb[0] = mean; mb[1] = rsqrtf(var + 1e-5f);
    }
    __syncthreads();
    float mean = mb[0], rstd = mb[1];
    X[i*704 + c0] = (bf16)((v0 - mean)*rstd*g[c0] + b[c0]);
    if (c1 < 516) X[i*704 + c1] = (bf16)((v1 - mean)*rstd*g[c1] + b[c1]);
    if (c2 < 516) X[i*704 + c2] = (bf16)((v2 - mean)*rstd*g[c2] + b[c2]);
    for (int c = 516 + t; c < 704; c += 256)
        X[i*704 + c] = (c < 688) ? nh16[i*192 + (c - 516)] : (bf16)0.f;
}

// ---------------- launch ----------------
extern "C" void kernel_launch(void* const* d_in, const int* in_sizes, int n_in,
                              void* d_out, int out_size, void* d_ws, size_t ws_size,
                              hipStream_t stream) {
    const float* node_h     = (const float*)d_in[0];
    const float* edge_t     = (const float*)d_in[1];
    const float* edge_feat  = (const float*)d_in[2];
    const int*   nbr_idx    = (const int*)d_in[3];
    const float* t_now      = (const float*)d_in[4];
    const float* w_q        = (const float*)d_in[6];
    const float* w_k        = (const float*)d_in[7];
    const float* w_v        = (const float*)d_in[8];
    const float* basis_freq = (const float*)d_in[9];
    const float* phase      = (const float*)d_in[10];
    const float* ln_g       = (const float*)d_in[11];
    const float* ln_b       = (const float*)d_in[12];
    const float* fc_w       = (const float*)d_in[13];
    const float* fc_b       = (const float*)d_in[14];
    const float* m1_w       = (const float*)d_in[15];
    const float* m1_b       = (const float*)d_in[16];
    const float* m2_w       = (const float*)d_in[17];
    const float* m2_b       = (const float*)d_in[18];

    char* ws = (char*)d_ws;
    bf16*  FCWT = (bf16*)(ws + FCWT_OFF);
    bf16*  M1WT = (bf16*)(ws + M1WT_OFF);
    bf16*  M2WT = (bf16*)(ws + M2WT_OFF);
    bf16*  WKH  = (bf16*)(ws + WKH_OFF);
    bf16*  WQHT = (bf16*)(ws + WQHT_OFF);
    bf16*  WVH  = (bf16*)(ws + WVH_OFF);
    bf16*  WQKT = (bf16*)(ws + WQKT_OFF);
    bf16*  WVFT = (bf16*)(ws + WVFT_OFF);
    float* QB   = (float*)(ws + QB_OFF);
    float* QKB  = (float*)(ws + QKB_OFF);
    float* CPH  = (float*)(ws + CPH_OFF);
    bf16*  NH16 = (bf16*)(ws + NH16_OFF);
    bf16*  QK   = (bf16*)(ws + QK_OFF);
    bf16*  ZB   = (bf16*)(ws + ZB_OFF);
    float* FCR  = (float*)(ws + FCR_OFF);
    bf16*  Xb   = (bf16*)(ws + X_OFF);
    bf16*  Rb   = (bf16*)(ws + R_OFF);

    // zero all weight-derived buffers (padding correctness)
    hipMemsetAsync(ws, 0, NH16_OFF, stream);

    packT_kernel<<<dim3(289, 3), 256, 0, stream>>>(fc_w, m1_w, m2_w, FCWT, M1WT, M2WT);
    slice_pack_kernel<<<1024, 256, 0, stream>>>(w_k, w_q, w_v, WKH, WQHT, WVH);
    nh_pack_kernel<<<2048, 256, 0, stream>>>(node_h, phase, NH16, CPH);
    qbias_kernel<<<516, 256, 0, stream>>>(w_q, phase, QB);
    qkb_kernel<<<1152, 256, 0, stream>>>(w_k, QB, QKB);

    // WQK^T[h*576+d][k] = sum_j wq[k][hs+j] wk[d][hs+j]
    for (int h = 0; h < 2; ++h)
        gemm_kernel<320, 1><<<dim3(2, 5), 256, 0, stream>>>(
            WKH + (size_t)h*576*320, 320, WQHT + (size_t)h*352*320,
            nullptr, WQKT + (size_t)h*576*192, 192,
            nullptr, nullptr, nullptr, 576, 192);

    // qk = NH16 @ WQK^T + qkb   -> QK [NPAD][1152]
    gemm_kernel<192, 0><<<dim3(7, 79), 256, 0, stream>>>(
        NH16, 192, WQKT, nullptr, QK, 1152, QKB, nullptr, nullptr, NN, 1152);

    // WVF^T[o][h*576+c] = sum_j fcw[hs+j][o] wv[c][hs+j]
    for (int h = 0; h < 2; ++h)
        gemm_kernel<320, 1><<<dim3(4, 5), 256, 0, stream>>>(
            FCWT + (size_t)h*258, 576, WVH + (size_t)h*704*320,
            nullptr, WVFT + (size_t)h*576, 1152,
            nullptr, nullptr, nullptr, 516, 576);

    // attention (z built in LDS, never materialized) -> ZB [NPAD][1152]
    attn_lite_kernel<<<NN / 2, 256, 0, stream>>>(
        QK, NH16, edge_feat, edge_t, nbr_idx, basis_freq, phase, t_now, ZB);

    // fcr = ZB @ WVF^T + fc_b + self_z
    gemm_kernel<1152, 2><<<dim3(3, 79), 256, 0, stream>>>(
        ZB, 1152, WVFT, FCR, nullptr, 516, fc_b, node_h, CPH, NN, 516);

    ln_x_kernel<<<NN, 256, 0, stream>>>(FCR, ln_g, ln_b, NH16, Xb);

    // m1 + relu
    gemm_kernel<704, 3><<<dim3(1, 79), 256, 0, stream>>>(
        Xb, 704, M1WT, nullptr, Rb, 192, m1_b, nullptr, nullptr, NN, 172);

    // m2 -> out
    gemm_kernel<192, 4><<<dim3(1, 79), 256, 0, stream>>>(
        Rb, 192, M2WT, (float*)d_out, nullptr, 172, m2_b, nullptr, nullptr, NN, 172);
}

// Round 8
// 307.593 us; speedup vs baseline: 8.7033x; 1.2437x over previous
//
#include <hip/hip_runtime.h>
#include <hip/hip_bf16.h>
#include <math.h>

typedef __bf16 bf16;
typedef __attribute__((ext_vector_type(8))) __bf16 bf16x8;
typedef __attribute__((ext_vector_type(4))) float f32x4;

// ---------------- problem constants ----------------
constexpr int NN   = 10000;
constexpr int NPAD = 10112;            // 128-aligned (DMA overrun pad)
constexpr int BM = 128, BN = 176, BK = 64;

// ---------------- workspace layout (bytes) ----------------
constexpr size_t FCWT_OFF = 0;                         // bf16 [528][576]   fcw^T (zero-padded)
constexpr size_t M1WT_OFF = 608256;                    // bf16 [176][704]
constexpr size_t M2WT_OFF = 856064;                    // bf16 [176][192]
constexpr size_t WKH_OFF  = 923648;                    // bf16 [2*576][320] wk head-slices
constexpr size_t WQHT_OFF = 1660928;                   // bf16 [2*352][320] wq head-slices (rows<172)
constexpr size_t WVH_OFF  = 2111488;                   // bf16 [2*704][320] wv head-slices
constexpr size_t WQKT_OFF = 3012608;                   // bf16 [1232][192]  WQK^T (qk GEMM B)
constexpr size_t WVFT_OFF = 3485696;                   // bf16 [528][1152]  WVF^T (fusedFC B)
constexpr size_t QB_OFF   = 4702208;                   // f32 [516]
constexpr size_t QKB_OFF  = 4706304;                   // f32 [1232]
constexpr size_t CPH_OFF  = 4714496;                   // f32 [172]
constexpr size_t NH16_OFF = 4715520;                   // bf16 [NPAD][192]
constexpr size_t QK_OFF   = NH16_OFF + (size_t)NPAD*192*2;    // bf16 [NPAD][1152]
constexpr size_t ZB_OFF   = QK_OFF   + (size_t)NPAD*1152*2;   // bf16 [NPAD][1152]
constexpr size_t FCR_OFF  = ZB_OFF   + (size_t)NPAD*1152*2;   // f32 [NN][516]
constexpr size_t X_OFF    = FCR_OFF  + (size_t)NN*516*4;      // bf16 [NPAD][704]

// ---------------- global_load_lds helper (width 16) ----------------
typedef __attribute__((address_space(3))) void lds_void;
typedef const __attribute__((address_space(1))) void glb_void;
__device__ __forceinline__ void gload16(const void* g, void* l) {
    __builtin_amdgcn_global_load_lds((glb_void*)(uintptr_t)g,
                                     (lds_void*)(unsigned int)(uintptr_t)l, 16, 0, 0);
}

// ---------------- tiled transpose-pack (fcw, m1w, m2w) ----------------
__global__ __launch_bounds__(256)
void packT_kernel(const float* __restrict__ fcw, const float* __restrict__ m1w,
                  const float* __restrict__ m2w,
                  bf16* __restrict__ FCWT, bf16* __restrict__ M1WT, bf16* __restrict__ M2WT) {
    __shared__ float tile[32][33];
    const float* src; bf16* dst; int K, C, LD;
    switch (blockIdx.y) {
        case 0:  src = fcw; K = 516; C = 516; dst = FCWT; LD = 576; break;
        case 1:  src = m1w; K = 688; C = 172; dst = M1WT; LD = 704; break;
        default: src = m2w; K = 172; C = 172; dst = M2WT; LD = 192; break;
    }
    const int tilesC = (C + 31) >> 5, tilesK = (K + 31) >> 5;
    const int nt = tilesC * tilesK;
    const int tx = threadIdx.x & 31, ty = threadIdx.x >> 5;
    for (int tb = blockIdx.x; tb < nt; tb += gridDim.x) {
        int tc = tb % tilesC, tk = tb / tilesC;
        #pragma unroll
        for (int i = 0; i < 4; ++i) {
            int k = tk*32 + ty + i*8, c = tc*32 + tx;
            tile[ty + i*8][tx] = (k < K && c < C) ? src[(size_t)k*C + c] : 0.f;
        }
        __syncthreads();
        #pragma unroll
        for (int i = 0; i < 4; ++i) {
            int c = tc*32 + ty + i*8, k = tk*32 + tx;
            if (c < C && k < K) dst[(size_t)c*LD + k] = (bf16)tile[tx][ty + i*8];
        }
        __syncthreads();
    }
}

// ---------------- fused misc packs: wk/wq/wv head-slices + nh16 + cph ----------------
__global__ void pack_misc_kernel(const float* __restrict__ wk, const float* __restrict__ wq,
                                 const float* __restrict__ wv, const float* __restrict__ node_h,
                                 const float* __restrict__ phase,
                                 bf16* __restrict__ WKH, bf16* __restrict__ WQHT,
                                 bf16* __restrict__ WVH, bf16* __restrict__ nh16,
                                 float* __restrict__ cph) {
    constexpr int T0 = 2*516*258;
    constexpr int T1 = T0 + 2*172*258;
    constexpr int T2 = T1 + 2*516*258;
    constexpr int T3 = T2 + NN*192;
    constexpr int T4 = T3 + 172;
    for (int idx = blockIdx.x * blockDim.x + threadIdx.x; idx < T4;
         idx += gridDim.x * blockDim.x) {
        if (idx < T0) {
            int h = idx / (516*258), rem = idx % (516*258), d = rem / 258, j = rem % 258;
            WKH[((size_t)h*576 + d)*320 + j] = (bf16)wk[(size_t)d*516 + h*258 + j];
        } else if (idx < T1) {
            int i = idx - T0;
            int h = i / (172*258), rem = i % (172*258), k = rem / 258, j = rem % 258;
            WQHT[((size_t)h*352 + k)*320 + j] = (bf16)wq[(size_t)k*516 + h*258 + j];
        } else if (idx < T2) {
            int i = idx - T1;
            int h = i / (516*258), rem = i % (516*258), c = rem / 258, j = rem % 258;
            WVH[((size_t)h*704 + c)*320 + j] = (bf16)wv[(size_t)c*516 + h*258 + j];
        } else if (idx < T3) {
            int i = idx - T2, r = i / 192, c = i % 192;
            nh16[i] = (c < 172) ? (bf16)node_h[(size_t)r*172 + c] : (bf16)0.f;
        } else cph[idx - T3] = cosf(phase[idx - T3]);
    }
}

// QB[c] = sum_j cos(phase[j]) * w_q[(344+j)*516 + c]
__global__ __launch_bounds__(256)
void qbias_kernel(const float* __restrict__ w_q, const float* __restrict__ phase,
                  float* __restrict__ q_bias) {
    __shared__ float red[256];
    const int c = blockIdx.x, j = threadIdx.x;
    red[j] = (j < 172) ? cosf(phase[j]) * w_q[(size_t)(344 + j) * 516 + c] : 0.f;
    __syncthreads();
    #pragma unroll
    for (int o = 128; o; o >>= 1) { if (j < o) red[j] += red[j + o]; __syncthreads(); }
    if (j == 0) q_bias[c] = red[0];
}

// qkb[h*576+d] = sum_{j<258} QB[h*258+j] * wk[d][h*258+j]   (d<516, else 0)
__global__ __launch_bounds__(256)
void qkb_kernel(const float* __restrict__ wk, const float* __restrict__ QB,
                float* __restrict__ qkb) {
    __shared__ float red[256];
    const int hd = blockIdx.x, h = hd / 576, d = hd % 576, t = threadIdx.x;
    float a = 0.f;
    if (d < 516) {
        a = QB[h*258 + t] * wk[(size_t)d*516 + h*258 + t];
        if (t < 2) a += QB[h*258 + 256 + t] * wk[(size_t)d*516 + h*258 + 256 + t];
    }
    red[t] = a; __syncthreads();
    #pragma unroll
    for (int o = 128; o; o >>= 1) { if (t < o) red[t] += red[t + o]; __syncthreads(); }
    if (t == 0) qkb[hd] = red[0];
}

// ---------------- MFMA GEMM (DMA staging + 2-phase dbuf), runtime lda/ldo ----------------
// EPI 0: bf16 out +bias    EPI 2: f32 out +bias +selfz
template<int KP, int EPI>
__global__ __launch_bounds__(256, 2)
void gemm_kernel(const bf16* __restrict__ A, int lda, const bf16* __restrict__ Bt,
                 float* __restrict__ outF, bf16* __restrict__ outB, int ldo,
                 const float* __restrict__ bias,
                 const float* __restrict__ aux0, const float* __restrict__ aux1,
                 int Mreal, int Nreal) {
    constexpr int NT = KP / BK;
    __shared__ __align__(16) bf16 As[2][BM][BK];
    __shared__ __align__(16) bf16 Bs[2][BN][BK];

    const int tid  = threadIdx.x;
    const int w    = tid >> 6;
    const int lane = tid & 63;
    const int lr   = lane & 15;
    const int ls   = lane >> 4;
    const int lrow = lane >> 3;
    const int lcol = (lane & 7) * 8;

    const bf16* aBase = A  + (size_t)(blockIdx.y * BM + w * 32 + lrow) * lda + lcol;
    const bf16* bBase = Bt + (size_t)(blockIdx.x * BN + lrow) * KP + lcol;

    auto stage = [&](int buf, int k0) {
        #pragma unroll
        for (int i = 0; i < 4; ++i)
            gload16(aBase + (size_t)(i * 8) * lda + k0, &As[buf][w * 32 + i * 8][0]);
        #pragma unroll
        for (int jj = 0; jj < 6; ++jj) {
            int j = jj * 4 + w;
            if (j < 22) gload16(bBase + (size_t)(j * 8) * KP + k0, &Bs[buf][j * 8][0]);
        }
    };

    f32x4 acc[2][11];
    #pragma unroll
    for (int a = 0; a < 2; ++a)
        #pragma unroll
        for (int b2 = 0; b2 < 11; ++b2) acc[a][b2] = (f32x4)(0.0f);

    stage(0, 0);
    __syncthreads();
    int cur = 0;
    for (int t = 0; t < NT; ++t) {
        if (t + 1 < NT) stage(cur ^ 1, (t + 1) * BK);
        #pragma unroll
        for (int kk = 0; kk < 2; ++kk) {
            bf16x8 a0 = *(const bf16x8*)&As[cur][w*32 +      lr][kk*32 + ls*8];
            bf16x8 a1 = *(const bf16x8*)&As[cur][w*32 + 16 + lr][kk*32 + ls*8];
            #pragma unroll
            for (int nt = 0; nt < 11; ++nt) {
                bf16x8 bfr = *(const bf16x8*)&Bs[cur][nt*16 + lr][kk*32 + ls*8];
                acc[0][nt] = __builtin_amdgcn_mfma_f32_16x16x32_bf16(a0, bfr, acc[0][nt], 0, 0, 0);
                acc[1][nt] = __builtin_amdgcn_mfma_f32_16x16x32_bf16(a1, bfr, acc[1][nt], 0, 0, 0);
            }
        }
        __syncthreads();
        cur ^= 1;
    }

    const int colb = blockIdx.x * BN + lr;
    const int rowb = blockIdx.y * BM + w*32 + ls*4;
    #pragma unroll
    for (int mt = 0; mt < 2; ++mt)
    #pragma unroll
    for (int nt = 0; nt < 11; ++nt)
    #pragma unroll
    for (int q2 = 0; q2 < 4; ++q2) {
        int row = rowb + mt*16 + q2;
        int col = colb + nt*16;
        if (row >= Mreal) continue;
        float v = acc[mt][nt][q2];
        if constexpr (EPI == 0) {
            if (col < Nreal) outB[(size_t)row*ldo + col] = (bf16)(v + bias[col]);
        } else {
            if (col < Nreal) {
                float sz = (col < 172) ? aux0[(size_t)row*172 + col]
                                       : ((col < 344) ? 0.f : aux1[col - 344]);
                outF[(size_t)row*ldo + col] = v + bias[col] + sz;
            }
        }
    }
}

// ---------------- combined WQK/WVF GEMMs (KP=320, bf16 plain out), blockIdx.z selects ----------------
__global__ __launch_bounds__(256, 2)
void gemm_multi_kernel(const bf16* __restrict__ WKH, const bf16* __restrict__ WQHT,
                       const bf16* __restrict__ FCWT, const bf16* __restrict__ WVH,
                       bf16* __restrict__ WQKT, bf16* __restrict__ WVFT) {
    constexpr int KP = 320, NT = KP / BK;
    const int z = blockIdx.z, h = z & 1;
    const bf16 *A, *Bt; bf16* outB; int lda, ldo, Mreal, Nreal;
    if (z < 2) {
        if (blockIdx.x >= 2) return;
        A = WKH + (size_t)h*576*320;  lda = 320;
        Bt = WQHT + (size_t)h*352*320;
        outB = WQKT + (size_t)h*576*192; ldo = 192; Mreal = 576; Nreal = 192;
    } else {
        A = FCWT + (size_t)h*258;     lda = 576;
        Bt = WVH + (size_t)h*704*320;
        outB = WVFT + (size_t)h*576;  ldo = 1152; Mreal = 516; Nreal = 576;
    }
    __shared__ __align__(16) bf16 As[2][BM][BK];
    __shared__ __align__(16) bf16 Bs[2][BN][BK];
    const int tid = threadIdx.x, w = tid >> 6, lane = tid & 63;
    const int lr = lane & 15, ls = lane >> 4;
    const int lrow = lane >> 3, lcol = (lane & 7) * 8;
    const bf16* aBase = A  + (size_t)(blockIdx.y * BM + w * 32 + lrow) * lda + lcol;
    const bf16* bBase = Bt + (size_t)(blockIdx.x * BN + lrow) * KP + lcol;
    auto stage = [&](int buf, int k0) {
        #pragma unroll
        for (int i = 0; i < 4; ++i)
            gload16(aBase + (size_t)(i * 8) * lda + k0, &As[buf][w * 32 + i * 8][0]);
        #pragma unroll
        for (int jj = 0; jj < 6; ++jj) {
            int j = jj * 4 + w;
            if (j < 22) gload16(bBase + (size_t)(j * 8) * KP + k0, &Bs[buf][j * 8][0]);
        }
    };
    f32x4 acc[2][11];
    #pragma unroll
    for (int a = 0; a < 2; ++a)
        #pragma unroll
        for (int b2 = 0; b2 < 11; ++b2) acc[a][b2] = (f32x4)(0.0f);
    stage(0, 0);
    __syncthreads();
    int cur = 0;
    for (int t = 0; t < NT; ++t) {
        if (t + 1 < NT) stage(cur ^ 1, (t + 1) * BK);
        #pragma unroll
        for (int kk = 0; kk < 2; ++kk) {
            bf16x8 a0 = *(const bf16x8*)&As[cur][w*32 +      lr][kk*32 + ls*8];
            bf16x8 a1 = *(const bf16x8*)&As[cur][w*32 + 16 + lr][kk*32 + ls*8];
            #pragma unroll
            for (int nt = 0; nt < 11; ++nt) {
                bf16x8 bfr = *(const bf16x8*)&Bs[cur][nt*16 + lr][kk*32 + ls*8];
                acc[0][nt] = __builtin_amdgcn_mfma_f32_16x16x32_bf16(a0, bfr, acc[0][nt], 0, 0, 0);
                acc[1][nt] = __builtin_amdgcn_mfma_f32_16x16x32_bf16(a1, bfr, acc[1][nt], 0, 0, 0);
            }
        }
        __syncthreads();
        cur ^= 1;
    }
    const int colb = blockIdx.x * BN + lr;
    const int rowb = blockIdx.y * BM + w*32 + ls*4;
    #pragma unroll
    for (int mt = 0; mt < 2; ++mt)
    #pragma unroll
    for (int nt = 0; nt < 11; ++nt)
    #pragma unroll
    for (int q2 = 0; q2 < 4; ++q2) {
        int row = rowb + mt*16 + q2;
        int col = colb + nt*16;
        if (row < Mreal && col < Nreal)
            outB[(size_t)row*ldo + col] = (bf16)acc[mt][nt][q2];
    }
}

// ---------------- attention-lite v3: MFMA logits, vectorized ZB, fast cos ----------------
__global__ __launch_bounds__(256, 3)
void attn_lite_kernel(const bf16* __restrict__ QK, const bf16* __restrict__ nh16,
                      const float* __restrict__ edge_feat, const float* __restrict__ edge_t,
                      const int* __restrict__ nbr_idx, const float* __restrict__ freq,
                      const float* __restrict__ ph, const float* __restrict__ tnow,
                      bf16* __restrict__ ZB) {
    __shared__ __align__(16) bf16 zs[40][576];
    __shared__ __align__(16) bf16 qks[4][576];
    __shared__ __align__(16) float G[40][4];
    __shared__ float sfreq[172], sph[172];
    __shared__ float sdt[40];
    __shared__ int   ssrc[40];
    __shared__ float lg[2][20], pp[2][20];

    const int r  = blockIdx.x;
    const int iA = 2 * r;
    const int t  = threadIdx.x;
    const int w  = t >> 6, lane = t & 63;
    const int lr = lane & 15, ls = lane >> 4;

    if (t < 172) { sfreq[t] = freq[t]; sph[t] = ph[t]; }
    if (t >= 192 && t < 232) {
        int e2 = t - 192, ge = iA * 20 + e2;
        sdt[e2]  = tnow[0] - edge_t[ge];
        ssrc[e2] = nbr_idx[ge];
    }
    // qks[m][k] = QK[(iA + (m>>1))*1152 + (m&1)*576 + k]   (m = a*2 + h)
    for (int idx = t; idx < 4 * 72; idx += 256) {
        int m = idx / 72, g = idx % 72;
        *(bf16x8*)&qks[m][g * 8] =
            *(const bf16x8*)(QK + (size_t)(iA + (m >> 1)) * 1152 + (m & 1) * 576 + g * 8);
    }
    __syncthreads();

    // build z rows in LDS (same bf16 rounding points; fast cos)
    for (int idx = t; idx < 40 * 72; idx += 256) {
        int row = idx / 72, c = idx % 72;
        int k0 = c * 8;
        int ge = iA * 20 + row;
        bf16x8 v;
        if (c < 21) {
            v = *(const bf16x8*)(nh16 + (size_t)ssrc[row] * 192 + k0);
        } else if (c == 21) {
            #pragma unroll
            for (int e = 0; e < 8; ++e) {
                int k = 168 + e;
                v[e] = (k < 172) ? nh16[(size_t)ssrc[row] * 192 + k]
                                 : (bf16)edge_feat[(size_t)ge * 172 + (k - 172)];
            }
        } else if (c < 43) {
            const float* ep = edge_feat + (size_t)ge * 172 + (k0 - 172);
            f32x4 a = *(const f32x4*)ep;
            f32x4 b = *(const f32x4*)(ep + 4);
            #pragma unroll
            for (int e = 0; e < 4; ++e) { v[e] = (bf16)a[e]; v[e+4] = (bf16)b[e]; }
        } else if (c < 64) {
            float dt = sdt[row];
            #pragma unroll
            for (int e = 0; e < 8; ++e) {
                int j = k0 - 344 + e;
                v[e] = (bf16)__cosf(dt * sfreq[j] + sph[j]);
            }
        } else if (c == 64) {
            float dt = sdt[row];
            #pragma unroll
            for (int e = 0; e < 8; ++e) {
                int k = 512 + e;
                v[e] = (k < 516) ? (bf16)__cosf(dt * sfreq[k - 344] + sph[k - 344]) : (bf16)0.f;
            }
        } else {
            #pragma unroll
            for (int e = 0; e < 8; ++e) v[e] = (bf16)0.f;
        }
        *(bf16x8*)&zs[row][k0] = v;
    }
    __syncthreads();

    // MFMA logits: G[4 x 40] = qks(4x576) . zs^T ; waves 0..2 each own one 16-col tile
    if (w < 3) {
        int brow = w * 16 + lr; if (brow > 39) brow = 39;   // clamp: cols>=40 discarded
        f32x4 acc = (f32x4)(0.0f);
        #pragma unroll
        for (int ks = 0; ks < 18; ++ks) {
            bf16x8 af = *(const bf16x8*)&qks[lr & 3][ks * 32 + ls * 8];  // rows>=4 discarded
            bf16x8 bf = *(const bf16x8*)&zs[brow][ks * 32 + ls * 8];
            acc = __builtin_amdgcn_mfma_f32_16x16x32_bf16(af, bf, acc, 0, 0, 0);
        }
        int col = w * 16 + lr;                 // C: col=lane&15, row=(lane>>4)*4+q
        if (ls == 0 && col < 40) *(f32x4*)&G[col][0] = acc;
    }
    __syncthreads();

    if (t < 40) {
        int h = t / 20, knbr = t % 20;
        int z0 = (knbr / 10) * 20 + 2 * (knbr % 10);
        lg[h][knbr] = (G[z0][h] + G[z0 + 1][2 + h]) * 0.0622573006f;   // 1/sqrt(258)
    }
    __syncthreads();
    if (t < 2) {
        float m = -1e30f;
        for (int k2 = 0; k2 < 20; ++k2) m = fmaxf(m, lg[t][k2]);
        float ssum = 0.f, ex[20];
        #pragma unroll
        for (int k2 = 0; k2 < 20; ++k2) { ex[k2] = expf(lg[t][k2] - m); ssum += ex[k2]; }
        float inv = 1.f / ssum;
        #pragma unroll
        for (int k2 = 0; k2 < 20; ++k2) pp[t][k2] = ex[k2] * inv;
    }
    __syncthreads();

    // ZB: 288 8-wide tasks; all lanes read the same z-row contiguously (conflict-free)
    for (int idx = t; idx < 288; idx += 256) {
        int nsel = idx / 144, rem = idx % 144;
        int hh = rem / 72, c8 = rem % 72;
        float a[8] = {0.f, 0.f, 0.f, 0.f, 0.f, 0.f, 0.f, 0.f};
        #pragma unroll
        for (int knbr = 0; knbr < 20; ++knbr) {
            int src = knbr / 10, e = knbr % 10;
            bf16x8 zv = *(const bf16x8*)&zs[src*20 + 2*e + nsel][c8 * 8];
            float p = pp[hh][knbr];
            #pragma unroll
            for (int i = 0; i < 8; ++i) a[i] += p * (float)zv[i];
        }
        bf16x8 o;
        #pragma unroll
        for (int i = 0; i < 8; ++i) o[i] = (bf16)a[i];
        *(bf16x8*)(ZB + (size_t)(iA + nsel) * 1152 + hh * 576 + c8 * 8) = o;
    }
}

// ---------------- LayerNorm + build X = [h_ln, node_h, 0pad] ----------------
__global__ __launch_bounds__(256)
void ln_x_kernel(const float* __restrict__ fcr, const float* __restrict__ g,
                 const float* __restrict__ b, const bf16* __restrict__ nh16,
                 bf16* __restrict__ X) {
    __shared__ float red[2][4];
    __shared__ float mb[2];
    const size_t i = blockIdx.x;
    const int t = threadIdx.x;
    int c0 = t, c1 = t + 256, c2 = t + 512;
    float v0 = fcr[i*516 + c0];
    float v1 = (c1 < 516) ? fcr[i*516 + c1] : 0.f;
    float v2 = (c2 < 516) ? fcr[i*516 + c2] : 0.f;
    float s = v0 + v1 + v2, ss = v0*v0 + v1*v1 + v2*v2;
    #pragma unroll
    for (int o = 32; o; o >>= 1) { s += __shfl_down(s, o); ss += __shfl_down(ss, o); }
    if ((t & 63) == 0) { red[0][t >> 6] = s; red[1][t >> 6] = ss; }
    __syncthreads();
    if (t == 0) {
        float S  = red[0][0] + red[0][1] + red[0][2] + red[0][3];
        float SS = red[1][0] + red[1][1] + red[1][2] + red[1][3];
        float mean = S / 516.f;
        float var  = SS / 516.f - mean*mean;
        mb[0] = mean; mb[1] = rsqrtf(var + 1e-5f);
    }
    __syncthreads();
    float mean = mb[0], rstd = mb[1];
    X[i*704 + c0] = (bf16)((v0 - mean)*rstd*g[c0] + b[c0]);
    if (c1 < 516) X[i*704 + c1] = (bf16)((v1 - mean)*rstd*g[c1] + b[c1]);
    if (c2 < 516) X[i*704 + c2] = (bf16)((v2 - mean)*rstd*g[c2] + b[c2]);
    for (int c = 516 + t; c < 704; c += 256)
        X[i*704 + c] = (c < 688) ? nh16[i*192 + (c - 516)] : (bf16)0.f;
}

// ---------------- fused M1(relu) + M2 -> d_out ----------------
__global__ __launch_bounds__(256)
void m1m2_kernel(const bf16* __restrict__ A, const bf16* __restrict__ B1,
                 const bf16* __restrict__ B2, const float* __restrict__ b1,
                 const float* __restrict__ b2, float* __restrict__ outF, int Mreal) {
    constexpr int KP = 704, NT = KP / BK;
    __shared__ __align__(16) union {
        struct { bf16 As[2][BM][BK]; bf16 Bs[2][BN][BK]; } g;   // 77824 B
        struct { bf16 Rs[BM][192];  bf16 B2s[BN][192]; } s;     // 116736 B
    } U;

    const int tid  = threadIdx.x;
    const int w    = tid >> 6;
    const int lane = tid & 63;
    const int lr   = lane & 15;
    const int ls   = lane >> 4;
    const int lrow = lane >> 3;
    const int lcol = (lane & 7) * 8;

    const bf16* aBase = A  + (size_t)(blockIdx.y * BM + w * 32 + lrow) * KP + lcol;
    const bf16* bBase = B1 + (size_t)lrow * KP + lcol;

    auto stage = [&](int buf, int k0) {
        #pragma unroll
        for (int i = 0; i < 4; ++i)
            gload16(aBase + (size_t)(i * 8) * KP + k0, &U.g.As[buf][w * 32 + i * 8][0]);
        #pragma unroll
        for (int jj = 0; jj < 6; ++jj) {
            int j = jj * 4 + w;
            if (j < 22) gload16(bBase + (size_t)(j * 8) * KP + k0, &U.g.Bs[buf][j * 8][0]);
        }
    };

    f32x4 acc[2][11];
    #pragma unroll
    for (int a = 0; a < 2; ++a)
        #pragma unroll
        for (int b = 0; b < 11; ++b) acc[a][b] = (f32x4)(0.0f);

    stage(0, 0);
    __syncthreads();
    int cur = 0;
    for (int t = 0; t < NT; ++t) {
        if (t + 1 < NT) stage(cur ^ 1, (t + 1) * BK);
        #pragma unroll
        for (int kk = 0; kk < 2; ++kk) {
            bf16x8 a0 = *(const bf16x8*)&U.g.As[cur][w*32 +      lr][kk*32 + ls*8];
            bf16x8 a1 = *(const bf16x8*)&U.g.As[cur][w*32 + 16 + lr][kk*32 + ls*8];
            #pragma unroll
            for (int nt = 0; nt < 11; ++nt) {
                bf16x8 bfr = *(const bf16x8*)&U.g.Bs[cur][nt*16 + lr][kk*32 + ls*8];
                acc[0][nt] = __builtin_amdgcn_mfma_f32_16x16x32_bf16(a0, bfr, acc[0][nt], 0, 0, 0);
                acc[1][nt] = __builtin_amdgcn_mfma_f32_16x16x32_bf16(a1, bfr, acc[1][nt], 0, 0, 0);
            }
        }
        __syncthreads();
        cur ^= 1;
    }

    // R tile -> LDS (relu + bias; cols>=172 zero), and DMA B2 into LDS
    #pragma unroll
    for (int mt = 0; mt < 2; ++mt)
    #pragma unroll
    for (int nt = 0; nt < 11; ++nt)
    #pragma unroll
    for (int q2 = 0; q2 < 4; ++q2) {
        int lro = w*32 + mt*16 + ls*4 + q2;
        int col = lr + nt*16;
        float vv = (col < 172) ? fmaxf(acc[mt][nt][q2] + b1[col], 0.f) : 0.f;
        U.s.Rs[lro][col] = (bf16)vv;
    }
    for (int idx = tid; idx < BM*16; idx += 256)
        U.s.Rs[idx >> 4][176 + (idx & 15)] = (bf16)0.f;
    // stage B2 [176][192] linearly: 66 chunks of 1024 B
    #pragma unroll
    for (int jj = 0; jj < 17; ++jj) {
        int j = jj * 4 + w;
        if (j < 66)
            gload16(B2 + (size_t)j*512 + lane*8, (bf16*)U.s.B2s + (size_t)j*512 + lane*8);
    }
    __syncthreads();

    // M2: K=192 (3 k-steps)
    f32x4 acc2[2][11];
    #pragma unroll
    for (int a = 0; a < 2; ++a)
        #pragma unroll
        for (int b = 0; b < 11; ++b) acc2[a][b] = (f32x4)(0.0f);
    #pragma unroll
    for (int t2 = 0; t2 < 3; ++t2) {
        #pragma unroll
        for (int kk = 0; kk < 2; ++kk) {
            int off = t2*64 + kk*32 + ls*8;
            bf16x8 a0 = *(const bf16x8*)&U.s.Rs[w*32 +      lr][off];
            bf16x8 a1 = *(const bf16x8*)&U.s.Rs[w*32 + 16 + lr][off];
            #pragma unroll
            for (int nt = 0; nt < 11; ++nt) {
                bf16x8 bfr = *(const bf16x8*)&U.s.B2s[nt*16 + lr][off];
                acc2[0][nt] = __builtin_amdgcn_mfma_f32_16x16x32_bf16(a0, bfr, acc2[0][nt], 0, 0, 0);
                acc2[1][nt] = __builtin_amdgcn_mfma_f32_16x16x32_bf16(a1, bfr, acc2[1][nt], 0, 0, 0);
            }
        }
    }

    const int rowb = blockIdx.y * BM + w*32 + ls*4;
    #pragma unroll
    for (int mt = 0; mt < 2; ++mt)
    #pragma unroll
    for (int nt = 0; nt < 11; ++nt)
    #pragma unroll
    for (int q2 = 0; q2 < 4; ++q2) {
        int row = rowb + mt*16 + q2;
        int col = lr + nt*16;
        if (row < Mreal && col < 172)
            outF[(size_t)row*172 + col] = acc2[mt][nt][q2] + b2[col];
    }
}

// ---------------- launch ----------------
extern "C" void kernel_launch(void* const* d_in, const int* in_sizes, int n_in,
                              void* d_out, int out_size, void* d_ws, size_t ws_size,
                              hipStream_t stream) {
    const float* node_h     = (const float*)d_in[0];
    const float* edge_t     = (const float*)d_in[1];
    const float* edge_feat  = (const float*)d_in[2];
    const int*   nbr_idx    = (const int*)d_in[3];
    const float* t_now      = (const float*)d_in[4];
    const float* w_q        = (const float*)d_in[6];
    const float* w_k        = (const float*)d_in[7];
    const float* w_v        = (const float*)d_in[8];
    const float* basis_freq = (const float*)d_in[9];
    const float* phase      = (const float*)d_in[10];
    const float* ln_g       = (const float*)d_in[11];
    const float* ln_b       = (const float*)d_in[12];
    const float* fc_w       = (const float*)d_in[13];
    const float* fc_b       = (const float*)d_in[14];
    const float* m1_w       = (const float*)d_in[15];
    const float* m1_b       = (const float*)d_in[16];
    const float* m2_w       = (const float*)d_in[17];
    const float* m2_b       = (const float*)d_in[18];

    char* ws = (char*)d_ws;
    bf16*  FCWT = (bf16*)(ws + FCWT_OFF);
    bf16*  M1WT = (bf16*)(ws + M1WT_OFF);
    bf16*  M2WT = (bf16*)(ws + M2WT_OFF);
    bf16*  WKH  = (bf16*)(ws + WKH_OFF);
    bf16*  WQHT = (bf16*)(ws + WQHT_OFF);
    bf16*  WVH  = (bf16*)(ws + WVH_OFF);
    bf16*  WQKT = (bf16*)(ws + WQKT_OFF);
    bf16*  WVFT = (bf16*)(ws + WVFT_OFF);
    float* QB   = (float*)(ws + QB_OFF);
    float* QKB  = (float*)(ws + QKB_OFF);
    float* CPH  = (float*)(ws + CPH_OFF);
    bf16*  NH16 = (bf16*)(ws + NH16_OFF);
    bf16*  QK   = (bf16*)(ws + QK_OFF);
    bf16*  ZB   = (bf16*)(ws + ZB_OFF);
    float* FCR  = (float*)(ws + FCR_OFF);
    bf16*  Xb   = (bf16*)(ws + X_OFF);

    hipMemsetAsync(ws, 0, NH16_OFF, stream);

    packT_kernel<<<dim3(289, 3), 256, 0, stream>>>(fc_w, m1_w, m2_w, FCWT, M1WT, M2WT);
    pack_misc_kernel<<<2048, 256, 0, stream>>>(w_k, w_q, w_v, node_h, phase,
                                               WKH, WQHT, WVH, NH16, CPH);
    qbias_kernel<<<516, 256, 0, stream>>>(w_q, phase, QB);
    qkb_kernel<<<1152, 256, 0, stream>>>(w_k, QB, QKB);

    // WQK^T (z=0,1) and WVF^T (z=2,3) in one launch
    gemm_multi_kernel<<<dim3(4, 5, 4), 256, 0, stream>>>(WKH, WQHT, FCWT, WVH, WQKT, WVFT);

    // qk = NH16 @ WQK^T + qkb   -> QK [NPAD][1152]
    gemm_kernel<192, 0><<<dim3(7, 79), 256, 0, stream>>>(
        NH16, 192, WQKT, nullptr, QK, 1152, QKB, nullptr, nullptr, NN, 1152);

    // attention (z built in LDS, MFMA logits) -> ZB [NPAD][1152]
    attn_lite_kernel<<<NN / 2, 256, 0, stream>>>(
        QK, NH16, edge_feat, edge_t, nbr_idx, basis_freq, phase, t_now, ZB);

    // fcr = ZB @ WVF^T + fc_b + self_z
    gemm_kernel<1152, 2><<<dim3(3, 79), 256, 0, stream>>>(
        ZB, 1152, WVFT, FCR, nullptr, 516, fc_b, node_h, CPH, NN, 516);

    ln_x_kernel<<<NN, 256, 0, stream>>>(FCR, ln_g, ln_b, NH16, Xb);

    // fused m1(relu) + m2 -> out
    m1m2_kernel<<<dim3(1, 79), 256, 0, stream>>>(
        Xb, M1WT, M2WT, m1_b, m2_b, (float*)d_out, NN);
}

// Round 9
// 306.338 us; speedup vs baseline: 8.7389x; 1.0041x over previous
//
#include <hip/hip_runtime.h>
#include <hip/hip_bf16.h>
#include <math.h>

typedef __bf16 bf16;
typedef __attribute__((ext_vector_type(4))) __bf16 bf16x4;
typedef __attribute__((ext_vector_type(8))) __bf16 bf16x8;
typedef __attribute__((ext_vector_type(4))) float f32x4;

// ---------------- problem constants ----------------
constexpr int NN   = 10000;
constexpr int NPAD = 10112;            // 128-aligned (DMA overrun pad)
constexpr int BM = 128, BN = 176, BK = 64;

// ---------------- workspace layout (bytes) ----------------
constexpr size_t FCWT_OFF = 0;                         // bf16 [528][576]   fcw^T (zero-padded)
constexpr size_t M1WT_OFF = 608256;                    // bf16 [176][704]
constexpr size_t M2WT_OFF = 856064;                    // bf16 [176][192]
constexpr size_t WKH_OFF  = 923648;                    // bf16 [2*576][320] wk head-slices
constexpr size_t WQHT_OFF = 1660928;                   // bf16 [2*352][320] wq head-slices (rows<172)
constexpr size_t WVH_OFF  = 2111488;                   // bf16 [2*704][320] wv head-slices
constexpr size_t WQKT_OFF = 3012608;                   // bf16 [1232][192]  WQK^T (qk GEMM B)
constexpr size_t WVFT_OFF = 3485696;                   // bf16 [528][1152]  WVF^T (fusedFC B)
constexpr size_t QB_OFF   = 4702208;                   // f32 [516]
constexpr size_t QKB_OFF  = 4706304;                   // f32 [1232]
constexpr size_t CPH_OFF  = 4714496;                   // f32 [172]
constexpr size_t NH16_OFF = 4715520;                   // bf16 [NPAD][192]
constexpr size_t QK_OFF   = NH16_OFF + (size_t)NPAD*192*2;    // bf16 [NPAD][1152]
constexpr size_t ZB_OFF   = QK_OFF   + (size_t)NPAD*1152*2;   // bf16 [NPAD][1152]
constexpr size_t FCR_OFF  = ZB_OFF   + (size_t)NPAD*1152*2;   // f32 [NN][516]
constexpr size_t X_OFF    = FCR_OFF  + (size_t)NN*516*4;      // bf16 [NPAD][704]

// ---------------- global_load_lds helper (width 16) ----------------
typedef __attribute__((address_space(3))) void lds_void;
typedef const __attribute__((address_space(1))) void glb_void;
__device__ __forceinline__ void gload16(const void* g, void* l) {
    __builtin_amdgcn_global_load_lds((glb_void*)(uintptr_t)g,
                                     (lds_void*)(unsigned int)(uintptr_t)l, 16, 0, 0);
}

// ---------------- tiled transpose-pack (fcw, m1w, m2w) ----------------
__global__ __launch_bounds__(256)
void packT_kernel(const float* __restrict__ fcw, const float* __restrict__ m1w,
                  const float* __restrict__ m2w,
                  bf16* __restrict__ FCWT, bf16* __restrict__ M1WT, bf16* __restrict__ M2WT) {
    __shared__ float tile[32][33];
    const float* src; bf16* dst; int K, C, LD;
    switch (blockIdx.y) {
        case 0:  src = fcw; K = 516; C = 516; dst = FCWT; LD = 576; break;
        case 1:  src = m1w; K = 688; C = 172; dst = M1WT; LD = 704; break;
        default: src = m2w; K = 172; C = 172; dst = M2WT; LD = 192; break;
    }
    const int tilesC = (C + 31) >> 5, tilesK = (K + 31) >> 5;
    const int nt = tilesC * tilesK;
    const int tx = threadIdx.x & 31, ty = threadIdx.x >> 5;
    for (int tb = blockIdx.x; tb < nt; tb += gridDim.x) {
        int tc = tb % tilesC, tk = tb / tilesC;
        #pragma unroll
        for (int i = 0; i < 4; ++i) {
            int k = tk*32 + ty + i*8, c = tc*32 + tx;
            tile[ty + i*8][tx] = (k < K && c < C) ? src[(size_t)k*C + c] : 0.f;
        }
        __syncthreads();
        #pragma unroll
        for (int i = 0; i < 4; ++i) {
            int c = tc*32 + ty + i*8, k = tk*32 + tx;
            if (c < C && k < K) dst[(size_t)c*LD + k] = (bf16)tile[tx][ty + i*8];
        }
        __syncthreads();
    }
}

// ---------------- fused misc packs: wk/wq/wv head-slices + nh16 + cph ----------------
__global__ void pack_misc_kernel(const float* __restrict__ wk, const float* __restrict__ wq,
                                 const float* __restrict__ wv, const float* __restrict__ node_h,
                                 const float* __restrict__ phase,
                                 bf16* __restrict__ WKH, bf16* __restrict__ WQHT,
                                 bf16* __restrict__ WVH, bf16* __restrict__ nh16,
                                 float* __restrict__ cph) {
    constexpr int T0 = 2*516*258;
    constexpr int T1 = T0 + 2*172*258;
    constexpr int T2 = T1 + 2*516*258;
    constexpr int T3 = T2 + NN*192;
    constexpr int T4 = T3 + 172;
    for (int idx = blockIdx.x * blockDim.x + threadIdx.x; idx < T4;
         idx += gridDim.x * blockDim.x) {
        if (idx < T0) {
            int h = idx / (516*258), rem = idx % (516*258), d = rem / 258, j = rem % 258;
            WKH[((size_t)h*576 + d)*320 + j] = (bf16)wk[(size_t)d*516 + h*258 + j];
        } else if (idx < T1) {
            int i = idx - T0;
            int h = i / (172*258), rem = i % (172*258), k = rem / 258, j = rem % 258;
            WQHT[((size_t)h*352 + k)*320 + j] = (bf16)wq[(size_t)k*516 + h*258 + j];
        } else if (idx < T2) {
            int i = idx - T1;
            int h = i / (516*258), rem = i % (516*258), c = rem / 258, j = rem % 258;
            WVH[((size_t)h*704 + c)*320 + j] = (bf16)wv[(size_t)c*516 + h*258 + j];
        } else if (idx < T3) {
            int i = idx - T2, r = i / 192, c = i % 192;
            nh16[i] = (c < 172) ? (bf16)node_h[(size_t)r*172 + c] : (bf16)0.f;
        } else cph[idx - T3] = cosf(phase[idx - T3]);
    }
}

// QB[c] = sum_j cos(phase[j]) * w_q[(344+j)*516 + c]
__global__ __launch_bounds__(256)
void qbias_kernel(const float* __restrict__ w_q, const float* __restrict__ phase,
                  float* __restrict__ q_bias) {
    __shared__ float red[256];
    const int c = blockIdx.x, j = threadIdx.x;
    red[j] = (j < 172) ? cosf(phase[j]) * w_q[(size_t)(344 + j) * 516 + c] : 0.f;
    __syncthreads();
    #pragma unroll
    for (int o = 128; o; o >>= 1) { if (j < o) red[j] += red[j + o]; __syncthreads(); }
    if (j == 0) q_bias[c] = red[0];
}

// qkb[h*576+d] = sum_{j<258} QB[h*258+j] * wk[d][h*258+j]   (d<516, else 0)
__global__ __launch_bounds__(256)
void qkb_kernel(const float* __restrict__ wk, const float* __restrict__ QB,
                float* __restrict__ qkb) {
    __shared__ float red[256];
    const int hd = blockIdx.x, h = hd / 576, d = hd % 576, t = threadIdx.x;
    float a = 0.f;
    if (d < 516) {
        a = QB[h*258 + t] * wk[(size_t)d*516 + h*258 + t];
        if (t < 2) a += QB[h*258 + 256 + t] * wk[(size_t)d*516 + h*258 + 256 + t];
    }
    red[t] = a; __syncthreads();
    #pragma unroll
    for (int o = 128; o; o >>= 1) { if (t < o) red[t] += red[t + o]; __syncthreads(); }
    if (t == 0) qkb[hd] = red[0];
}

// ---------------- MFMA GEMM (DMA staging + 2-phase dbuf), runtime lda/ldo ----------------
// EPI 0: bf16 out +bias    EPI 2: f32 out +bias +selfz
template<int KP, int EPI>
__global__ __launch_bounds__(256, 2)
void gemm_kernel(const bf16* __restrict__ A, int lda, const bf16* __restrict__ Bt,
                 float* __restrict__ outF, bf16* __restrict__ outB, int ldo,
                 const float* __restrict__ bias,
                 const float* __restrict__ aux0, const float* __restrict__ aux1,
                 int Mreal, int Nreal) {
    constexpr int NT = KP / BK;
    __shared__ __align__(16) bf16 As[2][BM][BK];
    __shared__ __align__(16) bf16 Bs[2][BN][BK];

    const int tid  = threadIdx.x;
    const int w    = tid >> 6;
    const int lane = tid & 63;
    const int lr   = lane & 15;
    const int ls   = lane >> 4;
    const int lrow = lane >> 3;
    const int lcol = (lane & 7) * 8;

    const bf16* aBase = A  + (size_t)(blockIdx.y * BM + w * 32 + lrow) * lda + lcol;
    const bf16* bBase = Bt + (size_t)(blockIdx.x * BN + lrow) * KP + lcol;

    auto stage = [&](int buf, int k0) {
        #pragma unroll
        for (int i = 0; i < 4; ++i)
            gload16(aBase + (size_t)(i * 8) * lda + k0, &As[buf][w * 32 + i * 8][0]);
        #pragma unroll
        for (int jj = 0; jj < 6; ++jj) {
            int j = jj * 4 + w;
            if (j < 22) gload16(bBase + (size_t)(j * 8) * KP + k0, &Bs[buf][j * 8][0]);
        }
    };

    f32x4 acc[2][11];
    #pragma unroll
    for (int a = 0; a < 2; ++a)
        #pragma unroll
        for (int b2 = 0; b2 < 11; ++b2) acc[a][b2] = (f32x4)(0.0f);

    stage(0, 0);
    __syncthreads();
    int cur = 0;
    for (int t = 0; t < NT; ++t) {
        if (t + 1 < NT) stage(cur ^ 1, (t + 1) * BK);
        #pragma unroll
        for (int kk = 0; kk < 2; ++kk) {
            bf16x8 a0 = *(const bf16x8*)&As[cur][w*32 +      lr][kk*32 + ls*8];
            bf16x8 a1 = *(const bf16x8*)&As[cur][w*32 + 16 + lr][kk*32 + ls*8];
            #pragma unroll
            for (int nt = 0; nt < 11; ++nt) {
                bf16x8 bfr = *(const bf16x8*)&Bs[cur][nt*16 + lr][kk*32 + ls*8];
                acc[0][nt] = __builtin_amdgcn_mfma_f32_16x16x32_bf16(a0, bfr, acc[0][nt], 0, 0, 0);
                acc[1][nt] = __builtin_amdgcn_mfma_f32_16x16x32_bf16(a1, bfr, acc[1][nt], 0, 0, 0);
            }
        }
        __syncthreads();
        cur ^= 1;
    }

    const int colb = blockIdx.x * BN + lr;
    const int rowb = blockIdx.y * BM + w*32 + ls*4;
    #pragma unroll
    for (int mt = 0; mt < 2; ++mt)
    #pragma unroll
    for (int nt = 0; nt < 11; ++nt)
    #pragma unroll
    for (int q2 = 0; q2 < 4; ++q2) {
        int row = rowb + mt*16 + q2;
        int col = colb + nt*16;
        if (row >= Mreal) continue;
        float v = acc[mt][nt][q2];
        if constexpr (EPI == 0) {
            if (col < Nreal) outB[(size_t)row*ldo + col] = (bf16)(v + bias[col]);
        } else {
            if (col < Nreal) {
                float sz = (col < 172) ? aux0[(size_t)row*172 + col]
                                       : ((col < 344) ? 0.f : aux1[col - 344]);
                outF[(size_t)row*ldo + col] = v + bias[col] + sz;
            }
        }
    }
}

// ---------------- combined WQK/WVF GEMMs (KP=320, bf16 plain out), blockIdx.z selects ----------------
__global__ __launch_bounds__(256, 2)
void gemm_multi_kernel(const bf16* __restrict__ WKH, const bf16* __restrict__ WQHT,
                       const bf16* __restrict__ FCWT, const bf16* __restrict__ WVH,
                       bf16* __restrict__ WQKT, bf16* __restrict__ WVFT) {
    constexpr int KP = 320, NT = KP / BK;
    const int z = blockIdx.z, h = z & 1;
    const bf16 *A, *Bt; bf16* outB; int lda, ldo, Mreal, Nreal;
    if (z < 2) {
        if (blockIdx.x >= 2) return;
        A = WKH + (size_t)h*576*320;  lda = 320;
        Bt = WQHT + (size_t)h*352*320;
        outB = WQKT + (size_t)h*576*192; ldo = 192; Mreal = 576; Nreal = 192;
    } else {
        A = FCWT + (size_t)h*258;     lda = 576;
        Bt = WVH + (size_t)h*704*320;
        outB = WVFT + (size_t)h*576;  ldo = 1152; Mreal = 516; Nreal = 576;
    }
    __shared__ __align__(16) bf16 As[2][BM][BK];
    __shared__ __align__(16) bf16 Bs[2][BN][BK];
    const int tid = threadIdx.x, w = tid >> 6, lane = tid & 63;
    const int lr = lane & 15, ls = lane >> 4;
    const int lrow = lane >> 3, lcol = (lane & 7) * 8;
    const bf16* aBase = A  + (size_t)(blockIdx.y * BM + w * 32 + lrow) * lda + lcol;
    const bf16* bBase = Bt + (size_t)(blockIdx.x * BN + lrow) * KP + lcol;
    auto stage = [&](int buf, int k0) {
        #pragma unroll
        for (int i = 0; i < 4; ++i)
            gload16(aBase + (size_t)(i * 8) * lda + k0, &As[buf][w * 32 + i * 8][0]);
        #pragma unroll
        for (int jj = 0; jj < 6; ++jj) {
            int j = jj * 4 + w;
            if (j < 22) gload16(bBase + (size_t)(j * 8) * KP + k0, &Bs[buf][j * 8][0]);
        }
    };
    f32x4 acc[2][11];
    #pragma unroll
    for (int a = 0; a < 2; ++a)
        #pragma unroll
        for (int b2 = 0; b2 < 11; ++b2) acc[a][b2] = (f32x4)(0.0f);
    stage(0, 0);
    __syncthreads();
    int cur = 0;
    for (int t = 0; t < NT; ++t) {
        if (t + 1 < NT) stage(cur ^ 1, (t + 1) * BK);
        #pragma unroll
        for (int kk = 0; kk < 2; ++kk) {
            bf16x8 a0 = *(const bf16x8*)&As[cur][w*32 +      lr][kk*32 + ls*8];
            bf16x8 a1 = *(const bf16x8*)&As[cur][w*32 + 16 + lr][kk*32 + ls*8];
            #pragma unroll
            for (int nt = 0; nt < 11; ++nt) {
                bf16x8 bfr = *(const bf16x8*)&Bs[cur][nt*16 + lr][kk*32 + ls*8];
                acc[0][nt] = __builtin_amdgcn_mfma_f32_16x16x32_bf16(a0, bfr, acc[0][nt], 0, 0, 0);
                acc[1][nt] = __builtin_amdgcn_mfma_f32_16x16x32_bf16(a1, bfr, acc[1][nt], 0, 0, 0);
            }
        }
        __syncthreads();
        cur ^= 1;
    }
    const int colb = blockIdx.x * BN + lr;
    const int rowb = blockIdx.y * BM + w*32 + ls*4;
    #pragma unroll
    for (int mt = 0; mt < 2; ++mt)
    #pragma unroll
    for (int nt = 0; nt < 11; ++nt)
    #pragma unroll
    for (int q2 = 0; q2 < 4; ++q2) {
        int row = rowb + mt*16 + q2;
        int col = colb + nt*16;
        if (row < Mreal && col < Nreal)
            outB[(size_t)row*ldo + col] = (bf16)acc[mt][nt][q2];
    }
}

// ---------------- attention-lite v4: swizzled LDS, MFMA logits, fused-hh ZB ----------------
__global__ __launch_bounds__(256, 3)
void attn_lite_kernel(const bf16* __restrict__ QK, const bf16* __restrict__ nh16,
                      const float* __restrict__ edge_feat, const float* __restrict__ edge_t,
                      const int* __restrict__ nbr_idx, const float* __restrict__ freq,
                      const float* __restrict__ ph, const float* __restrict__ tnow,
                      bf16* __restrict__ ZB) {
    __shared__ __align__(16) bf16 zs[40 * 576];    // XOR-swizzled rows (stride 1152 B)
    __shared__ __align__(16) bf16 qks[4 * 576];    // XOR-swizzled rows
    __shared__ __align__(16) float G[40][4];
    __shared__ float sfreq[172], sph[172];
    __shared__ float sdt[40];
    __shared__ int   ssrc[40];
    __shared__ float lg[2][20], exs[2][20], pp[2][20];

    const int r  = blockIdx.x;
    const int iA = 2 * r;
    const int t  = threadIdx.x;
    const int w  = t >> 6, lane = t & 63;
    const int lr = lane & 15, ls = lane >> 4;

    // swizzled LDS addressing: zs row pitch 1152 B, XOR bits 4-6 with row&7
    auto zsa = [&](int row, int c) -> bf16* {
        unsigned b = (unsigned)(row * 1152 + c * 2) ^ (unsigned)((row & 7) << 4);
        return (bf16*)((char*)zs + b);
    };
    auto qka = [&](int row, int c) -> bf16* {
        unsigned b = (unsigned)(row * 1152 + c * 2) ^ (unsigned)((row & 3) << 5);
        return (bf16*)((char*)qks + b);
    };

    if (t < 172) { sfreq[t] = freq[t]; sph[t] = ph[t]; }
    if (t >= 192 && t < 232) {
        int e2 = t - 192, ge = iA * 20 + e2;
        sdt[e2]  = tnow[0] - edge_t[ge];
        ssrc[e2] = nbr_idx[ge];
    }
    // qks[m][k] = QK[(iA + (m>>1))*1152 + (m&1)*576 + k]   (m = a*2 + h)
    for (int idx = t; idx < 4 * 72; idx += 256) {
        int m = idx / 72, g = idx % 72;
        *(bf16x8*)qka(m, g * 8) =
            *(const bf16x8*)(QK + (size_t)(iA + (m >> 1)) * 1152 + (m & 1) * 576 + g * 8);
    }
    __syncthreads();

    // build z rows in LDS (same bf16 rounding points; fast cos)
    for (int idx = t; idx < 40 * 72; idx += 256) {
        int row = idx / 72, c = idx % 72;
        int k0 = c * 8;
        int ge = iA * 20 + row;
        bf16x8 v;
        if (c < 21) {
            v = *(const bf16x8*)(nh16 + (size_t)ssrc[row] * 192 + k0);
        } else if (c == 21) {
            #pragma unroll
            for (int e = 0; e < 8; ++e) {
                int k = 168 + e;
                v[e] = (k < 172) ? nh16[(size_t)ssrc[row] * 192 + k]
                                 : (bf16)edge_feat[(size_t)ge * 172 + (k - 172)];
            }
        } else if (c < 43) {
            const float* ep = edge_feat + (size_t)ge * 172 + (k0 - 172);
            f32x4 a = *(const f32x4*)ep;
            f32x4 b = *(const f32x4*)(ep + 4);
            #pragma unroll
            for (int e = 0; e < 4; ++e) { v[e] = (bf16)a[e]; v[e+4] = (bf16)b[e]; }
        } else if (c < 64) {
            float dt = sdt[row];
            #pragma unroll
            for (int e = 0; e < 8; ++e) {
                int j = k0 - 344 + e;
                v[e] = (bf16)__cosf(dt * sfreq[j] + sph[j]);
            }
        } else if (c == 64) {
            float dt = sdt[row];
            #pragma unroll
            for (int e = 0; e < 8; ++e) {
                int k = 512 + e;
                v[e] = (k < 516) ? (bf16)__cosf(dt * sfreq[k - 344] + sph[k - 344]) : (bf16)0.f;
            }
        } else {
            #pragma unroll
            for (int e = 0; e < 8; ++e) v[e] = (bf16)0.f;
        }
        *(bf16x8*)zsa(row, k0) = v;
    }
    __syncthreads();

    // MFMA logits: G[4 x 40] = qks(4x576) . zs^T ; waves 0..2 each own one 16-col tile
    if (w < 3) {
        int brow = w * 16 + lr; if (brow > 39) brow = 39;   // clamp: cols>=40 discarded
        f32x4 acc = (f32x4)(0.0f);
        __builtin_amdgcn_s_setprio(1);
        #pragma unroll
        for (int ks = 0; ks < 18; ++ks) {
            bf16x8 af = *(const bf16x8*)qka(lr & 3, ks * 32 + ls * 8);  // rows>=4 discarded
            bf16x8 bf = *(const bf16x8*)zsa(brow, ks * 32 + ls * 8);
            acc = __builtin_amdgcn_mfma_f32_16x16x32_bf16(af, bf, acc, 0, 0, 0);
        }
        __builtin_amdgcn_s_setprio(0);
        int col = w * 16 + lr;                 // C: col=lane&15, row=(lane>>4)*4+q
        if (ls == 0 && col < 40) *(f32x4*)&G[col][0] = acc;
    }
    __syncthreads();

    if (t < 40) {
        int h = t / 20, knbr = t % 20;
        int z0 = (knbr / 10) * 20 + 2 * (knbr % 10);
        lg[h][knbr] = (G[z0][h] + G[z0 + 1][2 + h]) * 0.0622573006f;   // 1/sqrt(258)
    }
    __syncthreads();
    if (t < 40) {
        int h = t / 20, knbr = t % 20;
        float m = lg[h][0];
        #pragma unroll
        for (int j = 1; j < 20; ++j) m = fmaxf(m, lg[h][j]);
        exs[h][knbr] = __expf(lg[h][knbr] - m);
    }
    __syncthreads();
    if (t < 2) {
        float s = 0.f;
        #pragma unroll
        for (int j = 0; j < 20; ++j) s += exs[t][j];
        float inv = 1.f / s;
        #pragma unroll
        for (int j = 0; j < 20; ++j) pp[t][j] = exs[t][j] * inv;
    }
    __syncthreads();

    // ZB: 288 tasks (nsel, 4-elem chunk); z read ONCE, both heads accumulated
    for (int idx = t; idx < 288; idx += 256) {
        int nsel = idx / 144, c4 = (idx % 144) * 4;
        float a0[4] = {0.f, 0.f, 0.f, 0.f};
        float a1[4] = {0.f, 0.f, 0.f, 0.f};
        #pragma unroll
        for (int knbr = 0; knbr < 20; ++knbr) {
            int z0 = (knbr / 10) * 20 + 2 * (knbr % 10) + nsel;
            bf16x4 zv = *(const bf16x4*)zsa(z0, c4);
            float p0 = pp[0][knbr], p1 = pp[1][knbr];
            #pragma unroll
            for (int i = 0; i < 4; ++i) {
                float zf = (float)zv[i];
                a0[i] += p0 * zf;
                a1[i] += p1 * zf;
            }
        }
        bf16x4 o0, o1;
        #pragma unroll
        for (int i = 0; i < 4; ++i) { o0[i] = (bf16)a0[i]; o1[i] = (bf16)a1[i]; }
        *(bf16x4*)(ZB + (size_t)(iA + nsel) * 1152 + c4)       = o0;   // head 0
        *(bf16x4*)(ZB + (size_t)(iA + nsel) * 1152 + 576 + c4) = o1;   // head 1
    }
}

// ---------------- LayerNorm + build X = [h_ln, node_h, 0pad] ----------------
__global__ __launch_bounds__(256)
void ln_x_kernel(const float* __restrict__ fcr, const float* __restrict__ g,
                 const float* __restrict__ b, const bf16* __restrict__ nh16,
                 bf16* __restrict__ X) {
    __shared__ float red[2][4];
    __shared__ float mb[2];
    const size_t i = blockIdx.x;
    const int t = threadIdx.x;
    int c0 = t, c1 = t + 256, c2 = t + 512;
    float v0 = fcr[i*516 + c0];
    float v1 = (c1 < 516) ? fcr[i*516 + c1] : 0.f;
    float v2 = (c2 < 516) ? fcr[i*516 + c2] : 0.f;
    float s = v0 + v1 + v2, ss = v0*v0 + v1*v1 + v2*v2;
    #pragma unroll
    for (int o = 32; o; o >>= 1) { s += __shfl_down(s, o); ss += __shfl_down(ss, o); }
    if ((t & 63) == 0) { red[0][t >> 6] = s; red[1][t >> 6] = ss; }
    __syncthreads();
    if (t == 0) {
        float S  = red[0][0] + red[0][1] + red[0][2] + red[0][3];
        float SS = red[1][0] + red[1][1] + red[1][2] + red[1][3];
        float mean = S / 516.f;
        float var  = SS / 516.f - mean*mean;
        mb[0] = mean; mb[1] = rsqrtf(var + 1e-5f);
    }
    __syncthreads();
    float mean = mb[0], rstd = mb[1];
    X[i*704 + c0] = (bf16)((v0 - mean)*rstd*g[c0] + b[c0]);
    if (c1 < 516) X[i*704 + c1] = (bf16)((v1 - mean)*rstd*g[c1] + b[c1]);
    if (c2 < 516) X[i*704 + c2] = (bf16)((v2 - mean)*rstd*g[c2] + b[c2]);
    for (int c = 516 + t; c < 704; c += 256)
        X[i*704 + c] = (c < 688) ? nh16[i*192 + (c - 516)] : (bf16)0.f;
}

// ---------------- fused M1(relu) + M2 -> d_out ----------------
__global__ __launch_bounds__(256)
void m1m2_kernel(const bf16* __restrict__ A, const bf16* __restrict__ B1,
                 const bf16* __restrict__ B2, const float* __restrict__ b1,
                 const float* __restrict__ b2, float* __restrict__ outF, int Mreal) {
    constexpr int KP = 704, NT = KP / BK;
    __shared__ __align__(16) union {
        struct { bf16 As[2][BM][BK]; bf16 Bs[2][BN][BK]; } g;   // 77824 B
        struct { bf16 Rs[BM][192];  bf16 B2s[BN][192]; } s;     // 116736 B
    } U;

    const int tid  = threadIdx.x;
    const int w    = tid >> 6;
    const int lane = tid & 63;
    const int lr   = lane & 15;
    const int ls   = lane >> 4;
    const int lrow = lane >> 3;
    const int lcol = (lane & 7) * 8;

    const bf16* aBase = A  + (size_t)(blockIdx.y * BM + w * 32 + lrow) * KP + lcol;
    const bf16* bBase = B1 + (size_t)lrow * KP + lcol;

    auto stage = [&](int buf, int k0) {
        #pragma unroll
        for (int i = 0; i < 4; ++i)
            gload16(aBase + (size_t)(i * 8) * KP + k0, &U.g.As[buf][w * 32 + i * 8][0]);
        #pragma unroll
        for (int jj = 0; jj < 6; ++jj) {
            int j = jj * 4 + w;
            if (j < 22) gload16(bBase + (size_t)(j * 8) * KP + k0, &U.g.Bs[buf][j * 8][0]);
        }
    };

    f32x4 acc[2][11];
    #pragma unroll
    for (int a = 0; a < 2; ++a)
        #pragma unroll
        for (int b = 0; b < 11; ++b) acc[a][b] = (f32x4)(0.0f);

    stage(0, 0);
    __syncthreads();
    int cur = 0;
    for (int t = 0; t < NT; ++t) {
        if (t + 1 < NT) stage(cur ^ 1, (t + 1) * BK);
        #pragma unroll
        for (int kk = 0; kk < 2; ++kk) {
            bf16x8 a0 = *(const bf16x8*)&U.g.As[cur][w*32 +      lr][kk*32 + ls*8];
            bf16x8 a1 = *(const bf16x8*)&U.g.As[cur][w*32 + 16 + lr][kk*32 + ls*8];
            #pragma unroll
            for (int nt = 0; nt < 11; ++nt) {
                bf16x8 bfr = *(const bf16x8*)&U.g.Bs[cur][nt*16 + lr][kk*32 + ls*8];
                acc[0][nt] = __builtin_amdgcn_mfma_f32_16x16x32_bf16(a0, bfr, acc[0][nt], 0, 0, 0);
                acc[1][nt] = __builtin_amdgcn_mfma_f32_16x16x32_bf16(a1, bfr, acc[1][nt], 0, 0, 0);
            }
        }
        __syncthreads();
        cur ^= 1;
    }

    // R tile -> LDS (relu + bias; cols>=172 zero), and DMA B2 into LDS
    #pragma unroll
    for (int mt = 0; mt < 2; ++mt)
    #pragma unroll
    for (int nt = 0; nt < 11; ++nt)
    #pragma unroll
    for (int q2 = 0; q2 < 4; ++q2) {
        int lro = w*32 + mt*16 + ls*4 + q2;
        int col = lr + nt*16;
        float vv = (col < 172) ? fmaxf(acc[mt][nt][q2] + b1[col], 0.f) : 0.f;
        U.s.Rs[lro][col] = (bf16)vv;
    }
    for (int idx = tid; idx < BM*16; idx += 256)
        U.s.Rs[idx >> 4][176 + (idx & 15)] = (bf16)0.f;
    // stage B2 [176][192] linearly: 66 chunks of 1024 B
    #pragma unroll
    for (int jj = 0; jj < 17; ++jj) {
        int j = jj * 4 + w;
        if (j < 66)
            gload16(B2 + (size_t)j*512 + lane*8, (bf16*)U.s.B2s + (size_t)j*512 + lane*8);
    }
    __syncthreads();

    // M2: K=192 (3 k-steps)
    f32x4 acc2[2][11];
    #pragma unroll
    for (int a = 0; a < 2; ++a)
        #pragma unroll
        for (int b = 0; b < 11; ++b) acc2[a][b] = (f32x4)(0.0f);
    #pragma unroll
    for (int t2 = 0; t2 < 3; ++t2) {
        #pragma unroll
        for (int kk = 0; kk < 2; ++kk) {
            int off = t2*64 + kk*32 + ls*8;
            bf16x8 a0 = *(const bf16x8*)&U.s.Rs[w*32 +      lr][off];
            bf16x8 a1 = *(const bf16x8*)&U.s.Rs[w*32 + 16 + lr][off];
            #pragma unroll
            for (int nt = 0; nt < 11; ++nt) {
                bf16x8 bfr = *(const bf16x8*)&U.s.B2s[nt*16 + lr][off];
                acc2[0][nt] = __builtin_amdgcn_mfma_f32_16x16x32_bf16(a0, bfr, acc2[0][nt], 0, 0, 0);
                acc2[1][nt] = __builtin_amdgcn_mfma_f32_16x16x32_bf16(a1, bfr, acc2[1][nt], 0, 0, 0);
            }
        }
    }

    const int rowb = blockIdx.y * BM + w*32 + ls*4;
    #pragma unroll
    for (int mt = 0; mt < 2; ++mt)
    #pragma unroll
    for (int nt = 0; nt < 11; ++nt)
    #pragma unroll
    for (int q2 = 0; q2 < 4; ++q2) {
        int row = rowb + mt*16 + q2;
        int col = lr + nt*16;
        if (row < Mreal && col < 172)
            outF[(size_t)row*172 + col] = acc2[mt][nt][q2] + b2[col];
    }
}

// ---------------- launch ----------------
extern "C" void kernel_launch(void* const* d_in, const int* in_sizes, int n_in,
                              void* d_out, int out_size, void* d_ws, size_t ws_size,
                              hipStream_t stream) {
    const float* node_h     = (const float*)d_in[0];
    const float* edge_t     = (const float*)d_in[1];
    const float* edge_feat  = (const float*)d_in[2];
    const int*   nbr_idx    = (const int*)d_in[3];
    const float* t_now      = (const float*)d_in[4];
    const float* w_q        = (const float*)d_in[6];
    const float* w_k        = (const float*)d_in[7];
    const float* w_v        = (const float*)d_in[8];
    const float* basis_freq = (const float*)d_in[9];
    const float* phase      = (const float*)d_in[10];
    const float* ln_g       = (const float*)d_in[11];
    const float* ln_b       = (const float*)d_in[12];
    const float* fc_w       = (const float*)d_in[13];
    const float* fc_b       = (const float*)d_in[14];
    const float* m1_w       = (const float*)d_in[15];
    const float* m1_b       = (const float*)d_in[16];
    const float* m2_w       = (const float*)d_in[17];
    const float* m2_b       = (const float*)d_in[18];

    char* ws = (char*)d_ws;
    bf16*  FCWT = (bf16*)(ws + FCWT_OFF);
    bf16*  M1WT = (bf16*)(ws + M1WT_OFF);
    bf16*  M2WT = (bf16*)(ws + M2WT_OFF);
    bf16*  WKH  = (bf16*)(ws + WKH_OFF);
    bf16*  WQHT = (bf16*)(ws + WQHT_OFF);
    bf16*  WVH  = (bf16*)(ws + WVH_OFF);
    bf16*  WQKT = (bf16*)(ws + WQKT_OFF);
    bf16*  WVFT = (bf16*)(ws + WVFT_OFF);
    float* QB   = (float*)(ws + QB_OFF);
    float* QKB  = (float*)(ws + QKB_OFF);
    float* CPH  = (float*)(ws + CPH_OFF);
    bf16*  NH16 = (bf16*)(ws + NH16_OFF);
    bf16*  QK   = (bf16*)(ws + QK_OFF);
    bf16*  ZB   = (bf16*)(ws + ZB_OFF);
    float* FCR  = (float*)(ws + FCR_OFF);
    bf16*  Xb   = (bf16*)(ws + X_OFF);

    hipMemsetAsync(ws, 0, NH16_OFF, stream);

    packT_kernel<<<dim3(289, 3), 256, 0, stream>>>(fc_w, m1_w, m2_w, FCWT, M1WT, M2WT);
    pack_misc_kernel<<<2048, 256, 0, stream>>>(w_k, w_q, w_v, node_h, phase,
                                               WKH, WQHT, WVH, NH16, CPH);
    qbias_kernel<<<516, 256, 0, stream>>>(w_q, phase, QB);
    qkb_kernel<<<1152, 256, 0, stream>>>(w_k, QB, QKB);

    // WQK^T (z=0,1) and WVF^T (z=2,3) in one launch
    gemm_multi_kernel<<<dim3(4, 5, 4), 256, 0, stream>>>(WKH, WQHT, FCWT, WVH, WQKT, WVFT);

    // qk = NH16 @ WQK^T + qkb   -> QK [NPAD][1152]
    gemm_kernel<192, 0><<<dim3(7, 79), 256, 0, stream>>>(
        NH16, 192, WQKT, nullptr, QK, 1152, QKB, nullptr, nullptr, NN, 1152);

    // attention (z built in LDS, MFMA logits) -> ZB [NPAD][1152]
    attn_lite_kernel<<<NN / 2, 256, 0, stream>>>(
        QK, NH16, edge_feat, edge_t, nbr_idx, basis_freq, phase, t_now, ZB);

    // fcr = ZB @ WVF^T + fc_b + self_z
    gemm_kernel<1152, 2><<<dim3(3, 79), 256, 0, stream>>>(
        ZB, 1152, WVFT, FCR, nullptr, 516, fc_b, node_h, CPH, NN, 516);

    ln_x_kernel<<<NN, 256, 0, stream>>>(FCR, ln_g, ln_b, NH16, Xb);

    // fused m1(relu) + m2 -> out
    m1m2_kernel<<<dim3(1, 79), 256, 0, stream>>>(
        Xb, M1WT, M2WT, m1_b, m2_b, (float*)d_out, NN);
}

// Round 10
// 263.174 us; speedup vs baseline: 10.1722x; 1.1640x over previous
//
#include <hip/hip_runtime.h>
#include <hip/hip_bf16.h>
#include <math.h>

typedef __bf16 bf16;
typedef __attribute__((ext_vector_type(4))) __bf16 bf16x4;
typedef __attribute__((ext_vector_type(8))) __bf16 bf16x8;
typedef __attribute__((ext_vector_type(4))) float f32x4;

// ---------------- problem constants ----------------
constexpr int NN   = 10000;
constexpr int NPAD = 10112;            // 128-aligned (DMA overrun pad)
constexpr int BM = 128, BN = 176, BK = 64;

// ---------------- workspace layout (bytes) ----------------
constexpr size_t FCWT_OFF = 0;                         // bf16 [528][576]   fcw^T (zero-padded)
constexpr size_t M1WT_OFF = 608256;                    // bf16 [176][704]
constexpr size_t M2WT_OFF = 856064;                    // bf16 [176][192]
constexpr size_t WKH_OFF  = 923648;                    // bf16 [2*576][320] wk head-slices
constexpr size_t WQHT_OFF = 1660928;                   // bf16 [2*352][320] wq head-slices (rows<172)
constexpr size_t WVH_OFF  = 2111488;                   // bf16 [2*704][320] wv head-slices
constexpr size_t WQKT_OFF = 3012608;                   // bf16 [1232][192]  WQK^T (qk GEMM B)
constexpr size_t WVFT_OFF = 3485696;                   // bf16 [528][1152]  WVF^T (fusedFC B)
constexpr size_t QB_OFF   = 4702208;                   // f32 [516]
constexpr size_t QKB_OFF  = 4706304;                   // f32 [1232]
constexpr size_t CPH_OFF  = 4714496;                   // f32 [172]
constexpr size_t NH16_OFF = 4715520;                   // bf16 [NPAD][192]
constexpr size_t QK_OFF   = NH16_OFF + (size_t)NPAD*192*2;    // bf16 [NPAD][1152]
constexpr size_t ZB_OFF   = QK_OFF   + (size_t)NPAD*1152*2;   // bf16 [NPAD][1152]
constexpr size_t FCR_OFF  = ZB_OFF   + (size_t)NPAD*1152*2;   // f32 [NN][516]
constexpr size_t X_OFF    = FCR_OFF  + (size_t)NN*516*4;      // bf16 [NPAD][704]

// ---------------- global_load_lds helper (width 16) ----------------
typedef __attribute__((address_space(3))) void lds_void;
typedef const __attribute__((address_space(1))) void glb_void;
__device__ __forceinline__ void gload16(const void* g, void* l) {
    __builtin_amdgcn_global_load_lds((glb_void*)(uintptr_t)g,
                                     (lds_void*)(unsigned int)(uintptr_t)l, 16, 0, 0);
}

// ---------------- tiled transpose-pack (fcw, m1w, m2w) ----------------
__global__ __launch_bounds__(256)
void packT_kernel(const float* __restrict__ fcw, const float* __restrict__ m1w,
                  const float* __restrict__ m2w,
                  bf16* __restrict__ FCWT, bf16* __restrict__ M1WT, bf16* __restrict__ M2WT) {
    __shared__ float tile[32][33];
    const float* src; bf16* dst; int K, C, LD;
    switch (blockIdx.y) {
        case 0:  src = fcw; K = 516; C = 516; dst = FCWT; LD = 576; break;
        case 1:  src = m1w; K = 688; C = 172; dst = M1WT; LD = 704; break;
        default: src = m2w; K = 172; C = 172; dst = M2WT; LD = 192; break;
    }
    const int tilesC = (C + 31) >> 5, tilesK = (K + 31) >> 5;
    const int nt = tilesC * tilesK;
    const int tx = threadIdx.x & 31, ty = threadIdx.x >> 5;
    for (int tb = blockIdx.x; tb < nt; tb += gridDim.x) {
        int tc = tb % tilesC, tk = tb / tilesC;
        #pragma unroll
        for (int i = 0; i < 4; ++i) {
            int k = tk*32 + ty + i*8, c = tc*32 + tx;
            tile[ty + i*8][tx] = (k < K && c < C) ? src[(size_t)k*C + c] : 0.f;
        }
        __syncthreads();
        #pragma unroll
        for (int i = 0; i < 4; ++i) {
            int c = tc*32 + ty + i*8, k = tk*32 + tx;
            if (c < C && k < K) dst[(size_t)c*LD + k] = (bf16)tile[tx][ty + i*8];
        }
        __syncthreads();
    }
}

// ---------------- fused misc packs: wk/wq/wv head-slices + nh16 + cph ----------------
__global__ void pack_misc_kernel(const float* __restrict__ wk, const float* __restrict__ wq,
                                 const float* __restrict__ wv, const float* __restrict__ node_h,
                                 const float* __restrict__ phase,
                                 bf16* __restrict__ WKH, bf16* __restrict__ WQHT,
                                 bf16* __restrict__ WVH, bf16* __restrict__ nh16,
                                 float* __restrict__ cph) {
    constexpr int T0 = 2*516*258;
    constexpr int T1 = T0 + 2*172*258;
    constexpr int T2 = T1 + 2*516*258;
    constexpr int T3 = T2 + NN*192;
    constexpr int T4 = T3 + 172;
    for (int idx = blockIdx.x * blockDim.x + threadIdx.x; idx < T4;
         idx += gridDim.x * blockDim.x) {
        if (idx < T0) {
            int h = idx / (516*258), rem = idx % (516*258), d = rem / 258, j = rem % 258;
            WKH[((size_t)h*576 + d)*320 + j] = (bf16)wk[(size_t)d*516 + h*258 + j];
        } else if (idx < T1) {
            int i = idx - T0;
            int h = i / (172*258), rem = i % (172*258), k = rem / 258, j = rem % 258;
            WQHT[((size_t)h*352 + k)*320 + j] = (bf16)wq[(size_t)k*516 + h*258 + j];
        } else if (idx < T2) {
            int i = idx - T1;
            int h = i / (516*258), rem = i % (516*258), c = rem / 258, j = rem % 258;
            WVH[((size_t)h*704 + c)*320 + j] = (bf16)wv[(size_t)c*516 + h*258 + j];
        } else if (idx < T3) {
            int i = idx - T2, r = i / 192, c = i % 192;
            nh16[i] = (c < 172) ? (bf16)node_h[(size_t)r*172 + c] : (bf16)0.f;
        } else cph[idx - T3] = cosf(phase[idx - T3]);
    }
}

// QB[c] = sum_j cos(phase[j]) * w_q[(344+j)*516 + c]
__global__ __launch_bounds__(256)
void qbias_kernel(const float* __restrict__ w_q, const float* __restrict__ phase,
                  float* __restrict__ q_bias) {
    __shared__ float red[256];
    const int c = blockIdx.x, j = threadIdx.x;
    red[j] = (j < 172) ? cosf(phase[j]) * w_q[(size_t)(344 + j) * 516 + c] : 0.f;
    __syncthreads();
    #pragma unroll
    for (int o = 128; o; o >>= 1) { if (j < o) red[j] += red[j + o]; __syncthreads(); }
    if (j == 0) q_bias[c] = red[0];
}

// qkb[h*576+d] = sum_{j<258} QB[h*258+j] * wk[d][h*258+j]   (d<516, else 0)
__global__ __launch_bounds__(256)
void qkb_kernel(const float* __restrict__ wk, const float* __restrict__ QB,
                float* __restrict__ qkb) {
    __shared__ float red[256];
    const int hd = blockIdx.x, h = hd / 576, d = hd % 576, t = threadIdx.x;
    float a = 0.f;
    if (d < 516) {
        a = QB[h*258 + t] * wk[(size_t)d*516 + h*258 + t];
        if (t < 2) a += QB[h*258 + 256 + t] * wk[(size_t)d*516 + h*258 + 256 + t];
    }
    red[t] = a; __syncthreads();
    #pragma unroll
    for (int o = 128; o; o >>= 1) { if (t < o) red[t] += red[t + o]; __syncthreads(); }
    if (t == 0) qkb[hd] = red[0];
}

// ---------------- MFMA GEMM (DMA staging + 2-phase dbuf), runtime lda/ldo ----------------
// EPI 0: bf16 out +bias    EPI 2: f32 out +bias +selfz
template<int KP, int EPI>
__global__ __launch_bounds__(256, 2)
void gemm_kernel(const bf16* __restrict__ A, int lda, const bf16* __restrict__ Bt,
                 float* __restrict__ outF, bf16* __restrict__ outB, int ldo,
                 const float* __restrict__ bias,
                 const float* __restrict__ aux0, const float* __restrict__ aux1,
                 int Mreal, int Nreal) {
    constexpr int NT = KP / BK;
    __shared__ __align__(16) bf16 As[2][BM][BK];
    __shared__ __align__(16) bf16 Bs[2][BN][BK];

    const int tid  = threadIdx.x;
    const int w    = tid >> 6;
    const int lane = tid & 63;
    const int lr   = lane & 15;
    const int ls   = lane >> 4;
    const int lrow = lane >> 3;
    const int lcol = (lane & 7) * 8;

    const bf16* aBase = A  + (size_t)(blockIdx.y * BM + w * 32 + lrow) * lda + lcol;
    const bf16* bBase = Bt + (size_t)(blockIdx.x * BN + lrow) * KP + lcol;

    auto stage = [&](int buf, int k0) {
        #pragma unroll
        for (int i = 0; i < 4; ++i)
            gload16(aBase + (size_t)(i * 8) * lda + k0, &As[buf][w * 32 + i * 8][0]);
        #pragma unroll
        for (int jj = 0; jj < 6; ++jj) {
            int j = jj * 4 + w;
            if (j < 22) gload16(bBase + (size_t)(j * 8) * KP + k0, &Bs[buf][j * 8][0]);
        }
    };

    f32x4 acc[2][11];
    #pragma unroll
    for (int a = 0; a < 2; ++a)
        #pragma unroll
        for (int b2 = 0; b2 < 11; ++b2) acc[a][b2] = (f32x4)(0.0f);

    stage(0, 0);
    __syncthreads();
    int cur = 0;
    for (int t = 0; t < NT; ++t) {
        if (t + 1 < NT) stage(cur ^ 1, (t + 1) * BK);
        #pragma unroll
        for (int kk = 0; kk < 2; ++kk) {
            bf16x8 a0 = *(const bf16x8*)&As[cur][w*32 +      lr][kk*32 + ls*8];
            bf16x8 a1 = *(const bf16x8*)&As[cur][w*32 + 16 + lr][kk*32 + ls*8];
            #pragma unroll
            for (int nt = 0; nt < 11; ++nt) {
                bf16x8 bfr = *(const bf16x8*)&Bs[cur][nt*16 + lr][kk*32 + ls*8];
                acc[0][nt] = __builtin_amdgcn_mfma_f32_16x16x32_bf16(a0, bfr, acc[0][nt], 0, 0, 0);
                acc[1][nt] = __builtin_amdgcn_mfma_f32_16x16x32_bf16(a1, bfr, acc[1][nt], 0, 0, 0);
            }
        }
        __syncthreads();
        cur ^= 1;
    }

    const int colb = blockIdx.x * BN + lr;
    const int rowb = blockIdx.y * BM + w*32 + ls*4;
    #pragma unroll
    for (int mt = 0; mt < 2; ++mt)
    #pragma unroll
    for (int nt = 0; nt < 11; ++nt)
    #pragma unroll
    for (int q2 = 0; q2 < 4; ++q2) {
        int row = rowb + mt*16 + q2;
        int col = colb + nt*16;
        if (row >= Mreal) continue;
        float v = acc[mt][nt][q2];
        if constexpr (EPI == 0) {
            if (col < Nreal) outB[(size_t)row*ldo + col] = (bf16)(v + bias[col]);
        } else {
            if (col < Nreal) {
                float sz = (col < 172) ? aux0[(size_t)row*172 + col]
                                       : ((col < 344) ? 0.f : aux1[col - 344]);
                outF[(size_t)row*ldo + col] = v + bias[col] + sz;
            }
        }
    }
}

// ---------------- combined WQK/WVF GEMMs (KP=320, bf16 plain out), blockIdx.z selects ----------------
__global__ __launch_bounds__(256, 2)
void gemm_multi_kernel(const bf16* __restrict__ WKH, const bf16* __restrict__ WQHT,
                       const bf16* __restrict__ FCWT, const bf16* __restrict__ WVH,
                       bf16* __restrict__ WQKT, bf16* __restrict__ WVFT) {
    constexpr int KP = 320, NT = KP / BK;
    const int z = blockIdx.z, h = z & 1;
    const bf16 *A, *Bt; bf16* outB; int lda, ldo, Mreal, Nreal;
    if (z < 2) {
        if (blockIdx.x >= 2) return;
        A = WKH + (size_t)h*576*320;  lda = 320;
        Bt = WQHT + (size_t)h*352*320;
        outB = WQKT + (size_t)h*576*192; ldo = 192; Mreal = 576; Nreal = 192;
    } else {
        A = FCWT + (size_t)h*258;     lda = 576;
        Bt = WVH + (size_t)h*704*320;
        outB = WVFT + (size_t)h*576;  ldo = 1152; Mreal = 516; Nreal = 576;
    }
    __shared__ __align__(16) bf16 As[2][BM][BK];
    __shared__ __align__(16) bf16 Bs[2][BN][BK];
    const int tid = threadIdx.x, w = tid >> 6, lane = tid & 63;
    const int lr = lane & 15, ls = lane >> 4;
    const int lrow = lane >> 3, lcol = (lane & 7) * 8;
    const bf16* aBase = A  + (size_t)(blockIdx.y * BM + w * 32 + lrow) * lda + lcol;
    const bf16* bBase = Bt + (size_t)(blockIdx.x * BN + lrow) * KP + lcol;
    auto stage = [&](int buf, int k0) {
        #pragma unroll
        for (int i = 0; i < 4; ++i)
            gload16(aBase + (size_t)(i * 8) * lda + k0, &As[buf][w * 32 + i * 8][0]);
        #pragma unroll
        for (int jj = 0; jj < 6; ++jj) {
            int j = jj * 4 + w;
            if (j < 22) gload16(bBase + (size_t)(j * 8) * KP + k0, &Bs[buf][j * 8][0]);
        }
    };
    f32x4 acc[2][11];
    #pragma unroll
    for (int a = 0; a < 2; ++a)
        #pragma unroll
        for (int b2 = 0; b2 < 11; ++b2) acc[a][b2] = (f32x4)(0.0f);
    stage(0, 0);
    __syncthreads();
    int cur = 0;
    for (int t = 0; t < NT; ++t) {
        if (t + 1 < NT) stage(cur ^ 1, (t + 1) * BK);
        #pragma unroll
        for (int kk = 0; kk < 2; ++kk) {
            bf16x8 a0 = *(const bf16x8*)&As[cur][w*32 +      lr][kk*32 + ls*8];
            bf16x8 a1 = *(const bf16x8*)&As[cur][w*32 + 16 + lr][kk*32 + ls*8];
            #pragma unroll
            for (int nt = 0; nt < 11; ++nt) {
                bf16x8 bfr = *(const bf16x8*)&Bs[cur][nt*16 + lr][kk*32 + ls*8];
                acc[0][nt] = __builtin_amdgcn_mfma_f32_16x16x32_bf16(a0, bfr, acc[0][nt], 0, 0, 0);
                acc[1][nt] = __builtin_amdgcn_mfma_f32_16x16x32_bf16(a1, bfr, acc[1][nt], 0, 0, 0);
            }
        }
        __syncthreads();
        cur ^= 1;
    }
    const int colb = blockIdx.x * BN + lr;
    const int rowb = blockIdx.y * BM + w*32 + ls*4;
    #pragma unroll
    for (int mt = 0; mt < 2; ++mt)
    #pragma unroll
    for (int nt = 0; nt < 11; ++nt)
    #pragma unroll
    for (int q2 = 0; q2 < 4; ++q2) {
        int row = rowb + mt*16 + q2;
        int col = colb + nt*16;
        if (row < Mreal && col < Nreal)
            outB[(size_t)row*ldo + col] = (bf16)acc[mt][nt][q2];
    }
}

// ---------------- attention-lite v5: segment-uniform z-build, direct-global MFMA A ----------------
__global__ __launch_bounds__(256, 3)
void attn_lite_kernel(const bf16* __restrict__ QK, const bf16* __restrict__ nh16,
                      const float* __restrict__ edge_feat, const float* __restrict__ edge_t,
                      const int* __restrict__ nbr_idx, const float* __restrict__ freq,
                      const float* __restrict__ ph, const float* __restrict__ tnow,
                      bf16* __restrict__ ZB) {
    __shared__ __align__(16) bf16 zs[40 * 576];    // XOR-swizzled rows (pitch 1152 B)
    __shared__ __align__(16) float G[40][4];
    __shared__ float sfreq[172], sph[172];
    __shared__ float sdt[40];
    __shared__ int   ssrc[40];
    __shared__ float pp[2][20];

    const int r  = blockIdx.x;
    const int iA = 2 * r;
    const int t  = threadIdx.x;
    const int w  = t >> 6, lane = t & 63;
    const int lr = lane & 15, ls = lane >> 4;

    // swizzled LDS addressing: zs row pitch 1152 B, XOR bits 4-6 with row&7
    auto zsa = [&](int row, int c) -> bf16* {
        unsigned b = (unsigned)(row * 1152 + c * 2) ^ (unsigned)((row & 7) << 4);
        return (bf16*)((char*)zs + b);
    };

    if (t < 172) { sfreq[t] = freq[t]; sph[t] = ph[t]; }
    if (t >= 192 && t < 232) {
        int e2 = t - 192, ge = iA * 20 + e2;
        sdt[e2]  = tnow[0] - edge_t[ge];
        ssrc[e2] = nbr_idx[ge];
    }
    __syncthreads();

    // z-build: segment-major flat index -> waves are branch-uniform.
    // [0,880): nh+mix (row=i/22, c=i%22)   [880,1720): ef (row=i2/21, c=22+i2%21)
    // [1720,2600): tenc (row=i3/22, c=43+i3%22)   [2600,2880): zero (row=i4/7, c=65+i4%7)
    #pragma unroll
    for (int it = 0; it < 12; ++it) {
        int idx = t + it * 256;
        if (idx < 2880) {
            int row, c;
            bf16x8 v;
            if (idx < 880) {
                row = idx / 22; c = idx % 22;
                int ge = iA * 20 + row;
                if (c < 21) {
                    v = *(const bf16x8*)(nh16 + (size_t)ssrc[row] * 192 + c * 8);
                } else {
                    #pragma unroll
                    for (int e = 0; e < 8; ++e) {
                        int k = 168 + e;
                        v[e] = (k < 172) ? nh16[(size_t)ssrc[row] * 192 + k]
                                         : (bf16)edge_feat[(size_t)ge * 172 + (k - 172)];
                    }
                }
            } else if (idx < 1720) {
                int i2 = idx - 880;
                row = i2 / 21; c = 22 + i2 % 21;
                int ge = iA * 20 + row;
                const float* ep = edge_feat + (size_t)ge * 172 + (c * 8 - 172);
                f32x4 a = *(const f32x4*)ep;
                f32x4 b = *(const f32x4*)(ep + 4);
                #pragma unroll
                for (int e = 0; e < 4; ++e) { v[e] = (bf16)a[e]; v[e+4] = (bf16)b[e]; }
            } else if (idx < 2600) {
                int i3 = idx - 1720;
                row = i3 / 22; c = 43 + i3 % 22;
                float dt = sdt[row];
                int k0 = c * 8;
                #pragma unroll
                for (int e = 0; e < 8; ++e) {
                    int k = k0 + e;
                    v[e] = (k < 516) ? (bf16)__cosf(dt * sfreq[k - 344] + sph[k - 344]) : (bf16)0.f;
                }
            } else {
                int i4 = idx - 2600;
                row = i4 / 7; c = 65 + i4 % 7;
                #pragma unroll
                for (int e = 0; e < 8; ++e) v[e] = (bf16)0.f;
            }
            *(bf16x8*)zsa(row, c * 8) = v;
        }
    }
    __syncthreads();

    // MFMA logits: G[4 x 40] = qk(4x576) . zs^T ; A-fragments direct from global QK
    if (w < 3) {
        int brow = w * 16 + lr; if (brow > 39) brow = 39;   // clamp: cols>=40 discarded
        // A row m = lr&3:  QK[(iA + ((lr>>1)&1))*1152 + (lr&1)*576 + k]
        const bf16* aQK = QK + (size_t)(iA + ((lr >> 1) & 1)) * 1152 + (lane & 1) * 576;
        f32x4 acc = (f32x4)(0.0f);
        __builtin_amdgcn_s_setprio(1);
        #pragma unroll
        for (int ks = 0; ks < 18; ++ks) {
            bf16x8 af = *(const bf16x8*)(aQK + ks * 32 + ls * 8);
            bf16x8 bf = *(const bf16x8*)zsa(brow, ks * 32 + ls * 8);
            acc = __builtin_amdgcn_mfma_f32_16x16x32_bf16(af, bf, acc, 0, 0, 0);
        }
        __builtin_amdgcn_s_setprio(0);
        int col = w * 16 + lr;                 // C: col=lane&15, row=(lane>>4)*4+q
        if (ls == 0 && col < 40) *(f32x4*)&G[col][0] = acc;
    }
    __syncthreads();

    // softmax, single phase (t<2: one head each)
    if (t < 2) {
        const int h = t;
        float l[20];
        #pragma unroll
        for (int knbr = 0; knbr < 20; ++knbr) {
            int z0 = (knbr / 10) * 20 + 2 * (knbr % 10);
            l[knbr] = (G[z0][h] + G[z0 + 1][2 + h]) * 0.0622573006f;   // 1/sqrt(258)
        }
        float m = l[0];
        #pragma unroll
        for (int j = 1; j < 20; ++j) m = fmaxf(m, l[j]);
        float s = 0.f;
        #pragma unroll
        for (int j = 0; j < 20; ++j) { l[j] = __expf(l[j] - m); s += l[j]; }
        float inv = 1.f / s;
        #pragma unroll
        for (int j = 0; j < 20; ++j) pp[h][j] = l[j] * inv;
    }
    __syncthreads();

    // ZB: 288 tasks (nsel, 4-elem chunk); z read ONCE, both heads accumulated
    #pragma unroll
    for (int it = 0; it < 2; ++it) {
        int idx = t + it * 256;
        if (idx < 288) {
            int nsel = idx / 144, c4 = (idx % 144) * 4;
            float a0[4] = {0.f, 0.f, 0.f, 0.f};
            float a1[4] = {0.f, 0.f, 0.f, 0.f};
            #pragma unroll
            for (int knbr = 0; knbr < 20; ++knbr) {
                int z0 = (knbr / 10) * 20 + 2 * (knbr % 10) + nsel;
                bf16x4 zv = *(const bf16x4*)zsa(z0, c4);
                float p0 = pp[0][knbr], p1 = pp[1][knbr];
                #pragma unroll
                for (int i = 0; i < 4; ++i) {
                    float zf = (float)zv[i];
                    a0[i] += p0 * zf;
                    a1[i] += p1 * zf;
                }
            }
            bf16x4 o0, o1;
            #pragma unroll
            for (int i = 0; i < 4; ++i) { o0[i] = (bf16)a0[i]; o1[i] = (bf16)a1[i]; }
            *(bf16x4*)(ZB + (size_t)(iA + nsel) * 1152 + c4)       = o0;   // head 0
            *(bf16x4*)(ZB + (size_t)(iA + nsel) * 1152 + 576 + c4) = o1;   // head 1
        }
    }
}

// ---------------- LayerNorm + build X = [h_ln, node_h, 0pad] ----------------
__global__ __launch_bounds__(256)
void ln_x_kernel(const float* __restrict__ fcr, const float* __restrict__ g,
                 const float* __restrict__ b, const bf16* __restrict__ nh16,
                 bf16* __restrict__ X) {
    __shared__ float red[2][4];
    __shared__ float mb[2];
    const size_t i = blockIdx.x;
    const int t = threadIdx.x;
    int c0 = t, c1 = t + 256, c2 = t + 512;
    float v0 = fcr[i*516 + c0];
    float v1 = (c1 < 516) ? fcr[i*516 + c1] : 0.f;
    float v2 = (c2 < 516) ? fcr[i*516 + c2] : 0.f;
    float s = v0 + v1 + v2, ss = v0*v0 + v1*v1 + v2*v2;
    #pragma unroll
    for (int o = 32; o; o >>= 1) { s += __shfl_down(s, o); ss += __shfl_down(ss, o); }
    if ((t & 63) == 0) { red[0][t >> 6] = s; red[1][t >> 6] = ss; }
    __syncthreads();
    if (t == 0) {
        float S  = red[0][0] + red[0][1] + red[0][2] + red[0][3];
        float SS = red[1][0] + red[1][1] + red[1][2] + red[1][3];
        float mean = S / 516.f;
        float var  = SS / 516.f - mean*mean;
        mb[0] = mean; mb[1] = rsqrtf(var + 1e-5f);
    }
    __syncthreads();
    float mean = mb[0], rstd = mb[1];
    X[i*704 + c0] = (bf16)((v0 - mean)*rstd*g[c0] + b[c0]);
    if (c1 < 516) X[i*704 + c1] = (bf16)((v1 - mean)*rstd*g[c1] + b[c1]);
    if (c2 < 516) X[i*704 + c2] = (bf16)((v2 - mean)*rstd*g[c2] + b[c2]);
    for (int c = 516 + t; c < 704; c += 256)
        X[i*704 + c] = (c < 688) ? nh16[i*192 + (c - 516)] : (bf16)0.f;
}

// ---------------- fused M1(relu) + M2 -> d_out ----------------
__global__ __launch_bounds__(256)
void m1m2_kernel(const bf16* __restrict__ A, const bf16* __restrict__ B1,
                 const bf16* __restrict__ B2, const float* __restrict__ b1,
                 const float* __restrict__ b2, float* __restrict__ outF, int Mreal) {
    constexpr int KP = 704, NT = KP / BK;
    __shared__ __align__(16) union {
        struct { bf16 As[2][BM][BK]; bf16 Bs[2][BN][BK]; } g;   // 77824 B
        struct { bf16 Rs[BM][192];  bf16 B2s[BN][192]; } s;     // 116736 B
    } U;

    const int tid  = threadIdx.x;
    const int w    = tid >> 6;
    const int lane = tid & 63;
    const int lr   = lane & 15;
    const int ls   = lane >> 4;
    const int lrow = lane >> 3;
    const int lcol = (lane & 7) * 8;

    const bf16* aBase = A  + (size_t)(blockIdx.y * BM + w * 32 + lrow) * KP + lcol;
    const bf16* bBase = B1 + (size_t)lrow * KP + lcol;

    auto stage = [&](int buf, int k0) {
        #pragma unroll
        for (int i = 0; i < 4; ++i)
            gload16(aBase + (size_t)(i * 8) * KP + k0, &U.g.As[buf][w * 32 + i * 8][0]);
        #pragma unroll
        for (int jj = 0; jj < 6; ++jj) {
            int j = jj * 4 + w;
            if (j < 22) gload16(bBase + (size_t)(j * 8) * KP + k0, &U.g.Bs[buf][j * 8][0]);
        }
    };

    f32x4 acc[2][11];
    #pragma unroll
    for (int a = 0; a < 2; ++a)
        #pragma unroll
        for (int b = 0; b < 11; ++b) acc[a][b] = (f32x4)(0.0f);

    stage(0, 0);
    __syncthreads();
    int cur = 0;
    for (int t = 0; t < NT; ++t) {
        if (t + 1 < NT) stage(cur ^ 1, (t + 1) * BK);
        #pragma unroll
        for (int kk = 0; kk < 2; ++kk) {
            bf16x8 a0 = *(const bf16x8*)&U.g.As[cur][w*32 +      lr][kk*32 + ls*8];
            bf16x8 a1 = *(const bf16x8*)&U.g.As[cur][w*32 + 16 + lr][kk*32 + ls*8];
            #pragma unroll
            for (int nt = 0; nt < 11; ++nt) {
                bf16x8 bfr = *(const bf16x8*)&U.g.Bs[cur][nt*16 + lr][kk*32 + ls*8];
                acc[0][nt] = __builtin_amdgcn_mfma_f32_16x16x32_bf16(a0, bfr, acc[0][nt], 0, 0, 0);
                acc[1][nt] = __builtin_amdgcn_mfma_f32_16x16x32_bf16(a1, bfr, acc[1][nt], 0, 0, 0);
            }
        }
        __syncthreads();
        cur ^= 1;
    }

    // R tile -> LDS (relu + bias; cols>=172 zero), and DMA B2 into LDS
    #pragma unroll
    for (int mt = 0; mt < 2; ++mt)
    #pragma unroll
    for (int nt = 0; nt < 11; ++nt)
    #pragma unroll
    for (int q2 = 0; q2 < 4; ++q2) {
        int lro = w*32 + mt*16 + ls*4 + q2;
        int col = lr + nt*16;
        float vv = (col < 172) ? fmaxf(acc[mt][nt][q2] + b1[col], 0.f) : 0.f;
        U.s.Rs[lro][col] = (bf16)vv;
    }
    for (int idx = tid; idx < BM*16; idx += 256)
        U.s.Rs[idx >> 4][176 + (idx & 15)] = (bf16)0.f;
    // stage B2 [176][192] linearly: 66 chunks of 1024 B
    #pragma unroll
    for (int jj = 0; jj < 17; ++jj) {
        int j = jj * 4 + w;
        if (j < 66)
            gload16(B2 + (size_t)j*512 + lane*8, (bf16*)U.s.B2s + (size_t)j*512 + lane*8);
    }
    __syncthreads();

    // M2: K=192 (3 k-steps)
    f32x4 acc2[2][11];
    #pragma unroll
    for (int a = 0; a < 2; ++a)
        #pragma unroll
        for (int b = 0; b < 11; ++b) acc2[a][b] = (f32x4)(0.0f);
    #pragma unroll
    for (int t2 = 0; t2 < 3; ++t2) {
        #pragma unroll
        for (int kk = 0; kk < 2; ++kk) {
            int off = t2*64 + kk*32 + ls*8;
            bf16x8 a0 = *(const bf16x8*)&U.s.Rs[w*32 +      lr][off];
            bf16x8 a1 = *(const bf16x8*)&U.s.Rs[w*32 + 16 + lr][off];
            #pragma unroll
            for (int nt = 0; nt < 11; ++nt) {
                bf16x8 bfr = *(const bf16x8*)&U.s.B2s[nt*16 + lr][off];
                acc2[0][nt] = __builtin_amdgcn_mfma_f32_16x16x32_bf16(a0, bfr, acc2[0][nt], 0, 0, 0);
                acc2[1][nt] = __builtin_amdgcn_mfma_f32_16x16x32_bf16(a1, bfr, acc2[1][nt], 0, 0, 0);
            }
        }
    }

    const int rowb = blockIdx.y * BM + w*32 + ls*4;
    #pragma unroll
    for (int mt = 0; mt < 2; ++mt)
    #pragma unroll
    for (int nt = 0; nt < 11; ++nt)
    #pragma unroll
    for (int q2 = 0; q2 < 4; ++q2) {
        int row = rowb + mt*16 + q2;
        int col = lr + nt*16;
        if (row < Mreal && col < 172)
            outF[(size_t)row*172 + col] = acc2[mt][nt][q2] + b2[col];
    }
}

// ---------------- launch ----------------
extern "C" void kernel_launch(void* const* d_in, const int* in_sizes, int n_in,
                              void* d_out, int out_size, void* d_ws, size_t ws_size,
                              hipStream_t stream) {
    const float* node_h     = (const float*)d_in[0];
    const float* edge_t     = (const float*)d_in[1];
    const float* edge_feat  = (const float*)d_in[2];
    const int*   nbr_idx    = (const int*)d_in[3];
    const float* t_now      = (const float*)d_in[4];
    const float* w_q        = (const float*)d_in[6];
    const float* w_k        = (const float*)d_in[7];
    const float* w_v        = (const float*)d_in[8];
    const float* basis_freq = (const float*)d_in[9];
    const float* phase      = (const float*)d_in[10];
    const float* ln_g       = (const float*)d_in[11];
    const float* ln_b       = (const float*)d_in[12];
    const float* fc_w       = (const float*)d_in[13];
    const float* fc_b       = (const float*)d_in[14];
    const float* m1_w       = (const float*)d_in[15];
    const float* m1_b       = (const float*)d_in[16];
    const float* m2_w       = (const float*)d_in[17];
    const float* m2_b       = (const float*)d_in[18];

    char* ws = (char*)d_ws;
    bf16*  FCWT = (bf16*)(ws + FCWT_OFF);
    bf16*  M1WT = (bf16*)(ws + M1WT_OFF);
    bf16*  M2WT = (bf16*)(ws + M2WT_OFF);
    bf16*  WKH  = (bf16*)(ws + WKH_OFF);
    bf16*  WQHT = (bf16*)(ws + WQHT_OFF);
    bf16*  WVH  = (bf16*)(ws + WVH_OFF);
    bf16*  WQKT = (bf16*)(ws + WQKT_OFF);
    bf16*  WVFT = (bf16*)(ws + WVFT_OFF);
    float* QB   = (float*)(ws + QB_OFF);
    float* QKB  = (float*)(ws + QKB_OFF);
    float* CPH  = (float*)(ws + CPH_OFF);
    bf16*  NH16 = (bf16*)(ws + NH16_OFF);
    bf16*  QK   = (bf16*)(ws + QK_OFF);
    bf16*  ZB   = (bf16*)(ws + ZB_OFF);
    float* FCR  = (float*)(ws + FCR_OFF);
    bf16*  Xb   = (bf16*)(ws + X_OFF);

    hipMemsetAsync(ws, 0, NH16_OFF, stream);

    packT_kernel<<<dim3(289, 3), 256, 0, stream>>>(fc_w, m1_w, m2_w, FCWT, M1WT, M2WT);
    pack_misc_kernel<<<2048, 256, 0, stream>>>(w_k, w_q, w_v, node_h, phase,
                                               WKH, WQHT, WVH, NH16, CPH);
    qbias_kernel<<<516, 256, 0, stream>>>(w_q, phase, QB);
    qkb_kernel<<<1152, 256, 0, stream>>>(w_k, QB, QKB);

    // WQK^T (z=0,1) and WVF^T (z=2,3) in one launch
    gemm_multi_kernel<<<dim3(4, 5, 4), 256, 0, stream>>>(WKH, WQHT, FCWT, WVH, WQKT, WVFT);

    // qk = NH16 @ WQK^T + qkb   -> QK [NPAD][1152]
    gemm_kernel<192, 0><<<dim3(7, 79), 256, 0, stream>>>(
        NH16, 192, WQKT, nullptr, QK, 1152, QKB, nullptr, nullptr, NN, 1152);

    // attention (z built in LDS, MFMA logits) -> ZB [NPAD][1152]
    attn_lite_kernel<<<NN / 2, 256, 0, stream>>>(
        QK, NH16, edge_feat, edge_t, nbr_idx, basis_freq, phase, t_now, ZB);

    // fcr = ZB @ WVF^T + fc_b + self_z
    gemm_kernel<1152, 2><<<dim3(3, 79), 256, 0, stream>>>(
        ZB, 1152, WVFT, FCR, nullptr, 516, fc_b, node_h, CPH, NN, 516);

    ln_x_kernel<<<NN, 256, 0, stream>>>(FCR, ln_g, ln_b, NH16, Xb);

    // fused m1(relu) + m2 -> out
    m1m2_kernel<<<dim3(1, 79), 256, 0, stream>>>(
        Xb, M1WT, M2WT, m1_b, m2_b, (float*)d_out, NN);
}